// Round 9
// baseline (543.549 us; speedup 1.0000x reference)
//
#include <hip/hip_runtime.h>
#include <math.h>

#define B_ 4
#define L_ 2048
#define D_ 512
#define ED_ 1024
#define N_ 16
#define R_ 32
#define KC_ 4
#define M_ (B_*L_)   // 8192 rows
#define NC_ 128      // scan chunks (8 blocks/CU for latency hiding)
#define T_  (L_/NC_) // 16 steps per chunk
#define S_  (B_*ED_*N_)  // 65536 scan series
#define LOG2E 1.44269504f
#define LN2   0.69314718f

typedef __attribute__((ext_vector_type(8))) short short8;
typedef __attribute__((ext_vector_type(4))) float floatx4;
typedef __attribute__((ext_vector_type(2))) float floatv2;   // -> v_pk_*_f32

static __device__ __forceinline__ float b2f(unsigned short u) {
    unsigned int v = ((unsigned int)u) << 16;
    float f;
    __builtin_memcpy(&f, &v, 4);
    return f;
}
static __device__ __forceinline__ unsigned short f2b(float f) {
    unsigned int u;
    __builtin_memcpy(&u, &f, 4);
    unsigned int lsb = (u >> 16) & 1u;
    u += 0x7fffu + lsb;                 // round-to-nearest-even
    return (unsigned short)(u >> 16);
}
static __device__ __forceinline__ float silu(float x) {
    return x / (1.f + exp2f(-LOG2E * x));
}
static __device__ __forceinline__ float softplusf(float x) {
    return fmaxf(x, 0.f) + LN2 * log2f(1.f + exp2f(-LOG2E * fabsf(x)));
}
// pw[i] = {a^(2i+1), a^(2i+2)} via packed tree (depth 4)
static __device__ __forceinline__ void pow_tree2(float a1, floatv2* pw) {
    float a2 = a1 * a1, a4 = a2 * a2, a8 = a4 * a4;
    pw[0] = (floatv2){a1, a2};
    pw[1] = pw[0] * a2;
    pw[2] = pw[0] * a4;
    pw[3] = pw[1] * a4;
    pw[4] = pw[0] * a8;
    pw[5] = pw[1] * a8;
    pw[6] = pw[2] * a8;
    pw[7] = pw[3] * a8;
}

// ---------- dtype detection ----------
__global__ void k_flag0(int* flag) {
    if (blockIdx.x == 0 && threadIdx.x == 0) *flag = 0;
}
__global__ void k_detect(const unsigned short* __restrict__ x, int* flag) {
    int i = blockIdx.x * 256 + threadIdx.x;
    unsigned int e = (x[i] >> 7) & 0xFF;
    unsigned long long m = __ballot(e >= 0x88);
    if ((threadIdx.x & 63) == 0 && m != 0ull) atomicOr(flag, 1);
}

// ---------- batched conversions ----------
struct Seg9 { const void* src[9]; int prefix[10]; };
__global__ void k_cvt_batch(Seg9 segs, float* __restrict__ dst, int total,
                            const int* __restrict__ flag) {
    int i = blockIdx.x * 256 + threadIdx.x;
    if (i >= total) return;
    int s = 0;
#pragma unroll
    for (int k = 1; k < 9; ++k) if (i >= segs.prefix[k]) s = k;
    int off = i - segs.prefix[s];
    if (*flag) dst[i] = ((const float*)segs.src[s])[off];
    else       dst[i] = b2f(((const unsigned short*)segs.src[s])[off]);
}
__global__ void k_cvt_bf_batch(const void* __restrict__ src0,
                               const void* __restrict__ src1,
                               unsigned short* __restrict__ dst,
                               int n0, int total, const int* __restrict__ flag) {
    int i = blockIdx.x * 256 + threadIdx.x;
    if (i >= total) return;
    const void* src = (i < n0) ? src0 : src1;
    int off = (i < n0) ? i : i - n0;
    if (*flag) dst[i] = f2b(((const float*)src)[off]);
    else       dst[i] = ((const unsigned short*)src)[off];
}

// ---------- scan prep (once): transpose dtw to coalesced layout, A0, flag ----
// wT layout per layer: [R/4][ED][4] floats = float4 index (r4*ED + e).
__global__ void k_prep(const float* __restrict__ wdt,
                       const float* __restrict__ A_log,
                       float* __restrict__ wT,
                       float* __restrict__ A0s,
                       int* __restrict__ structf) {
    int idx = blockIdx.x * 256 + threadIdx.x;       // 0 .. 2*ED_-1
    int layer = idx >> 10, e = idx & (ED_ - 1);
    const float* src = wdt + (size_t)idx * R_;
    float* dstb = wT + (size_t)layer * (R_ * ED_);
#pragma unroll
    for (int r = 0; r < R_; ++r)
        dstb[(r >> 2) * (ED_ * 4) + e * 4 + (r & 3)] = src[r];
    float A0 = -exp2f(LOG2E * A_log[(size_t)idx * N_]) * LOG2E;
    bool st = true;
#pragma unroll
    for (int n = 1; n < N_; ++n) {
        float An = -exp2f(LOG2E * A_log[(size_t)idx * N_ + n]) * LOG2E;
        st = st && (fabsf(An - (n + 1) * A0) <= 1e-4f * fabsf(An));
    }
    A0s[idx] = A0;
    structf[idx] = st ? 1 : 0;
}

// ---------- rmsnorm with mask; writes masked x back (f32) and u (bf16) ----------
__global__ __launch_bounds__(128) void k_rmsnorm(float* __restrict__ x,
                                                 const int* __restrict__ mask,
                                                 const float* __restrict__ w,
                                                 unsigned short* __restrict__ ubf) {
    int row = blockIdx.x;
    int tid = threadIdx.x;
    size_t base = (size_t)row * D_ + tid * 4;
    float4 v = *(const float4*)(x + base);
    float mv = (float)mask[row];
    v.x *= mv; v.y *= mv; v.z *= mv; v.w *= mv;
    *(float4*)(x + base) = v;
    float ss = v.x*v.x + v.y*v.y + v.z*v.z + v.w*v.w;
#pragma unroll
    for (int o = 1; o < 64; o <<= 1) ss += __shfl_xor(ss, o, 64);
    __shared__ float sred[2];
    if ((tid & 63) == 0) sred[tid >> 6] = ss;
    __syncthreads();
    float rs = rsqrtf((sred[0] + sred[1]) / (float)D_ + 1e-5f);
    float4 wv = *(const float4*)(w + tid * 4);
    ushort4 b4;
    b4.x = f2b(v.x * rs * wv.x);
    b4.y = f2b(v.y * rs * wv.y);
    b4.z = f2b(v.z * rs * wv.z);
    b4.w = f2b(v.w * rs * wv.w);
    *(ushort4*)(ubf + base) = b4;
}

// ---------- bf16 MFMA GEMM: out = A[M,K] * W[N,K]^T ----------
// 3-buffer rotation, depth-2 prefetch, counted vmcnt (T3+T4). One raw
// s_barrier per K-step; lgkmcnt(0) before barrier closes the read-reuse race.
// XCD-aware bijective block swizzle (grid % 8 == 0 for all call sites).
// MODE 1: write bf16. MODE 2: C=xw RMW + mask. MODE 3: like 2 but writes the
// final output buffer (dtype by flag) + the x[:,0,:] slice; xw not written.
typedef __attribute__((address_space(1))) const unsigned int guint;
typedef __attribute__((address_space(3))) unsigned int luint;
#define GLL(gp, lp) __builtin_amdgcn_global_load_lds((guint*)(const void*)(gp), (luint*)(void*)(lp), 16, 0, 0)

template<int N> static __device__ __forceinline__ void waitv() {
    if constexpr (N == 0) asm volatile("s_waitcnt vmcnt(0)" ::: "memory");
    else if constexpr (N == 3) asm volatile("s_waitcnt vmcnt(3)" ::: "memory");
    else if constexpr (N == 4) asm volatile("s_waitcnt vmcnt(4)" ::: "memory");
}

template<int MODE, int BNT>
__global__ __launch_bounds__(256) void gemm_bt(const unsigned short* __restrict__ A,
                                               const unsigned short* __restrict__ W,
                                               void* __restrict__ C,
                                               const int* __restrict__ mask,
                                               const int* __restrict__ flag,
                                               void* __restrict__ out,
                                               int M, int N, int K) {
    constexpr int NF = BNT / 32;                 // n-frags per wave: 128->4, 64->2
    constexpr int LW = 2 + BNT / 64;             // GLL issues per wave per stage: 4 or 3
    __shared__ unsigned short As[3][128][32];
    __shared__ unsigned short Bs[3][BNT][32];
    int tid  = threadIdx.x;
    int wave = tid >> 6;
    int lane = tid & 63;
    // XCD-aware bijective swizzle (nwg multiple of 8)
    int nwg = gridDim.x * gridDim.y;
    int id  = blockIdx.y * gridDim.x + blockIdx.x;
    int swz = (id & 7) * (nwg >> 3) + (id >> 3);
    int m0 = (swz / gridDim.x) * 128;
    int n0 = (swz % gridDim.x) * BNT;
    int wm = (wave & 1) * 64;
    int wn = (wave >> 1) * (BNT / 2);
    int quad = lane >> 4;
    int l16  = lane & 15;
    int crd = (quad ^ ((l16 >> 1) & 3)) * 8;       // swizzled fragment-read position

    int rA0 = wave * 16 + (lane >> 2);             // rows 0..63; +64 for second issue
    int cA  = ((lane & 3) ^ ((rA0 >> 1) & 3)) * 8;

    floatx4 acc[4][NF] = {};

    auto stage = [&](int buf, int k0) {
        const unsigned short* gA0 = A + (size_t)(m0 + rA0) * K + k0 + cA;
        GLL(gA0,                   &As[buf][wave * 16][0]);
        GLL(gA0 + (size_t)64 * K,  &As[buf][64 + wave * 16][0]);
        const unsigned short* gB0 = W + (size_t)(n0 + rA0) * K + k0 + cA;
        GLL(gB0,                   &Bs[buf][wave * 16][0]);
        if constexpr (BNT == 128)
            GLL(gB0 + (size_t)64 * K, &Bs[buf][64 + wave * 16][0]);
    };

    int nk = K / 32;                               // >= 2 always here
    stage(0, 0);
    stage(1, 32);

    int cur = 0;
    for (int t = 0; t < nk; ++t) {
        if (t + 1 < nk) waitv<LW>();               // stage t landed; t+1 stays in flight
        else            waitv<0>();
        asm volatile("s_barrier" ::: "memory");    // collective: buf cur fully written,
                                                   // and all reads of buf (cur+2)%3 done
        if (t + 2 < nk) {
            int bw = cur + 2; if (bw >= 3) bw -= 3;
            stage(bw, (t + 2) * 32);
        }
        short8 af[4], bfr[NF];
#pragma unroll
        for (int f = 0; f < 4; ++f)
            af[f]  = *(const short8*)&As[cur][wm + f * 16 + l16][crd];
#pragma unroll
        for (int f = 0; f < NF; ++f)
            bfr[f] = *(const short8*)&Bs[cur][wn + f * 16 + l16][crd];
#pragma unroll
        for (int mf = 0; mf < 4; ++mf)
#pragma unroll
            for (int nf = 0; nf < NF; ++nf)
                acc[mf][nf] = __builtin_amdgcn_mfma_f32_16x16x32_bf16(af[mf], bfr[nf], acc[mf][nf], 0, 0, 0);
        asm volatile("s_waitcnt lgkmcnt(0)" ::: "memory");  // reads of buf cur complete
        cur = (cur == 2) ? 0 : cur + 1;
    }

    int fl = (MODE == 3) ? *flag : 0;
#pragma unroll
    for (int mf = 0; mf < 4; ++mf) {
#pragma unroll
        for (int nf = 0; nf < NF; ++nf) {
#pragma unroll
            for (int i = 0; i < 4; ++i) {
                int r = m0 + wm + mf * 16 + quad * 4 + i;   // C/D: row=quad*4+reg
                int c = n0 + wn + nf * 16 + l16;            //      col=lane&15
                size_t idx = (size_t)r * N + c;
                if (MODE == 1) {
                    ((unsigned short*)C)[idx] = f2b(acc[mf][nf][i]);
                } else if (MODE == 2) {
                    float* C32 = (float*)C;
                    float mv = (float)mask[r];
                    C32[idx] = (C32[idx] + acc[mf][nf][i]) * mv;
                } else {
                    const float* C32 = (const float*)C;
                    float mv = (float)mask[r];
                    float v = (C32[idx] + acc[mf][nf][i]) * mv;
                    if (fl) ((float*)out)[idx] = v;
                    else    ((unsigned short*)out)[idx] = f2b(v);
                    if ((r & (L_ - 1)) == 0) {
                        size_t oidx = (size_t)M_ * D_ + (size_t)(r >> 11) * D_ + c;
                        if (fl) ((float*)out)[oidx] = v;
                        else    ((unsigned short*)out)[oidx] = f2b(v);
                    }
                }
            }
        }
    }
}

// ---------- split-K f32 GEMM (GEMM2, N=64) ----------
#define BM 64
#define BN 64
#define BK 16
#define KS 8
__global__ __launch_bounds__(256) void gemm_nt_sk(const float* __restrict__ A,
                                                  const float* __restrict__ W,
                                                  float* __restrict__ part,
                                                  int M, int N, int K) {
    __shared__ float Asm[BK][BM + 4];
    __shared__ float Wsm[BK][BN + 4];
    int tid = threadIdx.x;
    int ks = blockIdx.x;
    int m0 = blockIdx.y * BM;
    int kb = ks * (K / KS);
    int ke = kb + (K / KS);
    int tx = tid & 15;
    int ty = tid >> 4;
    int lr = tid >> 2;
    int lk = (tid & 3) * 4;
    float acc[4][4] = {};
    for (int k0 = kb; k0 < ke; k0 += BK) {
        float4 av = *(const float4*)(A + (size_t)(m0 + lr) * K + k0 + lk);
        Asm[lk + 0][lr] = av.x; Asm[lk + 1][lr] = av.y;
        Asm[lk + 2][lr] = av.z; Asm[lk + 3][lr] = av.w;
        float4 wv = *(const float4*)(W + (size_t)lr * K + k0 + lk);
        Wsm[lk + 0][lr] = wv.x; Wsm[lk + 1][lr] = wv.y;
        Wsm[lk + 2][lr] = wv.z; Wsm[lk + 3][lr] = wv.w;
        __syncthreads();
#pragma unroll
        for (int kk = 0; kk < BK; ++kk) {
            float4 a = *(const float4*)&Asm[kk][ty * 4];
            float4 w = *(const float4*)&Wsm[kk][tx * 4];
            acc[0][0] += a.x * w.x; acc[0][1] += a.x * w.y; acc[0][2] += a.x * w.z; acc[0][3] += a.x * w.w;
            acc[1][0] += a.y * w.x; acc[1][1] += a.y * w.y; acc[1][2] += a.y * w.z; acc[1][3] += a.y * w.w;
            acc[2][0] += a.z * w.x; acc[2][1] += a.z * w.y; acc[2][2] += a.z * w.z; acc[2][3] += a.z * w.w;
            acc[3][0] += a.w * w.x; acc[3][1] += a.w * w.y; acc[3][2] += a.w * w.z; acc[3][3] += a.w * w.w;
        }
        __syncthreads();
    }
    float* p = part + (size_t)ks * M * N;
#pragma unroll
    for (int i = 0; i < 4; ++i) {
        int m = m0 + ty * 4 + i;
#pragma unroll
        for (int j = 0; j < 4; ++j) {
            int n = tx * 4 + j;
            p[(size_t)m * N + n] = acc[i][j];
        }
    }
}

__global__ void k_red8(const float* __restrict__ part, float* __restrict__ dbc, int mn4) {
    int i = blockIdx.x * 256 + threadIdx.x;
    if (i >= mn4) return;
    float4 s = ((const float4*)part)[i];
#pragma unroll
    for (int ks = 1; ks < KS; ++ks) {
        float4 v = ((const float4*)(part + (size_t)ks * mn4 * 4))[i];
        s.x += v.x; s.y += v.y; s.z += v.z; s.w += v.w;
    }
    ((float4*)dbc)[i] = s;
}

// ---------- depthwise causal conv (K=4) + bias + SiLU; xz in bf16 ----------
// 2-wide over e: ushort2 reads (4B/lane), float2 writes.
__global__ __launch_bounds__(256) void k_conv(const unsigned short* __restrict__ xzb,
                                              const float* __restrict__ cw,
                                              const float* __restrict__ cb,
                                              float* __restrict__ xc) {
    int idx = blockIdx.x * 256 + threadIdx.x;      // 0 .. M_*ED_/2
    int e2 = idx & (ED_ / 2 - 1);
    int e  = e2 * 2;
    int bl = idx >> 9;
    int l  = bl & (L_ - 1);
    float acc0 = cb[e], acc1 = cb[e + 1];
    const unsigned short* col = xzb + (size_t)bl * (2 * ED_) + e;
    float4 wa = *(const float4*)(cw + e * 4);
    float4 wb = *(const float4*)(cw + e * 4 + 4);
    ushort2 v3 = *(const ushort2*)(col);
    if (l >= 3) {
        ushort2 v0 = *(const ushort2*)(col - 3 * 2 * ED_);
        ushort2 v1 = *(const ushort2*)(col - 2 * 2 * ED_);
        ushort2 v2 = *(const ushort2*)(col - 1 * 2 * ED_);
        acc0 += wa.x * b2f(v0.x) + wa.y * b2f(v1.x) + wa.z * b2f(v2.x) + wa.w * b2f(v3.x);
        acc1 += wb.x * b2f(v0.y) + wb.y * b2f(v1.y) + wb.z * b2f(v2.y) + wb.w * b2f(v3.y);
    } else {
        if (l >= 2) {
            ushort2 v1 = *(const ushort2*)(col - 2 * 2 * ED_);
            acc0 += wa.y * b2f(v1.x); acc1 += wb.y * b2f(v1.y);
        }
        if (l >= 1) {
            ushort2 v2 = *(const ushort2*)(col - 1 * 2 * ED_);
            acc0 += wa.z * b2f(v2.x); acc1 += wb.z * b2f(v2.y);
        }
        acc0 += wa.w * b2f(v3.x); acc1 += wb.w * b2f(v3.y);
    }
    float2 o; o.x = silu(acc0); o.y = silu(acc1);
    *(float2*)(xc + (size_t)bl * ED_ + e) = o;
}

// ---------- chunked selective scan ----------
// Per-block prologue is now all-coalesced: wT float4 loads, precomputed A0 +
// structured flag (k_prep). scan_a stores h_local + sumd; scan_b rebuilds
// pa = exp2(sumd*A_n); scan_c recomputes delta (same packed op order).
__global__ __launch_bounds__(256) void k_scan_a(const float* __restrict__ xc,
                                                const float* __restrict__ dbc,
                                                const float* __restrict__ wt,
                                                const float* __restrict__ dtb,
                                                const float* __restrict__ A0s,
                                                const int* __restrict__ structf,
                                                const float* __restrict__ A_log,
                                                float* __restrict__ sumdbuf,
                                                float* __restrict__ hl) {
    int b = blockIdx.z, c = blockIdx.y;
    int e = blockIdx.x * 256 + threadIdx.x;
    __shared__ float sRow[T_][64];
    size_t t0 = (size_t)b * L_ + (size_t)c * T_;
    {
        const float4* src = (const float4*)(dbc + t0 * 64);   // T_*64 = 1024 floats
        ((float4*)&sRow[0][0])[threadIdx.x] = src[threadIdx.x];
    }
    __syncthreads();
    floatv2 w2[R_ / 2];
    {
        const float4* wtp = (const float4*)wt;
#pragma unroll
        for (int i = 0; i < 8; ++i) {
            float4 v = wtp[(size_t)i * ED_ + e];              // coalesced
            w2[2 * i]     = (floatv2){v.x, v.y};
            w2[2 * i + 1] = (floatv2){v.z, v.w};
        }
    }
    float bias = dtb[e];
    float A0 = A0s[e];
    bool structured = structf[e] != 0;
    floatv2 h2[8];
#pragma unroll
    for (int i = 0; i < 8; ++i) h2[i] = (floatv2){0.f, 0.f};
    float sumd = 0.f;
    if (structured) {
        const float* xp = xc + t0 * ED_ + e;
        float xv_t = *xp; xp += ED_;
        for (int t = 0; t < T_; ++t) {
            float xv_n = (t + 1 < T_) ? *xp : 0.f; xp += ED_;   // prefetch
            const floatv2* dt2 = (const floatv2*)&sRow[t][0];
            floatv2 q0 = {0.f, 0.f}, q1 = {0.f, 0.f}, q2 = {0.f, 0.f}, q3 = {0.f, 0.f};
#pragma unroll
            for (int r = 0; r < R_ / 2; r += 4) {
                q0 += dt2[r + 0] * w2[r + 0];
                q1 += dt2[r + 1] * w2[r + 1];
                q2 += dt2[r + 2] * w2[r + 2];
                q3 += dt2[r + 3] * w2[r + 3];
            }
            floatv2 qs = (q0 + q1) + (q2 + q3);
            float d = softplusf(qs.x + qs.y + bias);
            float dx = d * xv_t;
            sumd += d;
            floatv2 pw[8];
            pow_tree2(exp2f(d * A0), pw);
            const floatv2* bb2 = (const floatv2*)&sRow[t][32];
#pragma unroll
            for (int i = 0; i < 8; ++i)
                h2[i] = pw[i] * h2[i] + dx * bb2[i];
            xv_t = xv_n;
        }
    } else {
        float A[N_];
        float* h = (float*)h2;
#pragma unroll
        for (int n = 0; n < N_; ++n) A[n] = -exp2f(LOG2E * A_log[e * N_ + n]) * LOG2E;
        float* wsc = (float*)w2;
        for (int t = 0; t < T_; ++t) {
            size_t bl = t0 + t;
            float p0 = bias, p1 = 0.f, p2 = 0.f, p3 = 0.f;
#pragma unroll
            for (int r = 0; r < R_; r += 4) {
                p0 += sRow[t][r + 0] * wsc[r + 0];
                p1 += sRow[t][r + 1] * wsc[r + 1];
                p2 += sRow[t][r + 2] * wsc[r + 2];
                p3 += sRow[t][r + 3] * wsc[r + 3];
            }
            float d = softplusf((p0 + p1) + (p2 + p3));
            float dx = d * xc[bl * ED_ + e];
            sumd += d;
#pragma unroll
            for (int n = 0; n < N_; ++n) {
                float a = exp2f(d * A[n]);
                h[n] = a * h[n] + dx * sRow[t][32 + n];
            }
        }
    }
    size_t s = (size_t)c * S_ + ((size_t)b * ED_ + e) * N_;
    const float* h = (const float*)h2;
#pragma unroll
    for (int n = 0; n < N_; ++n) hl[s + n] = h[n];
    sumdbuf[(size_t)c * (B_ * ED_) + (size_t)b * ED_ + e] = sumd;
}

// carry recurrence over chunks; pa reconstructed as exp2(sumd*A_n).
// 8-deep prefetch ring (fully unrolled -> static reg indices).
__global__ __launch_bounds__(256) void k_scan_b(const float* __restrict__ sumd,
                                                const float* __restrict__ hl,
                                                const float* __restrict__ A_log,
                                                float* __restrict__ carry) {
    int s = blockIdx.x * 256 + threadIdx.x;
    float An = -exp2f(LOG2E * A_log[s & (ED_ * N_ - 1)]) * LOG2E;
    int be = s >> 4;                       // b*ED_ + e
    float sdr[8], hlr[8];
#pragma unroll
    for (int c = 0; c < 8; ++c) {
        sdr[c] = sumd[(size_t)c * (B_ * ED_) + be];
        hlr[c] = hl[(size_t)c * S_ + s];
    }
    float h = 0.f;
#pragma unroll
    for (int c = 0; c < NC_; ++c) {
        int r = c & 7;
        carry[(size_t)c * S_ + s] = h;
        float p = exp2f(sdr[r] * An), q = hlr[r];
        if (c + 8 < NC_) {
            sdr[r] = sumd[(size_t)(c + 8) * (B_ * ED_) + be];
            hlr[r] = hl[(size_t)(c + 8) * S_ + s];
        }
        h = p * h + q;
    }
}

__global__ __launch_bounds__(256) void k_scan_c(const float* __restrict__ xc,
                                                const float* __restrict__ dbc,
                                                const unsigned short* __restrict__ xzb,
                                                const float* __restrict__ wt,
                                                const float* __restrict__ dtb,
                                                const float* __restrict__ A0s,
                                                const int* __restrict__ structf,
                                                const float* __restrict__ A_log,
                                                const float* __restrict__ Dp,
                                                const float* __restrict__ carry,
                                                unsigned short* __restrict__ ybf) {
    int b = blockIdx.z, c = blockIdx.y;
    int e = blockIdx.x * 256 + threadIdx.x;
    __shared__ float sRow[T_][64];
    size_t t0 = (size_t)b * L_ + (size_t)c * T_;
    {
        const float4* src = (const float4*)(dbc + t0 * 64);
        ((float4*)&sRow[0][0])[threadIdx.x] = src[threadIdx.x];
    }
    __syncthreads();
    floatv2 w2[R_ / 2];
    {
        const float4* wtp = (const float4*)wt;
#pragma unroll
        for (int i = 0; i < 8; ++i) {
            float4 v = wtp[(size_t)i * ED_ + e];              // coalesced
            w2[2 * i]     = (floatv2){v.x, v.y};
            w2[2 * i + 1] = (floatv2){v.z, v.w};
        }
    }
    float bias = dtb[e];
    float A0 = A0s[e];
    bool structured = structf[e] != 0;
    floatv2 h2[8];
    size_t s = (size_t)c * S_ + ((size_t)b * ED_ + e) * N_;
    {
        const floatv2* cp = (const floatv2*)(carry + s);
#pragma unroll
        for (int i = 0; i < 8; ++i) h2[i] = cp[i];
    }
    float Dv = Dp[e];
    if (structured) {
        const float* xp  = xc  + t0 * ED_ + e;
        const unsigned short* zp = xzb + t0 * (2 * ED_) + ED_ + e;
        unsigned short* yp = ybf + t0 * ED_ + e;
        float xv_t = *xp;  xp  += ED_;
        unsigned short z_t = *zp; zp += 2 * ED_;
        for (int t = 0; t < T_; ++t) {
            float xv_n = 0.f;
            unsigned short z_n = 0;
            if (t + 1 < T_) {                       // prefetch next step
                xv_n = *xp;
                z_n  = *zp;
            }
            xp += ED_; zp += 2 * ED_;
            // recompute delta (same packed op order as scan_a)
            const floatv2* dt2 = (const floatv2*)&sRow[t][0];
            floatv2 q0 = {0.f, 0.f}, q1 = {0.f, 0.f}, q2 = {0.f, 0.f}, q3 = {0.f, 0.f};
#pragma unroll
            for (int r = 0; r < R_ / 2; r += 4) {
                q0 += dt2[r + 0] * w2[r + 0];
                q1 += dt2[r + 1] * w2[r + 1];
                q2 += dt2[r + 2] * w2[r + 2];
                q3 += dt2[r + 3] * w2[r + 3];
            }
            floatv2 qs = (q0 + q1) + (q2 + q3);
            float d_t = softplusf(qs.x + qs.y + bias);
            float dx = d_t * xv_t;
            floatv2 pw[8];
            pow_tree2(exp2f(d_t * A0), pw);
            const floatv2* bb2 = (const floatv2*)&sRow[t][32];
            const floatv2* cc2 = (const floatv2*)&sRow[t][48];
            floatv2 y0 = {0.f, 0.f}, y1 = {0.f, 0.f};
#pragma unroll
            for (int i = 0; i < 8; i += 2) {
                h2[i + 0] = pw[i + 0] * h2[i + 0] + dx * bb2[i + 0];
                h2[i + 1] = pw[i + 1] * h2[i + 1] + dx * bb2[i + 1];
                y0 += h2[i + 0] * cc2[i + 0];
                y1 += h2[i + 1] * cc2[i + 1];
            }
            floatv2 ys = y0 + y1;
            float y = ys.x + ys.y;
            float z = b2f(z_t);
            *yp = f2b((y + Dv * xv_t) * silu(z)); yp += ED_;
            xv_t = xv_n; z_t = z_n;
        }
    } else {
        float A[N_];
        float* h = (float*)h2;
#pragma unroll
        for (int n = 0; n < N_; ++n) A[n] = -exp2f(LOG2E * A_log[e * N_ + n]) * LOG2E;
        float* wsc = (float*)w2;
        for (int t = 0; t < T_; ++t) {
            size_t bl = t0 + t;
            float p0 = bias, p1 = 0.f, p2 = 0.f, p3 = 0.f;
#pragma unroll
            for (int r = 0; r < R_; r += 4) {
                p0 += sRow[t][r + 0] * wsc[r + 0];
                p1 += sRow[t][r + 1] * wsc[r + 1];
                p2 += sRow[t][r + 2] * wsc[r + 2];
                p3 += sRow[t][r + 3] * wsc[r + 3];
            }
            float d = softplusf((p0 + p1) + (p2 + p3));
            float xv = xc[bl * ED_ + e];
            float dx = d * xv;
            float y = 0.f;
#pragma unroll
            for (int n = 0; n < N_; ++n) {
                float a = exp2f(d * A[n]);
                h[n] = a * h[n] + dx * sRow[t][32 + n];
                y += h[n] * sRow[t][48 + n];
            }
            float z = b2f(xzb[bl * (2 * ED_) + ED_ + e]);
            ybf[bl * ED_ + e] = f2b((y + Dv * xv) * silu(z));
        }
    }
}

extern "C" void kernel_launch(void* const* d_in, const int* in_sizes, int n_in,
                              void* d_out, int out_size, void* d_ws, size_t ws_size,
                              hipStream_t stream) {
    const int* mask = (const int*)d_in[1];

    // workspace layout (~173 MB < proven budget)
    float* ws = (float*)d_ws;
    int*   flag = (int*)d_ws;
    float* xw   = ws + 16;                          // M_*D_         4,194,304
    float* wn   = xw   + (size_t)M_ * D_;           // 1,024
    float* wc   = wn   + 1024;                      // 8,192
    float* wcb  = wc   + 8192;                      // 2,048
    float* wx   = wcb  + 2048;                      // 131,072
    float* wdt  = wx   + 131072;                    // 65,536
    float* wdtb = wdt  + 65536;                     // 2,048
    float* wal  = wdtb + 2048;                      // 32,768
    float* wdp  = wal  + 32768;                     // 2,048
    unsigned short* wib = (unsigned short*)(wdp + 2048);      // 2,097,152 ushorts
    unsigned short* wob = wib + 2097152;                      // 1,048,576 ushorts
    unsigned short* ubf = wob + 1048576;                      // 4,194,304 ushorts
    unsigned short* xzb = ubf + (size_t)M_ * D_;              // 16,777,216 ushorts
    float* xc   = (float*)(xzb + (size_t)M_ * 2 * ED_);       // 8,388,608
    float* dbc  = xc    + (size_t)M_ * ED_;         // 524,288
    float* hl   = dbc   + (size_t)M_ * 64;          // NC_*S_ = 8,388,608
    float* carry= hl    + (size_t)NC_ * S_;         // 8,388,608
    float* sumd = carry + (size_t)NC_ * S_;         // NC_*B_*ED_ = 524,288
    float* wT   = sumd  + (size_t)NC_ * B_ * ED_;   // 2*R_*ED_ = 65,536
    float* A0s  = wT    + 2 * R_ * ED_;             // 2*ED_ = 2,048
    int*   stfl = (int*)(A0s + 2 * ED_);            // 2*ED_ = 2,048
    unsigned short* ybf = (unsigned short*)hl;      // alias: hl dead after scan_b
    float* part = carry;   // KS*M_*64 = 4,194,304 floats; carry dead until scan_b

    k_flag0<<<1, 1, 0, stream>>>(flag);
    k_detect<<<128, 256, 0, stream>>>((const unsigned short*)d_in[0], flag);

    {
        Seg9 segs;
        int idxs[9] = {0, 2, 4, 5, 6, 7, 8, 9, 10};
        int pre = 0;
        for (int i = 0; i < 9; ++i) {
            segs.src[i] = d_in[idxs[i]];
            segs.prefix[i] = pre;
            pre += in_sizes[idxs[i]];
        }
        segs.prefix[9] = pre;
        k_cvt_batch<<<(pre + 255) / 256, 256, 0, stream>>>(segs, xw, pre, flag);
        int n0 = 2 * 2 * ED_ * D_;
        int tot = n0 + 2 * D_ * ED_;
        k_cvt_bf_batch<<<(tot + 255) / 256, 256, 0, stream>>>(d_in[3], d_in[11], wib, n0, tot, flag);
    }
    k_prep<<<(2 * ED_) / 256, 256, 0, stream>>>(wdt, wal, wT, A0s, stfl);

    for (int layer = 0; layer < 2; ++layer) {
        const float* nw = wn  + layer * D_;
        const unsigned short* iw = wib + (size_t)layer * 2 * ED_ * D_;
        const float* cw = wc  + layer * ED_ * KC_;
        const float* cb = wcb + layer * ED_;
        const float* xwp= wx  + (size_t)layer * 64 * ED_;
        const float* db = wdtb+ layer * ED_;
        const float* al = wal + layer * ED_ * N_;
        const float* dp = wdp + layer * ED_;
        const float* wtl= wT  + (size_t)layer * R_ * ED_;
        const float* a0l= A0s + layer * ED_;
        const int*   sfl= stfl+ layer * ED_;
        const unsigned short* ow = wob + (size_t)layer * D_ * ED_;

        k_rmsnorm<<<M_, 128, 0, stream>>>(xw, mask, nw, ubf);
        gemm_bt<1, 128><<<dim3(2 * ED_ / 128, M_ / 128), 256, 0, stream>>>(ubf, iw, xzb, nullptr, nullptr, nullptr, M_, 2 * ED_, D_);
        k_conv<<<(M_ * ED_ / 2) / 256, 256, 0, stream>>>(xzb, cw, cb, xc);
        gemm_nt_sk<<<dim3(KS, M_ / BM), 256, 0, stream>>>(xc, xwp, part, M_, 64, ED_);
        k_red8<<<(M_ * 64 / 4 + 255) / 256, 256, 0, stream>>>(part, dbc, M_ * 64 / 4);
        k_scan_a<<<dim3(ED_ / 256, NC_, B_), 256, 0, stream>>>(xc, dbc, wtl, db, a0l, sfl, al, sumd, hl);
        k_scan_b<<<S_ / 256, 256, 0, stream>>>(sumd, hl, al, carry);
        k_scan_c<<<dim3(ED_ / 256, NC_, B_), 256, 0, stream>>>(xc, dbc, xzb, wtl, db, a0l, sfl, al, dp, carry, ybf);
        if (layer == 0) {
            gemm_bt<2, 64><<<dim3(D_ / 64, M_ / 128), 256, 0, stream>>>(ybf, ow, xw, mask, nullptr, nullptr, M_, D_, ED_);
        } else {
            gemm_bt<3, 64><<<dim3(D_ / 64, M_ / 128), 256, 0, stream>>>(ybf, ow, xw, mask, flag, d_out, M_, D_, ED_);
        }
    }
}

// Round 10
// 539.392 us; speedup vs baseline: 1.0077x; 1.0077x over previous
//
#include <hip/hip_runtime.h>
#include <math.h>

#define B_ 4
#define L_ 2048
#define D_ 512
#define ED_ 1024
#define N_ 16
#define R_ 32
#define KC_ 4
#define M_ (B_*L_)   // 8192 rows
#define NC_ 64       // scan chunks
#define T_  (L_/NC_) // 32 steps per chunk
#define S_  (B_*ED_*N_)  // 65536 scan series
#define BE_ (B_*ED_)     // 4096
#define LOG2E 1.44269504f
#define LN2   0.69314718f

typedef __attribute__((ext_vector_type(8))) short short8;
typedef __attribute__((ext_vector_type(4))) float floatx4;
typedef __attribute__((ext_vector_type(2))) float floatv2;   // -> v_pk_*_f32

static __device__ __forceinline__ float b2f(unsigned short u) {
    unsigned int v = ((unsigned int)u) << 16;
    float f;
    __builtin_memcpy(&f, &v, 4);
    return f;
}
static __device__ __forceinline__ unsigned short f2b(float f) {
    unsigned int u;
    __builtin_memcpy(&u, &f, 4);
    unsigned int lsb = (u >> 16) & 1u;
    u += 0x7fffu + lsb;                 // round-to-nearest-even
    return (unsigned short)(u >> 16);
}
static __device__ __forceinline__ float silu(float x) {
    return x / (1.f + exp2f(-LOG2E * x));
}
static __device__ __forceinline__ float softplusf(float x) {
    return fmaxf(x, 0.f) + LN2 * log2f(1.f + exp2f(-LOG2E * fabsf(x)));
}
// pw[i] = {a^(2i+1), a^(2i+2)} via packed tree (depth 4)
static __device__ __forceinline__ void pow_tree2(float a1, floatv2* pw) {
    float a2 = a1 * a1, a4 = a2 * a2, a8 = a4 * a4;
    pw[0] = (floatv2){a1, a2};
    pw[1] = pw[0] * a2;
    pw[2] = pw[0] * a4;
    pw[3] = pw[1] * a4;
    pw[4] = pw[0] * a8;
    pw[5] = pw[1] * a8;
    pw[6] = pw[2] * a8;
    pw[7] = pw[3] * a8;
}

// ---------- dtype detection ----------
__global__ void k_flag0(int* flag) {
    if (blockIdx.x == 0 && threadIdx.x == 0) *flag = 0;
}
__global__ void k_detect(const unsigned short* __restrict__ x, int* flag) {
    int i = blockIdx.x * 256 + threadIdx.x;
    unsigned int e = (x[i] >> 7) & 0xFF;
    unsigned long long m = __ballot(e >= 0x88);
    if ((threadIdx.x & 63) == 0 && m != 0ull) atomicOr(flag, 1);
}

// ---------- batched conversions ----------
struct Seg9 { const void* src[9]; int prefix[10]; };
__global__ void k_cvt_batch(Seg9 segs, float* __restrict__ dst, int total,
                            const int* __restrict__ flag) {
    int i = blockIdx.x * 256 + threadIdx.x;
    if (i >= total) return;
    int s = 0;
#pragma unroll
    for (int k = 1; k < 9; ++k) if (i >= segs.prefix[k]) s = k;
    int off = i - segs.prefix[s];
    if (*flag) dst[i] = ((const float*)segs.src[s])[off];
    else       dst[i] = b2f(((const unsigned short*)segs.src[s])[off]);
}
__global__ void k_cvt_bf_batch(const void* __restrict__ src0,
                               const void* __restrict__ src1,
                               unsigned short* __restrict__ dst,
                               int n0, int total, const int* __restrict__ flag) {
    int i = blockIdx.x * 256 + threadIdx.x;
    if (i >= total) return;
    const void* src = (i < n0) ? src0 : src1;
    int off = (i < n0) ? i : i - n0;
    if (*flag) dst[i] = f2b(((const float*)src)[off]);
    else       dst[i] = ((const unsigned short*)src)[off];
}

// ---------- scan prep (once): transpose dtw to coalesced layout, A0, flag ----
// wT layout per layer: [R/4][ED][4] floats = float4 index (r4*ED + e).
__global__ void k_prep(const float* __restrict__ wdt,
                       const float* __restrict__ A_log,
                       float* __restrict__ wT,
                       float* __restrict__ A0s,
                       int* __restrict__ structf) {
    int idx = blockIdx.x * 256 + threadIdx.x;       // 0 .. 2*ED_-1
    int layer = idx >> 10, e = idx & (ED_ - 1);
    const float* src = wdt + (size_t)idx * R_;
    float* dstb = wT + (size_t)layer * (R_ * ED_);
#pragma unroll
    for (int r = 0; r < R_; ++r)
        dstb[(r >> 2) * (ED_ * 4) + e * 4 + (r & 3)] = src[r];
    float A0 = -exp2f(LOG2E * A_log[(size_t)idx * N_]) * LOG2E;
    bool st = true;
#pragma unroll
    for (int n = 1; n < N_; ++n) {
        float An = -exp2f(LOG2E * A_log[(size_t)idx * N_ + n]) * LOG2E;
        st = st && (fabsf(An - (n + 1) * A0) <= 1e-4f * fabsf(An));
    }
    A0s[idx] = A0;
    structf[idx] = st ? 1 : 0;
}

// ---------- rmsnorm with mask; writes masked x back (f32) and u (bf16) ----------
__global__ __launch_bounds__(128) void k_rmsnorm(float* __restrict__ x,
                                                 const int* __restrict__ mask,
                                                 const float* __restrict__ w,
                                                 unsigned short* __restrict__ ubf) {
    int row = blockIdx.x;
    int tid = threadIdx.x;
    size_t base = (size_t)row * D_ + tid * 4;
    float4 v = *(const float4*)(x + base);
    float mv = (float)mask[row];
    v.x *= mv; v.y *= mv; v.z *= mv; v.w *= mv;
    *(float4*)(x + base) = v;
    float ss = v.x*v.x + v.y*v.y + v.z*v.z + v.w*v.w;
#pragma unroll
    for (int o = 1; o < 64; o <<= 1) ss += __shfl_xor(ss, o, 64);
    __shared__ float sred[2];
    if ((tid & 63) == 0) sred[tid >> 6] = ss;
    __syncthreads();
    float rs = rsqrtf((sred[0] + sred[1]) / (float)D_ + 1e-5f);
    float4 wv = *(const float4*)(w + tid * 4);
    ushort4 b4;
    b4.x = f2b(v.x * rs * wv.x);
    b4.y = f2b(v.y * rs * wv.y);
    b4.z = f2b(v.z * rs * wv.z);
    b4.w = f2b(v.w * rs * wv.w);
    *(ushort4*)(ubf + base) = b4;
}

// ---------- bf16 MFMA GEMM: out = A[M,K] * W[N,K]^T ----------
// 3-buffer rotation, depth-2 prefetch, counted vmcnt (T3+T4). One raw
// s_barrier per K-step; lgkmcnt(0) before barrier closes the read-reuse race.
// XCD-aware bijective block swizzle (grid % 8 == 0 for all call sites).
// MODE 1: write bf16. MODE 2: C=xw RMW + mask. MODE 3: like 2 but writes the
// final output buffer (dtype by flag) + the x[:,0,:] slice; xw not written.
typedef __attribute__((address_space(1))) const unsigned int guint;
typedef __attribute__((address_space(3))) unsigned int luint;
#define GLL(gp, lp) __builtin_amdgcn_global_load_lds((guint*)(const void*)(gp), (luint*)(void*)(lp), 16, 0, 0)

template<int N> static __device__ __forceinline__ void waitv() {
    if constexpr (N == 0) asm volatile("s_waitcnt vmcnt(0)" ::: "memory");
    else if constexpr (N == 3) asm volatile("s_waitcnt vmcnt(3)" ::: "memory");
    else if constexpr (N == 4) asm volatile("s_waitcnt vmcnt(4)" ::: "memory");
}

template<int MODE, int BNT>
__global__ __launch_bounds__(256) void gemm_bt(const unsigned short* __restrict__ A,
                                               const unsigned short* __restrict__ W,
                                               void* __restrict__ C,
                                               const int* __restrict__ mask,
                                               const int* __restrict__ flag,
                                               void* __restrict__ out,
                                               int M, int N, int K) {
    constexpr int NF = BNT / 32;                 // n-frags per wave: 128->4, 64->2
    constexpr int LW = 2 + BNT / 64;             // GLL issues per wave per stage: 4 or 3
    __shared__ unsigned short As[3][128][32];
    __shared__ unsigned short Bs[3][BNT][32];
    int tid  = threadIdx.x;
    int wave = tid >> 6;
    int lane = tid & 63;
    // XCD-aware bijective swizzle (nwg multiple of 8)
    int nwg = gridDim.x * gridDim.y;
    int id  = blockIdx.y * gridDim.x + blockIdx.x;
    int swz = (id & 7) * (nwg >> 3) + (id >> 3);
    int m0 = (swz / gridDim.x) * 128;
    int n0 = (swz % gridDim.x) * BNT;
    int wm = (wave & 1) * 64;
    int wn = (wave >> 1) * (BNT / 2);
    int quad = lane >> 4;
    int l16  = lane & 15;
    int crd = (quad ^ ((l16 >> 1) & 3)) * 8;       // swizzled fragment-read position

    int rA0 = wave * 16 + (lane >> 2);             // rows 0..63; +64 for second issue
    int cA  = ((lane & 3) ^ ((rA0 >> 1) & 3)) * 8;

    floatx4 acc[4][NF] = {};

    auto stage = [&](int buf, int k0) {
        const unsigned short* gA0 = A + (size_t)(m0 + rA0) * K + k0 + cA;
        GLL(gA0,                   &As[buf][wave * 16][0]);
        GLL(gA0 + (size_t)64 * K,  &As[buf][64 + wave * 16][0]);
        const unsigned short* gB0 = W + (size_t)(n0 + rA0) * K + k0 + cA;
        GLL(gB0,                   &Bs[buf][wave * 16][0]);
        if constexpr (BNT == 128)
            GLL(gB0 + (size_t)64 * K, &Bs[buf][64 + wave * 16][0]);
    };

    int nk = K / 32;                               // >= 2 always here
    stage(0, 0);
    stage(1, 32);

    int cur = 0;
    for (int t = 0; t < nk; ++t) {
        if (t + 1 < nk) waitv<LW>();               // stage t landed; t+1 stays in flight
        else            waitv<0>();
        asm volatile("s_barrier" ::: "memory");    // collective: buf cur fully written,
                                                   // and all reads of buf (cur+2)%3 done
        if (t + 2 < nk) {
            int bw = cur + 2; if (bw >= 3) bw -= 3;
            stage(bw, (t + 2) * 32);
        }
        short8 af[4], bfr[NF];
#pragma unroll
        for (int f = 0; f < 4; ++f)
            af[f]  = *(const short8*)&As[cur][wm + f * 16 + l16][crd];
#pragma unroll
        for (int f = 0; f < NF; ++f)
            bfr[f] = *(const short8*)&Bs[cur][wn + f * 16 + l16][crd];
#pragma unroll
        for (int mf = 0; mf < 4; ++mf)
#pragma unroll
            for (int nf = 0; nf < NF; ++nf)
                acc[mf][nf] = __builtin_amdgcn_mfma_f32_16x16x32_bf16(af[mf], bfr[nf], acc[mf][nf], 0, 0, 0);
        asm volatile("s_waitcnt lgkmcnt(0)" ::: "memory");  // reads of buf cur complete
        cur = (cur == 2) ? 0 : cur + 1;
    }

    int fl = (MODE == 3) ? *flag : 0;
#pragma unroll
    for (int mf = 0; mf < 4; ++mf) {
#pragma unroll
        for (int nf = 0; nf < NF; ++nf) {
#pragma unroll
            for (int i = 0; i < 4; ++i) {
                int r = m0 + wm + mf * 16 + quad * 4 + i;   // C/D: row=quad*4+reg
                int c = n0 + wn + nf * 16 + l16;            //      col=lane&15
                size_t idx = (size_t)r * N + c;
                if (MODE == 1) {
                    ((unsigned short*)C)[idx] = f2b(acc[mf][nf][i]);
                } else if (MODE == 2) {
                    float* C32 = (float*)C;
                    float mv = (float)mask[r];
                    C32[idx] = (C32[idx] + acc[mf][nf][i]) * mv;
                } else {
                    const float* C32 = (const float*)C;
                    float mv = (float)mask[r];
                    float v = (C32[idx] + acc[mf][nf][i]) * mv;
                    if (fl) ((float*)out)[idx] = v;
                    else    ((unsigned short*)out)[idx] = f2b(v);
                    if ((r & (L_ - 1)) == 0) {
                        size_t oidx = (size_t)M_ * D_ + (size_t)(r >> 11) * D_ + c;
                        if (fl) ((float*)out)[oidx] = v;
                        else    ((unsigned short*)out)[oidx] = f2b(v);
                    }
                }
            }
        }
    }
}

// ---------- split-K f32 GEMM (GEMM2, N=64) ----------
#define BM 64
#define BN 64
#define BK 16
#define KS 8
__global__ __launch_bounds__(256) void gemm_nt_sk(const float* __restrict__ A,
                                                  const float* __restrict__ W,
                                                  float* __restrict__ part,
                                                  int M, int N, int K) {
    __shared__ float Asm[BK][BM + 4];
    __shared__ float Wsm[BK][BN + 4];
    int tid = threadIdx.x;
    int ks = blockIdx.x;
    int m0 = blockIdx.y * BM;
    int kb = ks * (K / KS);
    int ke = kb + (K / KS);
    int tx = tid & 15;
    int ty = tid >> 4;
    int lr = tid >> 2;
    int lk = (tid & 3) * 4;
    float acc[4][4] = {};
    for (int k0 = kb; k0 < ke; k0 += BK) {
        float4 av = *(const float4*)(A + (size_t)(m0 + lr) * K + k0 + lk);
        Asm[lk + 0][lr] = av.x; Asm[lk + 1][lr] = av.y;
        Asm[lk + 2][lr] = av.z; Asm[lk + 3][lr] = av.w;
        float4 wv = *(const float4*)(W + (size_t)lr * K + k0 + lk);
        Wsm[lk + 0][lr] = wv.x; Wsm[lk + 1][lr] = wv.y;
        Wsm[lk + 2][lr] = wv.z; Wsm[lk + 3][lr] = wv.w;
        __syncthreads();
#pragma unroll
        for (int kk = 0; kk < BK; ++kk) {
            float4 a = *(const float4*)&Asm[kk][ty * 4];
            float4 w = *(const float4*)&Wsm[kk][tx * 4];
            acc[0][0] += a.x * w.x; acc[0][1] += a.x * w.y; acc[0][2] += a.x * w.z; acc[0][3] += a.x * w.w;
            acc[1][0] += a.y * w.x; acc[1][1] += a.y * w.y; acc[1][2] += a.y * w.z; acc[1][3] += a.y * w.w;
            acc[2][0] += a.z * w.x; acc[2][1] += a.z * w.y; acc[2][2] += a.z * w.z; acc[2][3] += a.z * w.w;
            acc[3][0] += a.w * w.x; acc[3][1] += a.w * w.y; acc[3][2] += a.w * w.z; acc[3][3] += a.w * w.w;
        }
        __syncthreads();
    }
    float* p = part + (size_t)ks * M * N;
#pragma unroll
    for (int i = 0; i < 4; ++i) {
        int m = m0 + ty * 4 + i;
#pragma unroll
        for (int j = 0; j < 4; ++j) {
            int n = tx * 4 + j;
            p[(size_t)m * N + n] = acc[i][j];
        }
    }
}

__global__ void k_red8(const float* __restrict__ part, float* __restrict__ dbc, int mn4) {
    int i = blockIdx.x * 256 + threadIdx.x;
    if (i >= mn4) return;
    float4 s = ((const float4*)part)[i];
#pragma unroll
    for (int ks = 1; ks < KS; ++ks) {
        float4 v = ((const float4*)(part + (size_t)ks * mn4 * 4))[i];
        s.x += v.x; s.y += v.y; s.z += v.z; s.w += v.w;
    }
    ((float4*)dbc)[i] = s;
}

// ---------- depthwise causal conv (K=4) + bias + SiLU; xz in bf16 ----------
// 2-wide over e: ushort2 reads (4B/lane), float2 writes.
__global__ __launch_bounds__(256) void k_conv(const unsigned short* __restrict__ xzb,
                                              const float* __restrict__ cw,
                                              const float* __restrict__ cb,
                                              float* __restrict__ xc) {
    int idx = blockIdx.x * 256 + threadIdx.x;      // 0 .. M_*ED_/2
    int e2 = idx & (ED_ / 2 - 1);
    int e  = e2 * 2;
    int bl = idx >> 9;
    int l  = bl & (L_ - 1);
    float acc0 = cb[e], acc1 = cb[e + 1];
    const unsigned short* col = xzb + (size_t)bl * (2 * ED_) + e;
    float4 wa = *(const float4*)(cw + e * 4);
    float4 wb = *(const float4*)(cw + e * 4 + 4);
    ushort2 v3 = *(const ushort2*)(col);
    if (l >= 3) {
        ushort2 v0 = *(const ushort2*)(col - 3 * 2 * ED_);
        ushort2 v1 = *(const ushort2*)(col - 2 * 2 * ED_);
        ushort2 v2 = *(const ushort2*)(col - 1 * 2 * ED_);
        acc0 += wa.x * b2f(v0.x) + wa.y * b2f(v1.x) + wa.z * b2f(v2.x) + wa.w * b2f(v3.x);
        acc1 += wb.x * b2f(v0.y) + wb.y * b2f(v1.y) + wb.z * b2f(v2.y) + wb.w * b2f(v3.y);
    } else {
        if (l >= 2) {
            ushort2 v1 = *(const ushort2*)(col - 2 * 2 * ED_);
            acc0 += wa.y * b2f(v1.x); acc1 += wb.y * b2f(v1.y);
        }
        if (l >= 1) {
            ushort2 v2 = *(const ushort2*)(col - 1 * 2 * ED_);
            acc0 += wa.z * b2f(v2.x); acc1 += wb.z * b2f(v2.y);
        }
        acc0 += wa.w * b2f(v3.x); acc1 += wb.w * b2f(v3.y);
    }
    float2 o; o.x = silu(acc0); o.y = silu(acc1);
    *(float2*)(xc + (size_t)bl * ED_ + e) = o;
}

// ---------- chunked selective scan ----------
// NC_=64 (T_=32): glue traffic halved vs NC_=128. hl/carry layout [n][c][b*ED+e]
// so every h store / carry load / scan_b access is per-instruction coalesced.
// Prologue all-coalesced via k_prep (wT, A0, structured flag). scan_a stores
// h_local + sumd; scan_b rebuilds pa = exp2(sumd*A_n); scan_c recomputes delta.
__global__ __launch_bounds__(256) void k_scan_a(const float* __restrict__ xc,
                                                const float* __restrict__ dbc,
                                                const float* __restrict__ wt,
                                                const float* __restrict__ dtb,
                                                const float* __restrict__ A0s,
                                                const int* __restrict__ structf,
                                                const float* __restrict__ A_log,
                                                float* __restrict__ sumdbuf,
                                                float* __restrict__ hl) {
    int b = blockIdx.z, c = blockIdx.y;
    int e = blockIdx.x * 256 + threadIdx.x;
    __shared__ float sRow[T_][64];
    size_t t0 = (size_t)b * L_ + (size_t)c * T_;
    {
        const float4* src = (const float4*)(dbc + t0 * 64);   // T_*64 = 2048 floats
        float4* dst = (float4*)&sRow[0][0];
        dst[threadIdx.x]       = src[threadIdx.x];
        dst[threadIdx.x + 256] = src[threadIdx.x + 256];
    }
    __syncthreads();
    floatv2 w2[R_ / 2];
    {
        const float4* wtp = (const float4*)wt;
#pragma unroll
        for (int i = 0; i < 8; ++i) {
            float4 v = wtp[(size_t)i * ED_ + e];              // coalesced
            w2[2 * i]     = (floatv2){v.x, v.y};
            w2[2 * i + 1] = (floatv2){v.z, v.w};
        }
    }
    float bias = dtb[e];
    float A0 = A0s[e];
    bool structured = structf[e] != 0;
    floatv2 h2[8];
#pragma unroll
    for (int i = 0; i < 8; ++i) h2[i] = (floatv2){0.f, 0.f};
    float sumd = 0.f;
    if (structured) {
        const float* xp = xc + t0 * ED_ + e;
        float xv_t = *xp; xp += ED_;
        for (int t = 0; t < T_; ++t) {
            float xv_n = (t + 1 < T_) ? *xp : 0.f; xp += ED_;   // prefetch
            const floatv2* dt2 = (const floatv2*)&sRow[t][0];
            floatv2 q0 = {0.f, 0.f}, q1 = {0.f, 0.f}, q2 = {0.f, 0.f}, q3 = {0.f, 0.f};
#pragma unroll
            for (int r = 0; r < R_ / 2; r += 4) {
                q0 += dt2[r + 0] * w2[r + 0];
                q1 += dt2[r + 1] * w2[r + 1];
                q2 += dt2[r + 2] * w2[r + 2];
                q3 += dt2[r + 3] * w2[r + 3];
            }
            floatv2 qs = (q0 + q1) + (q2 + q3);
            float d = softplusf(qs.x + qs.y + bias);
            float dx = d * xv_t;
            sumd += d;
            floatv2 pw[8];
            pow_tree2(exp2f(d * A0), pw);
            const floatv2* bb2 = (const floatv2*)&sRow[t][32];
#pragma unroll
            for (int i = 0; i < 8; ++i)
                h2[i] = pw[i] * h2[i] + dx * bb2[i];
            xv_t = xv_n;
        }
    } else {
        float A[N_];
        float* h = (float*)h2;
#pragma unroll
        for (int n = 0; n < N_; ++n) A[n] = -exp2f(LOG2E * A_log[e * N_ + n]) * LOG2E;
        float* wsc = (float*)w2;
        for (int t = 0; t < T_; ++t) {
            size_t bl = t0 + t;
            float p0 = bias, p1 = 0.f, p2 = 0.f, p3 = 0.f;
#pragma unroll
            for (int r = 0; r < R_; r += 4) {
                p0 += sRow[t][r + 0] * wsc[r + 0];
                p1 += sRow[t][r + 1] * wsc[r + 1];
                p2 += sRow[t][r + 2] * wsc[r + 2];
                p3 += sRow[t][r + 3] * wsc[r + 3];
            }
            float d = softplusf((p0 + p1) + (p2 + p3));
            float dx = d * xc[bl * ED_ + e];
            sumd += d;
#pragma unroll
            for (int n = 0; n < N_; ++n) {
                float a = exp2f(d * A[n]);
                h[n] = a * h[n] + dx * sRow[t][32 + n];
            }
        }
    }
    size_t base = (size_t)c * BE_ + (size_t)b * ED_ + e;
    const float* h = (const float*)h2;
#pragma unroll
    for (int n = 0; n < N_; ++n)
        hl[(size_t)n * (NC_ * BE_) + base] = h[n];              // coalesced streams
    sumdbuf[base] = sumd;
}

// carry recurrence over chunks; pa reconstructed as exp2(sumd*A_n).
// thread -> (n, be): all hl/carry/sumd accesses coalesced.
// 8-deep prefetch ring (fully unrolled -> static reg indices).
__global__ __launch_bounds__(256) void k_scan_b(const float* __restrict__ sumd,
                                                const float* __restrict__ hl,
                                                const float* __restrict__ A_log,
                                                float* __restrict__ carry) {
    int s = blockIdx.x * 256 + threadIdx.x;     // 0..S_-1
    int n  = s >> 12;                           // S_/N_ = 4096 = BE_
    int be = s & (BE_ - 1);
    int e  = be & (ED_ - 1);
    float An = -exp2f(LOG2E * A_log[e * N_ + n]) * LOG2E;
    const float* hln = hl    + (size_t)n * (NC_ * BE_);
    float*       crn = carry + (size_t)n * (NC_ * BE_);
    float sdr[8], hlr[8];
#pragma unroll
    for (int c = 0; c < 8; ++c) {
        sdr[c] = sumd[(size_t)c * BE_ + be];
        hlr[c] = hln[(size_t)c * BE_ + be];
    }
    float h = 0.f;
#pragma unroll
    for (int c = 0; c < NC_; ++c) {
        int r = c & 7;
        crn[(size_t)c * BE_ + be] = h;
        float p = exp2f(sdr[r] * An), q = hlr[r];
        if (c + 8 < NC_) {
            sdr[r] = sumd[(size_t)(c + 8) * BE_ + be];
            hlr[r] = hln[(size_t)(c + 8) * BE_ + be];
        }
        h = p * h + q;
    }
}

__global__ __launch_bounds__(256) void k_scan_c(const float* __restrict__ xc,
                                                const float* __restrict__ dbc,
                                                const unsigned short* __restrict__ xzb,
                                                const float* __restrict__ wt,
                                                const float* __restrict__ dtb,
                                                const float* __restrict__ A0s,
                                                const int* __restrict__ structf,
                                                const float* __restrict__ A_log,
                                                const float* __restrict__ Dp,
                                                const float* __restrict__ carry,
                                                unsigned short* __restrict__ ybf) {
    int b = blockIdx.z, c = blockIdx.y;
    int e = blockIdx.x * 256 + threadIdx.x;
    __shared__ float sRow[T_][64];
    size_t t0 = (size_t)b * L_ + (size_t)c * T_;
    {
        const float4* src = (const float4*)(dbc + t0 * 64);
        float4* dst = (float4*)&sRow[0][0];
        dst[threadIdx.x]       = src[threadIdx.x];
        dst[threadIdx.x + 256] = src[threadIdx.x + 256];
    }
    __syncthreads();
    floatv2 w2[R_ / 2];
    {
        const float4* wtp = (const float4*)wt;
#pragma unroll
        for (int i = 0; i < 8; ++i) {
            float4 v = wtp[(size_t)i * ED_ + e];              // coalesced
            w2[2 * i]     = (floatv2){v.x, v.y};
            w2[2 * i + 1] = (floatv2){v.z, v.w};
        }
    }
    float bias = dtb[e];
    float A0 = A0s[e];
    bool structured = structf[e] != 0;
    floatv2 h2[8];
    size_t base = (size_t)c * BE_ + (size_t)b * ED_ + e;
    {
        float hs[N_];
#pragma unroll
        for (int n = 0; n < N_; ++n)
            hs[n] = carry[(size_t)n * (NC_ * BE_) + base];      // coalesced streams
#pragma unroll
        for (int i = 0; i < 8; ++i) h2[i] = (floatv2){hs[2 * i], hs[2 * i + 1]};
    }
    float Dv = Dp[e];
    if (structured) {
        const float* xp  = xc  + t0 * ED_ + e;
        const unsigned short* zp = xzb + t0 * (2 * ED_) + ED_ + e;
        unsigned short* yp = ybf + t0 * ED_ + e;
        float xv_t = *xp;  xp  += ED_;
        unsigned short z_t = *zp; zp += 2 * ED_;
        for (int t = 0; t < T_; ++t) {
            float xv_n = 0.f;
            unsigned short z_n = 0;
            if (t + 1 < T_) {                       // prefetch next step
                xv_n = *xp;
                z_n  = *zp;
            }
            xp += ED_; zp += 2 * ED_;
            // recompute delta (same packed op order as scan_a)
            const floatv2* dt2 = (const floatv2*)&sRow[t][0];
            floatv2 q0 = {0.f, 0.f}, q1 = {0.f, 0.f}, q2 = {0.f, 0.f}, q3 = {0.f, 0.f};
#pragma unroll
            for (int r = 0; r < R_ / 2; r += 4) {
                q0 += dt2[r + 0] * w2[r + 0];
                q1 += dt2[r + 1] * w2[r + 1];
                q2 += dt2[r + 2] * w2[r + 2];
                q3 += dt2[r + 3] * w2[r + 3];
            }
            floatv2 qs = (q0 + q1) + (q2 + q3);
            float d_t = softplusf(qs.x + qs.y + bias);
            float dx = d_t * xv_t;
            floatv2 pw[8];
            pow_tree2(exp2f(d_t * A0), pw);
            const floatv2* bb2 = (const floatv2*)&sRow[t][32];
            const floatv2* cc2 = (const floatv2*)&sRow[t][48];
            floatv2 y0 = {0.f, 0.f}, y1 = {0.f, 0.f};
#pragma unroll
            for (int i = 0; i < 8; i += 2) {
                h2[i + 0] = pw[i + 0] * h2[i + 0] + dx * bb2[i + 0];
                h2[i + 1] = pw[i + 1] * h2[i + 1] + dx * bb2[i + 1];
                y0 += h2[i + 0] * cc2[i + 0];
                y1 += h2[i + 1] * cc2[i + 1];
            }
            floatv2 ys = y0 + y1;
            float y = ys.x + ys.y;
            float z = b2f(z_t);
            *yp = f2b((y + Dv * xv_t) * silu(z)); yp += ED_;
            xv_t = xv_n; z_t = z_n;
        }
    } else {
        float A[N_];
        float* h = (float*)h2;
#pragma unroll
        for (int n = 0; n < N_; ++n) A[n] = -exp2f(LOG2E * A_log[e * N_ + n]) * LOG2E;
        float* wsc = (float*)w2;
        for (int t = 0; t < T_; ++t) {
            size_t bl = t0 + t;
            float p0 = bias, p1 = 0.f, p2 = 0.f, p3 = 0.f;
#pragma unroll
            for (int r = 0; r < R_; r += 4) {
                p0 += sRow[t][r + 0] * wsc[r + 0];
                p1 += sRow[t][r + 1] * wsc[r + 1];
                p2 += sRow[t][r + 2] * wsc[r + 2];
                p3 += sRow[t][r + 3] * wsc[r + 3];
            }
            float d = softplusf((p0 + p1) + (p2 + p3));
            float xv = xc[bl * ED_ + e];
            float dx = d * xv;
            float y = 0.f;
#pragma unroll
            for (int n = 0; n < N_; ++n) {
                float a = exp2f(d * A[n]);
                h[n] = a * h[n] + dx * sRow[t][32 + n];
                y += h[n] * sRow[t][48 + n];
            }
            float z = b2f(xzb[bl * (2 * ED_) + ED_ + e]);
            ybf[bl * ED_ + e] = f2b((y + Dv * xv) * silu(z));
        }
    }
}

extern "C" void kernel_launch(void* const* d_in, const int* in_sizes, int n_in,
                              void* d_out, int out_size, void* d_ws, size_t ws_size,
                              hipStream_t stream) {
    const int* mask = (const int*)d_in[1];

    // workspace layout (~140 MB < proven budget)
    float* ws = (float*)d_ws;
    int*   flag = (int*)d_ws;
    float* xw   = ws + 16;                          // M_*D_         4,194,304
    float* wn   = xw   + (size_t)M_ * D_;           // 1,024
    float* wc   = wn   + 1024;                      // 8,192
    float* wcb  = wc   + 8192;                      // 2,048
    float* wx   = wcb  + 2048;                      // 131,072
    float* wdt  = wx   + 131072;                    // 65,536
    float* wdtb = wdt  + 65536;                     // 2,048
    float* wal  = wdtb + 2048;                      // 32,768
    float* wdp  = wal  + 32768;                     // 2,048
    unsigned short* wib = (unsigned short*)(wdp + 2048);      // 2,097,152 ushorts
    unsigned short* wob = wib + 2097152;                      // 1,048,576 ushorts
    unsigned short* ubf = wob + 1048576;                      // 4,194,304 ushorts
    unsigned short* xzb = ubf + (size_t)M_ * D_;              // 16,777,216 ushorts
    float* xc   = (float*)(xzb + (size_t)M_ * 2 * ED_);       // 8,388,608
    float* dbc  = xc    + (size_t)M_ * ED_;         // 524,288
    float* hl   = dbc   + (size_t)M_ * 64;          // NC_*S_ = 4,194,304
    float* carry= hl    + (size_t)NC_ * S_;         // 4,194,304
    float* sumd = carry + (size_t)NC_ * S_;         // NC_*BE_ = 262,144
    float* wT   = sumd  + (size_t)NC_ * BE_;        // 2*R_*ED_ = 65,536
    float* A0s  = wT    + 2 * R_ * ED_;             // 2*ED_ = 2,048
    int*   stfl = (int*)(A0s + 2 * ED_);            // 2*ED_ = 2,048
    unsigned short* ybf = (unsigned short*)hl;      // alias: hl dead after scan_b (exact fit)
    float* part = carry;   // KS*M_*64 = 4,194,304 floats; carry dead until scan_b (exact fit)

    k_flag0<<<1, 1, 0, stream>>>(flag);
    k_detect<<<128, 256, 0, stream>>>((const unsigned short*)d_in[0], flag);

    {
        Seg9 segs;
        int idxs[9] = {0, 2, 4, 5, 6, 7, 8, 9, 10};
        int pre = 0;
        for (int i = 0; i < 9; ++i) {
            segs.src[i] = d_in[idxs[i]];
            segs.prefix[i] = pre;
            pre += in_sizes[idxs[i]];
        }
        segs.prefix[9] = pre;
        k_cvt_batch<<<(pre + 255) / 256, 256, 0, stream>>>(segs, xw, pre, flag);
        int n0 = 2 * 2 * ED_ * D_;
        int tot = n0 + 2 * D_ * ED_;
        k_cvt_bf_batch<<<(tot + 255) / 256, 256, 0, stream>>>(d_in[3], d_in[11], wib, n0, tot, flag);
    }
    k_prep<<<(2 * ED_) / 256, 256, 0, stream>>>(wdt, wal, wT, A0s, stfl);

    for (int layer = 0; layer < 2; ++layer) {
        const float* nw = wn  + layer * D_;
        const unsigned short* iw = wib + (size_t)layer * 2 * ED_ * D_;
        const float* cw = wc  + layer * ED_ * KC_;
        const float* cb = wcb + layer * ED_;
        const float* xwp= wx  + (size_t)layer * 64 * ED_;
        const float* db = wdtb+ layer * ED_;
        const float* al = wal + layer * ED_ * N_;
        const float* dp = wdp + layer * ED_;
        const float* wtl= wT  + (size_t)layer * R_ * ED_;
        const float* a0l= A0s + layer * ED_;
        const int*   sfl= stfl+ layer * ED_;
        const unsigned short* ow = wob + (size_t)layer * D_ * ED_;

        k_rmsnorm<<<M_, 128, 0, stream>>>(xw, mask, nw, ubf);
        gemm_bt<1, 128><<<dim3(2 * ED_ / 128, M_ / 128), 256, 0, stream>>>(ubf, iw, xzb, nullptr, nullptr, nullptr, M_, 2 * ED_, D_);
        k_conv<<<(M_ * ED_ / 2) / 256, 256, 0, stream>>>(xzb, cw, cb, xc);
        gemm_nt_sk<<<dim3(KS, M_ / BM), 256, 0, stream>>>(xc, xwp, part, M_, 64, ED_);
        k_red8<<<(M_ * 64 / 4 + 255) / 256, 256, 0, stream>>>(part, dbc, M_ * 64 / 4);
        k_scan_a<<<dim3(ED_ / 256, NC_, B_), 256, 0, stream>>>(xc, dbc, wtl, db, a0l, sfl, al, sumd, hl);
        k_scan_b<<<S_ / 256, 256, 0, stream>>>(sumd, hl, al, carry);
        k_scan_c<<<dim3(ED_ / 256, NC_, B_), 256, 0, stream>>>(xc, dbc, xzb, wtl, db, a0l, sfl, al, dp, carry, ybf);
        if (layer == 0) {
            gemm_bt<2, 64><<<dim3(D_ / 64, M_ / 128), 256, 0, stream>>>(ybf, ow, xw, mask, nullptr, nullptr, M_, D_, ED_);
        } else {
            gemm_bt<3, 64><<<dim3(D_ / 64, M_ / 128), 256, 0, stream>>>(ybf, ow, xw, mask, flag, d_out, M_, D_, ED_);
        }
    }
}

// Round 11
// 528.613 us; speedup vs baseline: 1.0283x; 1.0204x over previous
//
#include <hip/hip_runtime.h>
#include <math.h>

#define B_ 4
#define L_ 2048
#define D_ 512
#define ED_ 1024
#define N_ 16
#define R_ 32
#define KC_ 4
#define M_ (B_*L_)   // 8192 rows
#define NC_ 128      // scan chunks (8 blocks/CU: occupancy beats glue traffic, r8 vs r10)
#define T_  (L_/NC_) // 16 steps per chunk
#define S_  (B_*ED_*N_)  // 65536 scan series
#define BE_ (B_*ED_)     // 4096
#define LOG2E 1.44269504f
#define LN2   0.69314718f

typedef __attribute__((ext_vector_type(8))) short short8;
typedef __attribute__((ext_vector_type(4))) float floatx4;
typedef __attribute__((ext_vector_type(2))) float floatv2;   // -> v_pk_*_f32

static __device__ __forceinline__ float b2f(unsigned short u) {
    unsigned int v = ((unsigned int)u) << 16;
    float f;
    __builtin_memcpy(&f, &v, 4);
    return f;
}
static __device__ __forceinline__ unsigned short f2b(float f) {
    unsigned int u;
    __builtin_memcpy(&u, &f, 4);
    unsigned int lsb = (u >> 16) & 1u;
    u += 0x7fffu + lsb;                 // round-to-nearest-even
    return (unsigned short)(u >> 16);
}
static __device__ __forceinline__ float silu(float x) {
    return x / (1.f + exp2f(-LOG2E * x));
}
static __device__ __forceinline__ float softplusf(float x) {
    return fmaxf(x, 0.f) + LN2 * log2f(1.f + exp2f(-LOG2E * fabsf(x)));
}
// pw[i] = {a^(2i+1), a^(2i+2)} via packed tree (depth 4)
static __device__ __forceinline__ void pow_tree2(float a1, floatv2* pw) {
    float a2 = a1 * a1, a4 = a2 * a2, a8 = a4 * a4;
    pw[0] = (floatv2){a1, a2};
    pw[1] = pw[0] * a2;
    pw[2] = pw[0] * a4;
    pw[3] = pw[1] * a4;
    pw[4] = pw[0] * a8;
    pw[5] = pw[1] * a8;
    pw[6] = pw[2] * a8;
    pw[7] = pw[3] * a8;
}

// ---------- dtype detection ----------
__global__ void k_flag0(int* flag) {
    if (blockIdx.x == 0 && threadIdx.x == 0) *flag = 0;
}
__global__ void k_detect(const unsigned short* __restrict__ x, int* flag) {
    int i = blockIdx.x * 256 + threadIdx.x;
    unsigned int e = (x[i] >> 7) & 0xFF;
    unsigned long long m = __ballot(e >= 0x88);
    if ((threadIdx.x & 63) == 0 && m != 0ull) atomicOr(flag, 1);
}

// ---------- batched conversions ----------
struct Seg9 { const void* src[9]; int prefix[10]; };
__global__ void k_cvt_batch(Seg9 segs, float* __restrict__ dst, int total,
                            const int* __restrict__ flag) {
    int i = blockIdx.x * 256 + threadIdx.x;
    if (i >= total) return;
    int s = 0;
#pragma unroll
    for (int k = 1; k < 9; ++k) if (i >= segs.prefix[k]) s = k;
    int off = i - segs.prefix[s];
    if (*flag) dst[i] = ((const float*)segs.src[s])[off];
    else       dst[i] = b2f(((const unsigned short*)segs.src[s])[off]);
}
__global__ void k_cvt_bf_batch(const void* __restrict__ src0,
                               const void* __restrict__ src1,
                               unsigned short* __restrict__ dst,
                               int n0, int total, const int* __restrict__ flag) {
    int i = blockIdx.x * 256 + threadIdx.x;
    if (i >= total) return;
    const void* src = (i < n0) ? src0 : src1;
    int off = (i < n0) ? i : i - n0;
    if (*flag) dst[i] = f2b(((const float*)src)[off]);
    else       dst[i] = ((const unsigned short*)src)[off];
}

// ---------- scan prep (once): transpose dtw to coalesced layout, A0, flag ----
// wT layout per layer: [R/4][ED][4] floats = float4 index (r4*ED + e).
__global__ void k_prep(const float* __restrict__ wdt,
                       const float* __restrict__ A_log,
                       float* __restrict__ wT,
                       float* __restrict__ A0s,
                       int* __restrict__ structf) {
    int idx = blockIdx.x * 256 + threadIdx.x;       // 0 .. 2*ED_-1
    int layer = idx >> 10, e = idx & (ED_ - 1);
    const float* src = wdt + (size_t)idx * R_;
    float* dstb = wT + (size_t)layer * (R_ * ED_);
#pragma unroll
    for (int r = 0; r < R_; ++r)
        dstb[(r >> 2) * (ED_ * 4) + e * 4 + (r & 3)] = src[r];
    float A0 = -exp2f(LOG2E * A_log[(size_t)idx * N_]) * LOG2E;
    bool st = true;
#pragma unroll
    for (int n = 1; n < N_; ++n) {
        float An = -exp2f(LOG2E * A_log[(size_t)idx * N_ + n]) * LOG2E;
        st = st && (fabsf(An - (n + 1) * A0) <= 1e-4f * fabsf(An));
    }
    A0s[idx] = A0;
    structf[idx] = st ? 1 : 0;
}

// ---------- rmsnorm with mask; writes masked x back (f32) and u (bf16) ----------
__global__ __launch_bounds__(128) void k_rmsnorm(float* __restrict__ x,
                                                 const int* __restrict__ mask,
                                                 const float* __restrict__ w,
                                                 unsigned short* __restrict__ ubf) {
    int row = blockIdx.x;
    int tid = threadIdx.x;
    size_t base = (size_t)row * D_ + tid * 4;
    float4 v = *(const float4*)(x + base);
    float mv = (float)mask[row];
    v.x *= mv; v.y *= mv; v.z *= mv; v.w *= mv;
    *(float4*)(x + base) = v;
    float ss = v.x*v.x + v.y*v.y + v.z*v.z + v.w*v.w;
#pragma unroll
    for (int o = 1; o < 64; o <<= 1) ss += __shfl_xor(ss, o, 64);
    __shared__ float sred[2];
    if ((tid & 63) == 0) sred[tid >> 6] = ss;
    __syncthreads();
    float rs = rsqrtf((sred[0] + sred[1]) / (float)D_ + 1e-5f);
    float4 wv = *(const float4*)(w + tid * 4);
    ushort4 b4;
    b4.x = f2b(v.x * rs * wv.x);
    b4.y = f2b(v.y * rs * wv.y);
    b4.z = f2b(v.z * rs * wv.z);
    b4.w = f2b(v.w * rs * wv.w);
    *(ushort4*)(ubf + base) = b4;
}

// ---------- bf16 MFMA GEMM: out = A[M,K] * W[N,K]^T ----------
// 3-buffer rotation, depth-2 prefetch, counted vmcnt (T3+T4). One raw
// s_barrier per K-step; lgkmcnt(0) before barrier closes the read-reuse race.
// XCD-aware bijective block swizzle (grid % 8 == 0 for all call sites).
// MODE 1: write bf16. MODE 2: C=xw RMW + mask. MODE 3: like 2 but writes the
// final output buffer (dtype by flag) + the x[:,0,:] slice; xw not written.
typedef __attribute__((address_space(1))) const unsigned int guint;
typedef __attribute__((address_space(3))) unsigned int luint;
#define GLL(gp, lp) __builtin_amdgcn_global_load_lds((guint*)(const void*)(gp), (luint*)(void*)(lp), 16, 0, 0)

template<int N> static __device__ __forceinline__ void waitv() {
    if constexpr (N == 0) asm volatile("s_waitcnt vmcnt(0)" ::: "memory");
    else if constexpr (N == 3) asm volatile("s_waitcnt vmcnt(3)" ::: "memory");
    else if constexpr (N == 4) asm volatile("s_waitcnt vmcnt(4)" ::: "memory");
}

template<int MODE, int BNT>
__global__ __launch_bounds__(256) void gemm_bt(const unsigned short* __restrict__ A,
                                               const unsigned short* __restrict__ W,
                                               void* __restrict__ C,
                                               const int* __restrict__ mask,
                                               const int* __restrict__ flag,
                                               void* __restrict__ out,
                                               int M, int N, int K) {
    constexpr int NF = BNT / 32;                 // n-frags per wave: 128->4, 64->2
    constexpr int LW = 2 + BNT / 64;             // GLL issues per wave per stage: 4 or 3
    __shared__ unsigned short As[3][128][32];
    __shared__ unsigned short Bs[3][BNT][32];
    int tid  = threadIdx.x;
    int wave = tid >> 6;
    int lane = tid & 63;
    // XCD-aware bijective swizzle (nwg multiple of 8)
    int nwg = gridDim.x * gridDim.y;
    int id  = blockIdx.y * gridDim.x + blockIdx.x;
    int swz = (id & 7) * (nwg >> 3) + (id >> 3);
    int m0 = (swz / gridDim.x) * 128;
    int n0 = (swz % gridDim.x) * BNT;
    int wm = (wave & 1) * 64;
    int wn = (wave >> 1) * (BNT / 2);
    int quad = lane >> 4;
    int l16  = lane & 15;
    int crd = (quad ^ ((l16 >> 1) & 3)) * 8;       // swizzled fragment-read position

    int rA0 = wave * 16 + (lane >> 2);             // rows 0..63; +64 for second issue
    int cA  = ((lane & 3) ^ ((rA0 >> 1) & 3)) * 8;

    floatx4 acc[4][NF] = {};

    auto stage = [&](int buf, int k0) {
        const unsigned short* gA0 = A + (size_t)(m0 + rA0) * K + k0 + cA;
        GLL(gA0,                   &As[buf][wave * 16][0]);
        GLL(gA0 + (size_t)64 * K,  &As[buf][64 + wave * 16][0]);
        const unsigned short* gB0 = W + (size_t)(n0 + rA0) * K + k0 + cA;
        GLL(gB0,                   &Bs[buf][wave * 16][0]);
        if constexpr (BNT == 128)
            GLL(gB0 + (size_t)64 * K, &Bs[buf][64 + wave * 16][0]);
    };

    int nk = K / 32;                               // >= 2 always here
    stage(0, 0);
    stage(1, 32);

    int cur = 0;
    for (int t = 0; t < nk; ++t) {
        if (t + 1 < nk) waitv<LW>();               // stage t landed; t+1 stays in flight
        else            waitv<0>();
        asm volatile("s_barrier" ::: "memory");    // collective: buf cur fully written,
                                                   // and all reads of buf (cur+2)%3 done
        if (t + 2 < nk) {
            int bw = cur + 2; if (bw >= 3) bw -= 3;
            stage(bw, (t + 2) * 32);
        }
        short8 af[4], bfr[NF];
#pragma unroll
        for (int f = 0; f < 4; ++f)
            af[f]  = *(const short8*)&As[cur][wm + f * 16 + l16][crd];
#pragma unroll
        for (int f = 0; f < NF; ++f)
            bfr[f] = *(const short8*)&Bs[cur][wn + f * 16 + l16][crd];
#pragma unroll
        for (int mf = 0; mf < 4; ++mf)
#pragma unroll
            for (int nf = 0; nf < NF; ++nf)
                acc[mf][nf] = __builtin_amdgcn_mfma_f32_16x16x32_bf16(af[mf], bfr[nf], acc[mf][nf], 0, 0, 0);
        asm volatile("s_waitcnt lgkmcnt(0)" ::: "memory");  // reads of buf cur complete
        cur = (cur == 2) ? 0 : cur + 1;
    }

    int fl = (MODE == 3) ? *flag : 0;
#pragma unroll
    for (int mf = 0; mf < 4; ++mf) {
#pragma unroll
        for (int nf = 0; nf < NF; ++nf) {
#pragma unroll
            for (int i = 0; i < 4; ++i) {
                int r = m0 + wm + mf * 16 + quad * 4 + i;   // C/D: row=quad*4+reg
                int c = n0 + wn + nf * 16 + l16;            //      col=lane&15
                size_t idx = (size_t)r * N + c;
                if (MODE == 1) {
                    ((unsigned short*)C)[idx] = f2b(acc[mf][nf][i]);
                } else if (MODE == 2) {
                    float* C32 = (float*)C;
                    float mv = (float)mask[r];
                    C32[idx] = (C32[idx] + acc[mf][nf][i]) * mv;
                } else {
                    const float* C32 = (const float*)C;
                    float mv = (float)mask[r];
                    float v = (C32[idx] + acc[mf][nf][i]) * mv;
                    if (fl) ((float*)out)[idx] = v;
                    else    ((unsigned short*)out)[idx] = f2b(v);
                    if ((r & (L_ - 1)) == 0) {
                        size_t oidx = (size_t)M_ * D_ + (size_t)(r >> 11) * D_ + c;
                        if (fl) ((float*)out)[oidx] = v;
                        else    ((unsigned short*)out)[oidx] = f2b(v);
                    }
                }
            }
        }
    }
}

// ---------- split-K f32 GEMM (GEMM2, N=64) ----------
#define BM 64
#define BN 64
#define BK 16
#define KS 8
__global__ __launch_bounds__(256) void gemm_nt_sk(const float* __restrict__ A,
                                                  const float* __restrict__ W,
                                                  float* __restrict__ part,
                                                  int M, int N, int K) {
    __shared__ float Asm[BK][BM + 4];
    __shared__ float Wsm[BK][BN + 4];
    int tid = threadIdx.x;
    int ks = blockIdx.x;
    int m0 = blockIdx.y * BM;
    int kb = ks * (K / KS);
    int ke = kb + (K / KS);
    int tx = tid & 15;
    int ty = tid >> 4;
    int lr = tid >> 2;
    int lk = (tid & 3) * 4;
    float acc[4][4] = {};
    for (int k0 = kb; k0 < ke; k0 += BK) {
        float4 av = *(const float4*)(A + (size_t)(m0 + lr) * K + k0 + lk);
        Asm[lk + 0][lr] = av.x; Asm[lk + 1][lr] = av.y;
        Asm[lk + 2][lr] = av.z; Asm[lk + 3][lr] = av.w;
        float4 wv = *(const float4*)(W + (size_t)lr * K + k0 + lk);
        Wsm[lk + 0][lr] = wv.x; Wsm[lk + 1][lr] = wv.y;
        Wsm[lk + 2][lr] = wv.z; Wsm[lk + 3][lr] = wv.w;
        __syncthreads();
#pragma unroll
        for (int kk = 0; kk < BK; ++kk) {
            float4 a = *(const float4*)&Asm[kk][ty * 4];
            float4 w = *(const float4*)&Wsm[kk][tx * 4];
            acc[0][0] += a.x * w.x; acc[0][1] += a.x * w.y; acc[0][2] += a.x * w.z; acc[0][3] += a.x * w.w;
            acc[1][0] += a.y * w.x; acc[1][1] += a.y * w.y; acc[1][2] += a.y * w.z; acc[1][3] += a.y * w.w;
            acc[2][0] += a.z * w.x; acc[2][1] += a.z * w.y; acc[2][2] += a.z * w.z; acc[2][3] += a.z * w.w;
            acc[3][0] += a.w * w.x; acc[3][1] += a.w * w.y; acc[3][2] += a.w * w.z; acc[3][3] += a.w * w.w;
        }
        __syncthreads();
    }
    float* p = part + (size_t)ks * M * N;
#pragma unroll
    for (int i = 0; i < 4; ++i) {
        int m = m0 + ty * 4 + i;
#pragma unroll
        for (int j = 0; j < 4; ++j) {
            int n = tx * 4 + j;
            p[(size_t)m * N + n] = acc[i][j];
        }
    }
}

__global__ void k_red8(const float* __restrict__ part, float* __restrict__ dbc, int mn4) {
    int i = blockIdx.x * 256 + threadIdx.x;
    if (i >= mn4) return;
    float4 s = ((const float4*)part)[i];
#pragma unroll
    for (int ks = 1; ks < KS; ++ks) {
        float4 v = ((const float4*)(part + (size_t)ks * mn4 * 4))[i];
        s.x += v.x; s.y += v.y; s.z += v.z; s.w += v.w;
    }
    ((float4*)dbc)[i] = s;
}

// ---------- depthwise causal conv (K=4) + bias + SiLU; xz in bf16 ----------
// 2-wide over e: ushort2 reads (4B/lane), float2 writes.
__global__ __launch_bounds__(256) void k_conv(const unsigned short* __restrict__ xzb,
                                              const float* __restrict__ cw,
                                              const float* __restrict__ cb,
                                              float* __restrict__ xc) {
    int idx = blockIdx.x * 256 + threadIdx.x;      // 0 .. M_*ED_/2
    int e2 = idx & (ED_ / 2 - 1);
    int e  = e2 * 2;
    int bl = idx >> 9;
    int l  = bl & (L_ - 1);
    float acc0 = cb[e], acc1 = cb[e + 1];
    const unsigned short* col = xzb + (size_t)bl * (2 * ED_) + e;
    float4 wa = *(const float4*)(cw + e * 4);
    float4 wb = *(const float4*)(cw + e * 4 + 4);
    ushort2 v3 = *(const ushort2*)(col);
    if (l >= 3) {
        ushort2 v0 = *(const ushort2*)(col - 3 * 2 * ED_);
        ushort2 v1 = *(const ushort2*)(col - 2 * 2 * ED_);
        ushort2 v2 = *(const ushort2*)(col - 1 * 2 * ED_);
        acc0 += wa.x * b2f(v0.x) + wa.y * b2f(v1.x) + wa.z * b2f(v2.x) + wa.w * b2f(v3.x);
        acc1 += wb.x * b2f(v0.y) + wb.y * b2f(v1.y) + wb.z * b2f(v2.y) + wb.w * b2f(v3.y);
    } else {
        if (l >= 2) {
            ushort2 v1 = *(const ushort2*)(col - 2 * 2 * ED_);
            acc0 += wa.y * b2f(v1.x); acc1 += wb.y * b2f(v1.y);
        }
        if (l >= 1) {
            ushort2 v2 = *(const ushort2*)(col - 1 * 2 * ED_);
            acc0 += wa.z * b2f(v2.x); acc1 += wb.z * b2f(v2.y);
        }
        acc0 += wa.w * b2f(v3.x); acc1 += wb.w * b2f(v3.y);
    }
    float2 o; o.x = silu(acc0); o.y = silu(acc1);
    *(float2*)(xc + (size_t)bl * ED_ + e) = o;
}

// ---------- chunked selective scan ----------
// NC_=128 (occupancy regime, r8/r9) + k_prep coalesced prologue (r9) +
// [n][c][b*ED+e] coalesced hl/carry layout (r10). scan_a stores h_local +
// sumd; scan_b rebuilds pa = exp2(sumd*A_n); scan_c recomputes delta with
// the identical packed-dot op order.
__global__ __launch_bounds__(256) void k_scan_a(const float* __restrict__ xc,
                                                const float* __restrict__ dbc,
                                                const float* __restrict__ wt,
                                                const float* __restrict__ dtb,
                                                const float* __restrict__ A0s,
                                                const int* __restrict__ structf,
                                                const float* __restrict__ A_log,
                                                float* __restrict__ sumdbuf,
                                                float* __restrict__ hl) {
    int b = blockIdx.z, c = blockIdx.y;
    int e = blockIdx.x * 256 + threadIdx.x;
    __shared__ float sRow[T_][64];
    size_t t0 = (size_t)b * L_ + (size_t)c * T_;
    {
        const float4* src = (const float4*)(dbc + t0 * 64);
        float4* dst = (float4*)&sRow[0][0];
#pragma unroll
        for (int i = 0; i < T_ * 16; i += 256)
            dst[i + threadIdx.x] = src[i + threadIdx.x];
    }
    __syncthreads();
    floatv2 w2[R_ / 2];
    {
        const float4* wtp = (const float4*)wt;
#pragma unroll
        for (int i = 0; i < 8; ++i) {
            float4 v = wtp[(size_t)i * ED_ + e];              // coalesced
            w2[2 * i]     = (floatv2){v.x, v.y};
            w2[2 * i + 1] = (floatv2){v.z, v.w};
        }
    }
    float bias = dtb[e];
    float A0 = A0s[e];
    bool structured = structf[e] != 0;
    floatv2 h2[8];
#pragma unroll
    for (int i = 0; i < 8; ++i) h2[i] = (floatv2){0.f, 0.f};
    float sumd = 0.f;
    if (structured) {
        const float* xp = xc + t0 * ED_ + e;
        float xv_t = *xp; xp += ED_;
        for (int t = 0; t < T_; ++t) {
            float xv_n = (t + 1 < T_) ? *xp : 0.f; xp += ED_;   // prefetch
            const floatv2* dt2 = (const floatv2*)&sRow[t][0];
            floatv2 q0 = {0.f, 0.f}, q1 = {0.f, 0.f}, q2 = {0.f, 0.f}, q3 = {0.f, 0.f};
#pragma unroll
            for (int r = 0; r < R_ / 2; r += 4) {
                q0 += dt2[r + 0] * w2[r + 0];
                q1 += dt2[r + 1] * w2[r + 1];
                q2 += dt2[r + 2] * w2[r + 2];
                q3 += dt2[r + 3] * w2[r + 3];
            }
            floatv2 qs = (q0 + q1) + (q2 + q3);
            float d = softplusf(qs.x + qs.y + bias);
            float dx = d * xv_t;
            sumd += d;
            floatv2 pw[8];
            pow_tree2(exp2f(d * A0), pw);
            const floatv2* bb2 = (const floatv2*)&sRow[t][32];
#pragma unroll
            for (int i = 0; i < 8; ++i)
                h2[i] = pw[i] * h2[i] + dx * bb2[i];
            xv_t = xv_n;
        }
    } else {
        float A[N_];
        float* h = (float*)h2;
#pragma unroll
        for (int n = 0; n < N_; ++n) A[n] = -exp2f(LOG2E * A_log[e * N_ + n]) * LOG2E;
        float* wsc = (float*)w2;
        for (int t = 0; t < T_; ++t) {
            size_t bl = t0 + t;
            float p0 = bias, p1 = 0.f, p2 = 0.f, p3 = 0.f;
#pragma unroll
            for (int r = 0; r < R_; r += 4) {
                p0 += sRow[t][r + 0] * wsc[r + 0];
                p1 += sRow[t][r + 1] * wsc[r + 1];
                p2 += sRow[t][r + 2] * wsc[r + 2];
                p3 += sRow[t][r + 3] * wsc[r + 3];
            }
            float d = softplusf((p0 + p1) + (p2 + p3));
            float dx = d * xc[bl * ED_ + e];
            sumd += d;
#pragma unroll
            for (int n = 0; n < N_; ++n) {
                float a = exp2f(d * A[n]);
                h[n] = a * h[n] + dx * sRow[t][32 + n];
            }
        }
    }
    size_t base = (size_t)c * BE_ + (size_t)b * ED_ + e;
    const float* h = (const float*)h2;
#pragma unroll
    for (int n = 0; n < N_; ++n)
        hl[(size_t)n * (NC_ * BE_) + base] = h[n];              // coalesced streams
    sumdbuf[base] = sumd;
}

// carry recurrence over chunks; pa reconstructed as exp2(sumd*A_n).
// thread -> (n, be): all hl/carry/sumd accesses coalesced.
// 8-deep prefetch ring (fully unrolled -> static reg indices).
__global__ __launch_bounds__(256) void k_scan_b(const float* __restrict__ sumd,
                                                const float* __restrict__ hl,
                                                const float* __restrict__ A_log,
                                                float* __restrict__ carry) {
    int s = blockIdx.x * 256 + threadIdx.x;     // 0..S_-1
    int n  = s >> 12;                           // S_/N_ = 4096 = BE_
    int be = s & (BE_ - 1);
    int e  = be & (ED_ - 1);
    float An = -exp2f(LOG2E * A_log[e * N_ + n]) * LOG2E;
    const float* hln = hl    + (size_t)n * (NC_ * BE_);
    float*       crn = carry + (size_t)n * (NC_ * BE_);
    float sdr[8], hlr[8];
#pragma unroll
    for (int c = 0; c < 8; ++c) {
        sdr[c] = sumd[(size_t)c * BE_ + be];
        hlr[c] = hln[(size_t)c * BE_ + be];
    }
    float h = 0.f;
#pragma unroll
    for (int c = 0; c < NC_; ++c) {
        int r = c & 7;
        crn[(size_t)c * BE_ + be] = h;
        float p = exp2f(sdr[r] * An), q = hlr[r];
        if (c + 8 < NC_) {
            sdr[r] = sumd[(size_t)(c + 8) * BE_ + be];
            hlr[r] = hln[(size_t)(c + 8) * BE_ + be];
        }
        h = p * h + q;
    }
}

__global__ __launch_bounds__(256) void k_scan_c(const float* __restrict__ xc,
                                                const float* __restrict__ dbc,
                                                const unsigned short* __restrict__ xzb,
                                                const float* __restrict__ wt,
                                                const float* __restrict__ dtb,
                                                const float* __restrict__ A0s,
                                                const int* __restrict__ structf,
                                                const float* __restrict__ A_log,
                                                const float* __restrict__ Dp,
                                                const float* __restrict__ carry,
                                                unsigned short* __restrict__ ybf) {
    int b = blockIdx.z, c = blockIdx.y;
    int e = blockIdx.x * 256 + threadIdx.x;
    __shared__ float sRow[T_][64];
    size_t t0 = (size_t)b * L_ + (size_t)c * T_;
    {
        const float4* src = (const float4*)(dbc + t0 * 64);
        float4* dst = (float4*)&sRow[0][0];
#pragma unroll
        for (int i = 0; i < T_ * 16; i += 256)
            dst[i + threadIdx.x] = src[i + threadIdx.x];
    }
    __syncthreads();
    floatv2 w2[R_ / 2];
    {
        const float4* wtp = (const float4*)wt;
#pragma unroll
        for (int i = 0; i < 8; ++i) {
            float4 v = wtp[(size_t)i * ED_ + e];              // coalesced
            w2[2 * i]     = (floatv2){v.x, v.y};
            w2[2 * i + 1] = (floatv2){v.z, v.w};
        }
    }
    float bias = dtb[e];
    float A0 = A0s[e];
    bool structured = structf[e] != 0;
    floatv2 h2[8];
    size_t base = (size_t)c * BE_ + (size_t)b * ED_ + e;
    {
        float hs[N_];
#pragma unroll
        for (int n = 0; n < N_; ++n)
            hs[n] = carry[(size_t)n * (NC_ * BE_) + base];      // coalesced streams
#pragma unroll
        for (int i = 0; i < 8; ++i) h2[i] = (floatv2){hs[2 * i], hs[2 * i + 1]};
    }
    float Dv = Dp[e];
    if (structured) {
        const float* xp  = xc  + t0 * ED_ + e;
        const unsigned short* zp = xzb + t0 * (2 * ED_) + ED_ + e;
        unsigned short* yp = ybf + t0 * ED_ + e;
        float xv_t = *xp;  xp  += ED_;
        unsigned short z_t = *zp; zp += 2 * ED_;
        for (int t = 0; t < T_; ++t) {
            float xv_n = 0.f;
            unsigned short z_n = 0;
            if (t + 1 < T_) {                       // prefetch next step
                xv_n = *xp;
                z_n  = *zp;
            }
            xp += ED_; zp += 2 * ED_;
            // recompute delta (same packed op order as scan_a)
            const floatv2* dt2 = (const floatv2*)&sRow[t][0];
            floatv2 q0 = {0.f, 0.f}, q1 = {0.f, 0.f}, q2 = {0.f, 0.f}, q3 = {0.f, 0.f};
#pragma unroll
            for (int r = 0; r < R_ / 2; r += 4) {
                q0 += dt2[r + 0] * w2[r + 0];
                q1 += dt2[r + 1] * w2[r + 1];
                q2 += dt2[r + 2] * w2[r + 2];
                q3 += dt2[r + 3] * w2[r + 3];
            }
            floatv2 qs = (q0 + q1) + (q2 + q3);
            float d_t = softplusf(qs.x + qs.y + bias);
            float dx = d_t * xv_t;
            floatv2 pw[8];
            pow_tree2(exp2f(d_t * A0), pw);
            const floatv2* bb2 = (const floatv2*)&sRow[t][32];
            const floatv2* cc2 = (const floatv2*)&sRow[t][48];
            floatv2 y0 = {0.f, 0.f}, y1 = {0.f, 0.f};
#pragma unroll
            for (int i = 0; i < 8; i += 2) {
                h2[i + 0] = pw[i + 0] * h2[i + 0] + dx * bb2[i + 0];
                h2[i + 1] = pw[i + 1] * h2[i + 1] + dx * bb2[i + 1];
                y0 += h2[i + 0] * cc2[i + 0];
                y1 += h2[i + 1] * cc2[i + 1];
            }
            floatv2 ys = y0 + y1;
            float y = ys.x + ys.y;
            float z = b2f(z_t);
            *yp = f2b((y + Dv * xv_t) * silu(z)); yp += ED_;
            xv_t = xv_n; z_t = z_n;
        }
    } else {
        float A[N_];
        float* h = (float*)h2;
#pragma unroll
        for (int n = 0; n < N_; ++n) A[n] = -exp2f(LOG2E * A_log[e * N_ + n]) * LOG2E;
        float* wsc = (float*)w2;
        for (int t = 0; t < T_; ++t) {
            size_t bl = t0 + t;
            float p0 = bias, p1 = 0.f, p2 = 0.f, p3 = 0.f;
#pragma unroll
            for (int r = 0; r < R_; r += 4) {
                p0 += sRow[t][r + 0] * wsc[r + 0];
                p1 += sRow[t][r + 1] * wsc[r + 1];
                p2 += sRow[t][r + 2] * wsc[r + 2];
                p3 += sRow[t][r + 3] * wsc[r + 3];
            }
            float d = softplusf((p0 + p1) + (p2 + p3));
            float xv = xc[bl * ED_ + e];
            float dx = d * xv;
            float y = 0.f;
#pragma unroll
            for (int n = 0; n < N_; ++n) {
                float a = exp2f(d * A[n]);
                h[n] = a * h[n] + dx * sRow[t][32 + n];
                y += h[n] * sRow[t][48 + n];
            }
            float z = b2f(xzb[bl * (2 * ED_) + ED_ + e]);
            ybf[bl * ED_ + e] = f2b((y + Dv * xv) * silu(z));
        }
    }
}

extern "C" void kernel_launch(void* const* d_in, const int* in_sizes, int n_in,
                              void* d_out, int out_size, void* d_ws, size_t ws_size,
                              hipStream_t stream) {
    const int* mask = (const int*)d_in[1];

    // workspace layout (~173 MB < proven budget)
    float* ws = (float*)d_ws;
    int*   flag = (int*)d_ws;
    float* xw   = ws + 16;                          // M_*D_         4,194,304
    float* wn   = xw   + (size_t)M_ * D_;           // 1,024
    float* wc   = wn   + 1024;                      // 8,192
    float* wcb  = wc   + 8192;                      // 2,048
    float* wx   = wcb  + 2048;                      // 131,072
    float* wdt  = wx   + 131072;                    // 65,536
    float* wdtb = wdt  + 65536;                     // 2,048
    float* wal  = wdtb + 2048;                      // 32,768
    float* wdp  = wal  + 32768;                     // 2,048
    unsigned short* wib = (unsigned short*)(wdp + 2048);      // 2,097,152 ushorts
    unsigned short* wob = wib + 2097152;                      // 1,048,576 ushorts
    unsigned short* ubf = wob + 1048576;                      // 4,194,304 ushorts
    unsigned short* xzb = ubf + (size_t)M_ * D_;              // 16,777,216 ushorts
    float* xc   = (float*)(xzb + (size_t)M_ * 2 * ED_);       // 8,388,608
    float* dbc  = xc    + (size_t)M_ * ED_;         // 524,288
    float* hl   = dbc   + (size_t)M_ * 64;          // NC_*S_ = 8,388,608
    float* carry= hl    + (size_t)NC_ * S_;         // 8,388,608
    float* sumd = carry + (size_t)NC_ * S_;         // NC_*BE_ = 524,288
    float* wT   = sumd  + (size_t)NC_ * BE_;        // 2*R_*ED_ = 65,536
    float* A0s  = wT    + 2 * R_ * ED_;             // 2*ED_ = 2,048
    int*   stfl = (int*)(A0s + 2 * ED_);            // 2*ED_ = 2,048
    unsigned short* ybf = (unsigned short*)hl;      // alias: hl dead after scan_b
    float* part = carry;   // KS*M_*64 = 4,194,304 floats; carry dead until scan_b

    k_flag0<<<1, 1, 0, stream>>>(flag);
    k_detect<<<128, 256, 0, stream>>>((const unsigned short*)d_in[0], flag);

    {
        Seg9 segs;
        int idxs[9] = {0, 2, 4, 5, 6, 7, 8, 9, 10};
        int pre = 0;
        for (int i = 0; i < 9; ++i) {
            segs.src[i] = d_in[idxs[i]];
            segs.prefix[i] = pre;
            pre += in_sizes[idxs[i]];
        }
        segs.prefix[9] = pre;
        k_cvt_batch<<<(pre + 255) / 256, 256, 0, stream>>>(segs, xw, pre, flag);
        int n0 = 2 * 2 * ED_ * D_;
        int tot = n0 + 2 * D_ * ED_;
        k_cvt_bf_batch<<<(tot + 255) / 256, 256, 0, stream>>>(d_in[3], d_in[11], wib, n0, tot, flag);
    }
    k_prep<<<(2 * ED_) / 256, 256, 0, stream>>>(wdt, wal, wT, A0s, stfl);

    for (int layer = 0; layer < 2; ++layer) {
        const float* nw = wn  + layer * D_;
        const unsigned short* iw = wib + (size_t)layer * 2 * ED_ * D_;
        const float* cw = wc  + layer * ED_ * KC_;
        const float* cb = wcb + layer * ED_;
        const float* xwp= wx  + (size_t)layer * 64 * ED_;
        const float* db = wdtb+ layer * ED_;
        const float* al = wal + layer * ED_ * N_;
        const float* dp = wdp + layer * ED_;
        const float* wtl= wT  + (size_t)layer * R_ * ED_;
        const float* a0l= A0s + layer * ED_;
        const int*   sfl= stfl+ layer * ED_;
        const unsigned short* ow = wob + (size_t)layer * D_ * ED_;

        k_rmsnorm<<<M_, 128, 0, stream>>>(xw, mask, nw, ubf);
        gemm_bt<1, 128><<<dim3(2 * ED_ / 128, M_ / 128), 256, 0, stream>>>(ubf, iw, xzb, nullptr, nullptr, nullptr, M_, 2 * ED_, D_);
        k_conv<<<(M_ * ED_ / 2) / 256, 256, 0, stream>>>(xzb, cw, cb, xc);
        gemm_nt_sk<<<dim3(KS, M_ / BM), 256, 0, stream>>>(xc, xwp, part, M_, 64, ED_);
        k_red8<<<(M_ * 64 / 4 + 255) / 256, 256, 0, stream>>>(part, dbc, M_ * 64 / 4);
        k_scan_a<<<dim3(ED_ / 256, NC_, B_), 256, 0, stream>>>(xc, dbc, wtl, db, a0l, sfl, al, sumd, hl);
        k_scan_b<<<S_ / 256, 256, 0, stream>>>(sumd, hl, al, carry);
        k_scan_c<<<dim3(ED_ / 256, NC_, B_), 256, 0, stream>>>(xc, dbc, xzb, wtl, db, a0l, sfl, al, dp, carry, ybf);
        if (layer == 0) {
            gemm_bt<2, 64><<<dim3(D_ / 64, M_ / 128), 256, 0, stream>>>(ybf, ow, xw, mask, nullptr, nullptr, M_, D_, ED_);
        } else {
            gemm_bt<3, 64><<<dim3(D_ / 64, M_ / 128), 256, 0, stream>>>(ybf, ow, xw, mask, flag, d_out, M_, D_, ED_);
        }
    }
}

// Round 12
// 502.461 us; speedup vs baseline: 1.0818x; 1.0520x over previous
//
#include <hip/hip_runtime.h>
#include <math.h>

#define B_ 4
#define L_ 2048
#define D_ 512
#define ED_ 1024
#define N_ 16
#define R_ 32
#define KC_ 4
#define M_ (B_*L_)   // 8192 rows
#define NC_ 128      // scan chunks (8 blocks/CU occupancy regime)
#define T_  (L_/NC_) // 16 steps per chunk
#define S_  (B_*ED_*N_)  // 65536 scan series
#define BE_ (B_*ED_)     // 4096
#define LOG2E 1.44269504f
#define LN2   0.69314718f

typedef __attribute__((ext_vector_type(8))) short short8;
typedef __attribute__((ext_vector_type(4))) float floatx4;
typedef __attribute__((ext_vector_type(2))) float floatv2;   // -> v_pk_*_f32

static __device__ __forceinline__ float b2f(unsigned short u) {
    unsigned int v = ((unsigned int)u) << 16;
    float f;
    __builtin_memcpy(&f, &v, 4);
    return f;
}
static __device__ __forceinline__ unsigned short f2b(float f) {
    unsigned int u;
    __builtin_memcpy(&u, &f, 4);
    unsigned int lsb = (u >> 16) & 1u;
    u += 0x7fffu + lsb;                 // round-to-nearest-even
    return (unsigned short)(u >> 16);
}
static __device__ __forceinline__ float silu(float x) {
    return x / (1.f + exp2f(-LOG2E * x));
}
static __device__ __forceinline__ float softplusf(float x) {
    return fmaxf(x, 0.f) + LN2 * log2f(1.f + exp2f(-LOG2E * fabsf(x)));
}
// pw[i] = {a^(2i+1), a^(2i+2)} via packed tree (depth 4)
static __device__ __forceinline__ void pow_tree2(float a1, floatv2* pw) {
    float a2 = a1 * a1, a4 = a2 * a2, a8 = a4 * a4;
    pw[0] = (floatv2){a1, a2};
    pw[1] = pw[0] * a2;
    pw[2] = pw[0] * a4;
    pw[3] = pw[1] * a4;
    pw[4] = pw[0] * a8;
    pw[5] = pw[1] * a8;
    pw[6] = pw[2] * a8;
    pw[7] = pw[3] * a8;
}

// ---------- dtype detection ----------
__global__ void k_flag0(int* flag) {
    if (blockIdx.x == 0 && threadIdx.x == 0) *flag = 0;
}
__global__ void k_detect(const unsigned short* __restrict__ x, int* flag) {
    int i = blockIdx.x * 256 + threadIdx.x;
    unsigned int e = (x[i] >> 7) & 0xFF;
    unsigned long long m = __ballot(e >= 0x88);
    if ((threadIdx.x & 63) == 0 && m != 0ull) atomicOr(flag, 1);
}

// ---------- batched conversions ----------
struct Seg9 { const void* src[9]; int prefix[10]; };
__global__ void k_cvt_batch(Seg9 segs, float* __restrict__ dst, int total,
                            const int* __restrict__ flag) {
    int i = blockIdx.x * 256 + threadIdx.x;
    if (i >= total) return;
    int s = 0;
#pragma unroll
    for (int k = 1; k < 9; ++k) if (i >= segs.prefix[k]) s = k;
    int off = i - segs.prefix[s];
    if (*flag) dst[i] = ((const float*)segs.src[s])[off];
    else       dst[i] = b2f(((const unsigned short*)segs.src[s])[off]);
}
__global__ void k_cvt_bf_batch(const void* __restrict__ src0,
                               const void* __restrict__ src1,
                               unsigned short* __restrict__ dst,
                               int n0, int total, const int* __restrict__ flag) {
    int i = blockIdx.x * 256 + threadIdx.x;
    if (i >= total) return;
    const void* src = (i < n0) ? src0 : src1;
    int off = (i < n0) ? i : i - n0;
    if (*flag) dst[i] = f2b(((const float*)src)[off]);
    else       dst[i] = ((const unsigned short*)src)[off];
}

// ---------- scan prep (once): transpose dtw to coalesced layout, A0, flag ----
// wT layout per layer: [R/4][ED][4] floats = float4 index (r4*ED + e).
__global__ void k_prep(const float* __restrict__ wdt,
                       const float* __restrict__ A_log,
                       float* __restrict__ wT,
                       float* __restrict__ A0s,
                       int* __restrict__ structf) {
    int idx = blockIdx.x * 256 + threadIdx.x;       // 0 .. 2*ED_-1
    int layer = idx >> 10, e = idx & (ED_ - 1);
    const float* src = wdt + (size_t)idx * R_;
    float* dstb = wT + (size_t)layer * (R_ * ED_);
#pragma unroll
    for (int r = 0; r < R_; ++r)
        dstb[(r >> 2) * (ED_ * 4) + e * 4 + (r & 3)] = src[r];
    float A0 = -exp2f(LOG2E * A_log[(size_t)idx * N_]) * LOG2E;
    bool st = true;
#pragma unroll
    for (int n = 1; n < N_; ++n) {
        float An = -exp2f(LOG2E * A_log[(size_t)idx * N_ + n]) * LOG2E;
        st = st && (fabsf(An - (n + 1) * A0) <= 1e-4f * fabsf(An));
    }
    A0s[idx] = A0;
    structf[idx] = st ? 1 : 0;
}

// ---------- rmsnorm with mask; writes masked x back (f32) and u (bf16) ----------
__global__ __launch_bounds__(128) void k_rmsnorm(float* __restrict__ x,
                                                 const int* __restrict__ mask,
                                                 const float* __restrict__ w,
                                                 unsigned short* __restrict__ ubf) {
    int row = blockIdx.x;
    int tid = threadIdx.x;
    size_t base = (size_t)row * D_ + tid * 4;
    float4 v = *(const float4*)(x + base);
    float mv = (float)mask[row];
    v.x *= mv; v.y *= mv; v.z *= mv; v.w *= mv;
    *(float4*)(x + base) = v;
    float ss = v.x*v.x + v.y*v.y + v.z*v.z + v.w*v.w;
#pragma unroll
    for (int o = 1; o < 64; o <<= 1) ss += __shfl_xor(ss, o, 64);
    __shared__ float sred[2];
    if ((tid & 63) == 0) sred[tid >> 6] = ss;
    __syncthreads();
    float rs = rsqrtf((sred[0] + sred[1]) / (float)D_ + 1e-5f);
    float4 wv = *(const float4*)(w + tid * 4);
    ushort4 b4;
    b4.x = f2b(v.x * rs * wv.x);
    b4.y = f2b(v.y * rs * wv.y);
    b4.z = f2b(v.z * rs * wv.z);
    b4.w = f2b(v.w * rs * wv.w);
    *(ushort4*)(ubf + base) = b4;
}

// ---------- bf16 MFMA GEMM: out = A[M,K] * W[N,K]^T ----------
// 3-buffer rotation, depth-2 prefetch, counted vmcnt (T3+T4). One raw
// s_barrier per K-step; lgkmcnt(0) before barrier closes the read-reuse race.
// XCD-aware bijective block swizzle (grid % 8 == 0 for all call sites).
// MODE 1: write bf16. MODE 2: C=xw RMW + mask. MODE 3: like 2 but writes the
// final output buffer (dtype by flag) + the x[:,0,:] slice; xw not written.
typedef __attribute__((address_space(1))) const unsigned int guint;
typedef __attribute__((address_space(3))) unsigned int luint;
#define GLL(gp, lp) __builtin_amdgcn_global_load_lds((guint*)(const void*)(gp), (luint*)(void*)(lp), 16, 0, 0)

template<int N> static __device__ __forceinline__ void waitv() {
    if constexpr (N == 0) asm volatile("s_waitcnt vmcnt(0)" ::: "memory");
    else if constexpr (N == 3) asm volatile("s_waitcnt vmcnt(3)" ::: "memory");
    else if constexpr (N == 4) asm volatile("s_waitcnt vmcnt(4)" ::: "memory");
}

template<int MODE, int BNT>
__global__ __launch_bounds__(256) void gemm_bt(const unsigned short* __restrict__ A,
                                               const unsigned short* __restrict__ W,
                                               void* __restrict__ C,
                                               const int* __restrict__ mask,
                                               const int* __restrict__ flag,
                                               void* __restrict__ out,
                                               int M, int N, int K) {
    constexpr int NF = BNT / 32;                 // n-frags per wave: 128->4, 64->2
    constexpr int LW = 2 + BNT / 64;             // GLL issues per wave per stage: 4 or 3
    __shared__ unsigned short As[3][128][32];
    __shared__ unsigned short Bs[3][BNT][32];
    int tid  = threadIdx.x;
    int wave = tid >> 6;
    int lane = tid & 63;
    // XCD-aware bijective swizzle (nwg multiple of 8)
    int nwg = gridDim.x * gridDim.y;
    int id  = blockIdx.y * gridDim.x + blockIdx.x;
    int swz = (id & 7) * (nwg >> 3) + (id >> 3);
    int m0 = (swz / gridDim.x) * 128;
    int n0 = (swz % gridDim.x) * BNT;
    int wm = (wave & 1) * 64;
    int wn = (wave >> 1) * (BNT / 2);
    int quad = lane >> 4;
    int l16  = lane & 15;
    int crd = (quad ^ ((l16 >> 1) & 3)) * 8;       // swizzled fragment-read position

    int rA0 = wave * 16 + (lane >> 2);             // rows 0..63; +64 for second issue
    int cA  = ((lane & 3) ^ ((rA0 >> 1) & 3)) * 8;

    floatx4 acc[4][NF] = {};

    auto stage = [&](int buf, int k0) {
        const unsigned short* gA0 = A + (size_t)(m0 + rA0) * K + k0 + cA;
        GLL(gA0,                   &As[buf][wave * 16][0]);
        GLL(gA0 + (size_t)64 * K,  &As[buf][64 + wave * 16][0]);
        const unsigned short* gB0 = W + (size_t)(n0 + rA0) * K + k0 + cA;
        GLL(gB0,                   &Bs[buf][wave * 16][0]);
        if constexpr (BNT == 128)
            GLL(gB0 + (size_t)64 * K, &Bs[buf][64 + wave * 16][0]);
    };

    int nk = K / 32;                               // >= 2 always here
    stage(0, 0);
    stage(1, 32);

    int cur = 0;
    for (int t = 0; t < nk; ++t) {
        if (t + 1 < nk) waitv<LW>();               // stage t landed; t+1 stays in flight
        else            waitv<0>();
        asm volatile("s_barrier" ::: "memory");    // collective: buf cur fully written,
                                                   // and all reads of buf (cur+2)%3 done
        if (t + 2 < nk) {
            int bw = cur + 2; if (bw >= 3) bw -= 3;
            stage(bw, (t + 2) * 32);
        }
        short8 af[4], bfr[NF];
#pragma unroll
        for (int f = 0; f < 4; ++f)
            af[f]  = *(const short8*)&As[cur][wm + f * 16 + l16][crd];
#pragma unroll
        for (int f = 0; f < NF; ++f)
            bfr[f] = *(const short8*)&Bs[cur][wn + f * 16 + l16][crd];
#pragma unroll
        for (int mf = 0; mf < 4; ++mf)
#pragma unroll
            for (int nf = 0; nf < NF; ++nf)
                acc[mf][nf] = __builtin_amdgcn_mfma_f32_16x16x32_bf16(af[mf], bfr[nf], acc[mf][nf], 0, 0, 0);
        asm volatile("s_waitcnt lgkmcnt(0)" ::: "memory");  // reads of buf cur complete
        cur = (cur == 2) ? 0 : cur + 1;
    }

    int fl = (MODE == 3) ? *flag : 0;
#pragma unroll
    for (int mf = 0; mf < 4; ++mf) {
#pragma unroll
        for (int nf = 0; nf < NF; ++nf) {
#pragma unroll
            for (int i = 0; i < 4; ++i) {
                int r = m0 + wm + mf * 16 + quad * 4 + i;   // C/D: row=quad*4+reg
                int c = n0 + wn + nf * 16 + l16;            //      col=lane&15
                size_t idx = (size_t)r * N + c;
                if (MODE == 1) {
                    ((unsigned short*)C)[idx] = f2b(acc[mf][nf][i]);
                } else if (MODE == 2) {
                    float* C32 = (float*)C;
                    float mv = (float)mask[r];
                    C32[idx] = (C32[idx] + acc[mf][nf][i]) * mv;
                } else {
                    const float* C32 = (const float*)C;
                    float mv = (float)mask[r];
                    float v = (C32[idx] + acc[mf][nf][i]) * mv;
                    if (fl) ((float*)out)[idx] = v;
                    else    ((unsigned short*)out)[idx] = f2b(v);
                    if ((r & (L_ - 1)) == 0) {
                        size_t oidx = (size_t)M_ * D_ + (size_t)(r >> 11) * D_ + c;
                        if (fl) ((float*)out)[oidx] = v;
                        else    ((unsigned short*)out)[oidx] = f2b(v);
                    }
                }
            }
        }
    }
}

// ---------- split-K f32 GEMM (GEMM2, N=64); A in bf16 ----------
#define BM 64
#define BN 64
#define BK 16
#define KS 8
__global__ __launch_bounds__(256) void gemm_nt_sk(const unsigned short* __restrict__ A,
                                                  const float* __restrict__ W,
                                                  float* __restrict__ part,
                                                  int M, int N, int K) {
    __shared__ float Asm[BK][BM + 4];
    __shared__ float Wsm[BK][BN + 4];
    int tid = threadIdx.x;
    int ks = blockIdx.x;
    int m0 = blockIdx.y * BM;
    int kb = ks * (K / KS);
    int ke = kb + (K / KS);
    int tx = tid & 15;
    int ty = tid >> 4;
    int lr = tid >> 2;
    int lk = (tid & 3) * 4;
    float acc[4][4] = {};
    for (int k0 = kb; k0 < ke; k0 += BK) {
        ushort4 av = *(const ushort4*)(A + (size_t)(m0 + lr) * K + k0 + lk);
        Asm[lk + 0][lr] = b2f(av.x); Asm[lk + 1][lr] = b2f(av.y);
        Asm[lk + 2][lr] = b2f(av.z); Asm[lk + 3][lr] = b2f(av.w);
        float4 wv = *(const float4*)(W + (size_t)lr * K + k0 + lk);
        Wsm[lk + 0][lr] = wv.x; Wsm[lk + 1][lr] = wv.y;
        Wsm[lk + 2][lr] = wv.z; Wsm[lk + 3][lr] = wv.w;
        __syncthreads();
#pragma unroll
        for (int kk = 0; kk < BK; ++kk) {
            float4 a = *(const float4*)&Asm[kk][ty * 4];
            float4 w = *(const float4*)&Wsm[kk][tx * 4];
            acc[0][0] += a.x * w.x; acc[0][1] += a.x * w.y; acc[0][2] += a.x * w.z; acc[0][3] += a.x * w.w;
            acc[1][0] += a.y * w.x; acc[1][1] += a.y * w.y; acc[1][2] += a.y * w.z; acc[1][3] += a.y * w.w;
            acc[2][0] += a.z * w.x; acc[2][1] += a.z * w.y; acc[2][2] += a.z * w.z; acc[2][3] += a.z * w.w;
            acc[3][0] += a.w * w.x; acc[3][1] += a.w * w.y; acc[3][2] += a.w * w.z; acc[3][3] += a.w * w.w;
        }
        __syncthreads();
    }
    float* p = part + (size_t)ks * M * N;
#pragma unroll
    for (int i = 0; i < 4; ++i) {
        int m = m0 + ty * 4 + i;
#pragma unroll
        for (int j = 0; j < 4; ++j) {
            int n = tx * 4 + j;
            p[(size_t)m * N + n] = acc[i][j];
        }
    }
}

__global__ void k_red8(const float* __restrict__ part, float* __restrict__ dbc, int mn4) {
    int i = blockIdx.x * 256 + threadIdx.x;
    if (i >= mn4) return;
    float4 s = ((const float4*)part)[i];
#pragma unroll
    for (int ks = 1; ks < KS; ++ks) {
        float4 v = ((const float4*)(part + (size_t)ks * mn4 * 4))[i];
        s.x += v.x; s.y += v.y; s.z += v.z; s.w += v.w;
    }
    ((float4*)dbc)[i] = s;
}

// ---------- depthwise causal conv (K=4) + bias + SiLU; xz in bf16 ----------
// 2-wide over e: ushort2 reads (4B/lane); OUTPUT bf16 (halves write + all
// downstream xc reads: gemm2, scan_a, scan_c -- ~67 MB/layer saved).
__global__ __launch_bounds__(256) void k_conv(const unsigned short* __restrict__ xzb,
                                              const float* __restrict__ cw,
                                              const float* __restrict__ cb,
                                              unsigned short* __restrict__ xcb) {
    int idx = blockIdx.x * 256 + threadIdx.x;      // 0 .. M_*ED_/2
    int e2 = idx & (ED_ / 2 - 1);
    int e  = e2 * 2;
    int bl = idx >> 9;
    int l  = bl & (L_ - 1);
    float acc0 = cb[e], acc1 = cb[e + 1];
    const unsigned short* col = xzb + (size_t)bl * (2 * ED_) + e;
    float4 wa = *(const float4*)(cw + e * 4);
    float4 wb = *(const float4*)(cw + e * 4 + 4);
    ushort2 v3 = *(const ushort2*)(col);
    if (l >= 3) {
        ushort2 v0 = *(const ushort2*)(col - 3 * 2 * ED_);
        ushort2 v1 = *(const ushort2*)(col - 2 * 2 * ED_);
        ushort2 v2 = *(const ushort2*)(col - 1 * 2 * ED_);
        acc0 += wa.x * b2f(v0.x) + wa.y * b2f(v1.x) + wa.z * b2f(v2.x) + wa.w * b2f(v3.x);
        acc1 += wb.x * b2f(v0.y) + wb.y * b2f(v1.y) + wb.z * b2f(v2.y) + wb.w * b2f(v3.y);
    } else {
        if (l >= 2) {
            ushort2 v1 = *(const ushort2*)(col - 2 * 2 * ED_);
            acc0 += wa.y * b2f(v1.x); acc1 += wb.y * b2f(v1.y);
        }
        if (l >= 1) {
            ushort2 v2 = *(const ushort2*)(col - 1 * 2 * ED_);
            acc0 += wa.z * b2f(v2.x); acc1 += wb.z * b2f(v2.y);
        }
        acc0 += wa.w * b2f(v3.x); acc1 += wb.w * b2f(v3.y);
    }
    ushort2 o;
    o.x = f2b(silu(acc0));
    o.y = f2b(silu(acc1));
    *(ushort2*)(xcb + (size_t)bl * ED_ + e) = o;
}

// ---------- chunked selective scan ----------
// NC_=128 (occupancy regime) + k_prep coalesced prologue + [n][c][b*ED+e]
// coalesced hl/carry layout. xc consumed as bf16. scan_a stores h_local +
// sumd; scan_b rebuilds pa = exp2(sumd*A_n); scan_c recomputes delta with
// the identical packed-dot op order.
__global__ __launch_bounds__(256) void k_scan_a(const unsigned short* __restrict__ xcb,
                                                const float* __restrict__ dbc,
                                                const float* __restrict__ wt,
                                                const float* __restrict__ dtb,
                                                const float* __restrict__ A0s,
                                                const int* __restrict__ structf,
                                                const float* __restrict__ A_log,
                                                float* __restrict__ sumdbuf,
                                                float* __restrict__ hl) {
    int b = blockIdx.z, c = blockIdx.y;
    int e = blockIdx.x * 256 + threadIdx.x;
    __shared__ float sRow[T_][64];
    size_t t0 = (size_t)b * L_ + (size_t)c * T_;
    {
        const float4* src = (const float4*)(dbc + t0 * 64);
        float4* dst = (float4*)&sRow[0][0];
#pragma unroll
        for (int i = 0; i < T_ * 16; i += 256)
            dst[i + threadIdx.x] = src[i + threadIdx.x];
    }
    __syncthreads();
    floatv2 w2[R_ / 2];
    {
        const float4* wtp = (const float4*)wt;
#pragma unroll
        for (int i = 0; i < 8; ++i) {
            float4 v = wtp[(size_t)i * ED_ + e];              // coalesced
            w2[2 * i]     = (floatv2){v.x, v.y};
            w2[2 * i + 1] = (floatv2){v.z, v.w};
        }
    }
    float bias = dtb[e];
    float A0 = A0s[e];
    bool structured = structf[e] != 0;
    floatv2 h2[8];
#pragma unroll
    for (int i = 0; i < 8; ++i) h2[i] = (floatv2){0.f, 0.f};
    float sumd = 0.f;
    if (structured) {
        const unsigned short* xp = xcb + t0 * ED_ + e;
        float xv_t = b2f(*xp); xp += ED_;
        for (int t = 0; t < T_; ++t) {
            unsigned short xr = (t + 1 < T_) ? *xp : (unsigned short)0; xp += ED_;  // prefetch
            const floatv2* dt2 = (const floatv2*)&sRow[t][0];
            floatv2 q0 = {0.f, 0.f}, q1 = {0.f, 0.f}, q2 = {0.f, 0.f}, q3 = {0.f, 0.f};
#pragma unroll
            for (int r = 0; r < R_ / 2; r += 4) {
                q0 += dt2[r + 0] * w2[r + 0];
                q1 += dt2[r + 1] * w2[r + 1];
                q2 += dt2[r + 2] * w2[r + 2];
                q3 += dt2[r + 3] * w2[r + 3];
            }
            floatv2 qs = (q0 + q1) + (q2 + q3);
            float d = softplusf(qs.x + qs.y + bias);
            float dx = d * xv_t;
            sumd += d;
            floatv2 pw[8];
            pow_tree2(exp2f(d * A0), pw);
            const floatv2* bb2 = (const floatv2*)&sRow[t][32];
#pragma unroll
            for (int i = 0; i < 8; ++i)
                h2[i] = pw[i] * h2[i] + dx * bb2[i];
            xv_t = b2f(xr);
        }
    } else {
        float A[N_];
        float* h = (float*)h2;
#pragma unroll
        for (int n = 0; n < N_; ++n) A[n] = -exp2f(LOG2E * A_log[e * N_ + n]) * LOG2E;
        float* wsc = (float*)w2;
        for (int t = 0; t < T_; ++t) {
            size_t bl = t0 + t;
            float p0 = bias, p1 = 0.f, p2 = 0.f, p3 = 0.f;
#pragma unroll
            for (int r = 0; r < R_; r += 4) {
                p0 += sRow[t][r + 0] * wsc[r + 0];
                p1 += sRow[t][r + 1] * wsc[r + 1];
                p2 += sRow[t][r + 2] * wsc[r + 2];
                p3 += sRow[t][r + 3] * wsc[r + 3];
            }
            float d = softplusf((p0 + p1) + (p2 + p3));
            float dx = d * b2f(xcb[bl * ED_ + e]);
            sumd += d;
#pragma unroll
            for (int n = 0; n < N_; ++n) {
                float a = exp2f(d * A[n]);
                h[n] = a * h[n] + dx * sRow[t][32 + n];
            }
        }
    }
    size_t base = (size_t)c * BE_ + (size_t)b * ED_ + e;
    const float* h = (const float*)h2;
#pragma unroll
    for (int n = 0; n < N_; ++n)
        hl[(size_t)n * (NC_ * BE_) + base] = h[n];              // coalesced streams
    sumdbuf[base] = sumd;
}

// carry recurrence over chunks; pa reconstructed as exp2(sumd*A_n).
// thread -> (n, be): all hl/carry/sumd accesses coalesced.
// 8-deep prefetch ring (fully unrolled -> static reg indices).
__global__ __launch_bounds__(256) void k_scan_b(const float* __restrict__ sumd,
                                                const float* __restrict__ hl,
                                                const float* __restrict__ A_log,
                                                float* __restrict__ carry) {
    int s = blockIdx.x * 256 + threadIdx.x;     // 0..S_-1
    int n  = s >> 12;                           // S_/N_ = 4096 = BE_
    int be = s & (BE_ - 1);
    int e  = be & (ED_ - 1);
    float An = -exp2f(LOG2E * A_log[e * N_ + n]) * LOG2E;
    const float* hln = hl    + (size_t)n * (NC_ * BE_);
    float*       crn = carry + (size_t)n * (NC_ * BE_);
    float sdr[8], hlr[8];
#pragma unroll
    for (int c = 0; c < 8; ++c) {
        sdr[c] = sumd[(size_t)c * BE_ + be];
        hlr[c] = hln[(size_t)c * BE_ + be];
    }
    float h = 0.f;
#pragma unroll
    for (int c = 0; c < NC_; ++c) {
        int r = c & 7;
        crn[(size_t)c * BE_ + be] = h;
        float p = exp2f(sdr[r] * An), q = hlr[r];
        if (c + 8 < NC_) {
            sdr[r] = sumd[(size_t)(c + 8) * BE_ + be];
            hlr[r] = hln[(size_t)(c + 8) * BE_ + be];
        }
        h = p * h + q;
    }
}

__global__ __launch_bounds__(256) void k_scan_c(const unsigned short* __restrict__ xcb,
                                                const float* __restrict__ dbc,
                                                const unsigned short* __restrict__ xzb,
                                                const float* __restrict__ wt,
                                                const float* __restrict__ dtb,
                                                const float* __restrict__ A0s,
                                                const int* __restrict__ structf,
                                                const float* __restrict__ A_log,
                                                const float* __restrict__ Dp,
                                                const float* __restrict__ carry,
                                                unsigned short* __restrict__ ybf) {
    int b = blockIdx.z, c = blockIdx.y;
    int e = blockIdx.x * 256 + threadIdx.x;
    __shared__ float sRow[T_][64];
    size_t t0 = (size_t)b * L_ + (size_t)c * T_;
    {
        const float4* src = (const float4*)(dbc + t0 * 64);
        float4* dst = (float4*)&sRow[0][0];
#pragma unroll
        for (int i = 0; i < T_ * 16; i += 256)
            dst[i + threadIdx.x] = src[i + threadIdx.x];
    }
    __syncthreads();
    floatv2 w2[R_ / 2];
    {
        const float4* wtp = (const float4*)wt;
#pragma unroll
        for (int i = 0; i < 8; ++i) {
            float4 v = wtp[(size_t)i * ED_ + e];              // coalesced
            w2[2 * i]     = (floatv2){v.x, v.y};
            w2[2 * i + 1] = (floatv2){v.z, v.w};
        }
    }
    float bias = dtb[e];
    float A0 = A0s[e];
    bool structured = structf[e] != 0;
    floatv2 h2[8];
    size_t base = (size_t)c * BE_ + (size_t)b * ED_ + e;
    {
        float hs[N_];
#pragma unroll
        for (int n = 0; n < N_; ++n)
            hs[n] = carry[(size_t)n * (NC_ * BE_) + base];      // coalesced streams
#pragma unroll
        for (int i = 0; i < 8; ++i) h2[i] = (floatv2){hs[2 * i], hs[2 * i + 1]};
    }
    float Dv = Dp[e];
    if (structured) {
        const unsigned short* xp = xcb + t0 * ED_ + e;
        const unsigned short* zp = xzb + t0 * (2 * ED_) + ED_ + e;
        unsigned short* yp = ybf + t0 * ED_ + e;
        float xv_t = b2f(*xp); xp += ED_;
        unsigned short z_t = *zp; zp += 2 * ED_;
        for (int t = 0; t < T_; ++t) {
            unsigned short xr = 0, z_n = 0;
            if (t + 1 < T_) {                       // prefetch next step
                xr  = *xp;
                z_n = *zp;
            }
            xp += ED_; zp += 2 * ED_;
            // recompute delta (same packed op order as scan_a)
            const floatv2* dt2 = (const floatv2*)&sRow[t][0];
            floatv2 q0 = {0.f, 0.f}, q1 = {0.f, 0.f}, q2 = {0.f, 0.f}, q3 = {0.f, 0.f};
#pragma unroll
            for (int r = 0; r < R_ / 2; r += 4) {
                q0 += dt2[r + 0] * w2[r + 0];
                q1 += dt2[r + 1] * w2[r + 1];
                q2 += dt2[r + 2] * w2[r + 2];
                q3 += dt2[r + 3] * w2[r + 3];
            }
            floatv2 qs = (q0 + q1) + (q2 + q3);
            float d_t = softplusf(qs.x + qs.y + bias);
            float dx = d_t * xv_t;
            floatv2 pw[8];
            pow_tree2(exp2f(d_t * A0), pw);
            const floatv2* bb2 = (const floatv2*)&sRow[t][32];
            const floatv2* cc2 = (const floatv2*)&sRow[t][48];
            floatv2 y0 = {0.f, 0.f}, y1 = {0.f, 0.f};
#pragma unroll
            for (int i = 0; i < 8; i += 2) {
                h2[i + 0] = pw[i + 0] * h2[i + 0] + dx * bb2[i + 0];
                h2[i + 1] = pw[i + 1] * h2[i + 1] + dx * bb2[i + 1];
                y0 += h2[i + 0] * cc2[i + 0];
                y1 += h2[i + 1] * cc2[i + 1];
            }
            floatv2 ys = y0 + y1;
            float y = ys.x + ys.y;
            float z = b2f(z_t);
            *yp = f2b((y + Dv * xv_t) * silu(z)); yp += ED_;
            xv_t = b2f(xr); z_t = z_n;
        }
    } else {
        float A[N_];
        float* h = (float*)h2;
#pragma unroll
        for (int n = 0; n < N_; ++n) A[n] = -exp2f(LOG2E * A_log[e * N_ + n]) * LOG2E;
        float* wsc = (float*)w2;
        for (int t = 0; t < T_; ++t) {
            size_t bl = t0 + t;
            float p0 = bias, p1 = 0.f, p2 = 0.f, p3 = 0.f;
#pragma unroll
            for (int r = 0; r < R_; r += 4) {
                p0 += sRow[t][r + 0] * wsc[r + 0];
                p1 += sRow[t][r + 1] * wsc[r + 1];
                p2 += sRow[t][r + 2] * wsc[r + 2];
                p3 += sRow[t][r + 3] * wsc[r + 3];
            }
            float d = softplusf((p0 + p1) + (p2 + p3));
            float xv = b2f(xcb[bl * ED_ + e]);
            float dx = d * xv;
            float y = 0.f;
#pragma unroll
            for (int n = 0; n < N_; ++n) {
                float a = exp2f(d * A[n]);
                h[n] = a * h[n] + dx * sRow[t][32 + n];
                y += h[n] * sRow[t][48 + n];
            }
            float z = b2f(xzb[bl * (2 * ED_) + ED_ + e]);
            ybf[bl * ED_ + e] = f2b((y + Dv * xv) * silu(z));
        }
    }
}

extern "C" void kernel_launch(void* const* d_in, const int* in_sizes, int n_in,
                              void* d_out, int out_size, void* d_ws, size_t ws_size,
                              hipStream_t stream) {
    const int* mask = (const int*)d_in[1];

    // workspace layout (~160 MB < proven budget; xcb uses half the old xc region)
    float* ws = (float*)d_ws;
    int*   flag = (int*)d_ws;
    float* xw   = ws + 16;                          // M_*D_         4,194,304
    float* wn   = xw   + (size_t)M_ * D_;           // 1,024
    float* wc   = wn   + 1024;                      // 8,192
    float* wcb  = wc   + 8192;                      // 2,048
    float* wx   = wcb  + 2048;                      // 131,072
    float* wdt  = wx   + 131072;                    // 65,536
    float* wdtb = wdt  + 65536;                     // 2,048
    float* wal  = wdtb + 2048;                      // 32,768
    float* wdp  = wal  + 32768;                     // 2,048
    unsigned short* wib = (unsigned short*)(wdp + 2048);      // 2,097,152 ushorts
    unsigned short* wob = wib + 2097152;                      // 1,048,576 ushorts
    unsigned short* ubf = wob + 1048576;                      // 4,194,304 ushorts
    unsigned short* xzb = ubf + (size_t)M_ * D_;              // 16,777,216 ushorts
    unsigned short* xcb = xzb + (size_t)M_ * 2 * ED_;         // 8,388,608 ushorts (bf16 xc)
    float* dbc  = (float*)(xcb + (size_t)M_ * ED_);  // 524,288
    float* hl   = dbc   + (size_t)M_ * 64;          // NC_*S_ = 8,388,608
    float* carry= hl    + (size_t)NC_ * S_;         // 8,388,608
    float* sumd = carry + (size_t)NC_ * S_;         // NC_*BE_ = 524,288
    float* wT   = sumd  + (size_t)NC_ * BE_;        // 2*R_*ED_ = 65,536
    float* A0s  = wT    + 2 * R_ * ED_;             // 2*ED_ = 2,048
    int*   stfl = (int*)(A0s + 2 * ED_);            // 2*ED_ = 2,048
    unsigned short* ybf = (unsigned short*)hl;      // alias: hl dead after scan_b
    float* part = carry;   // KS*M_*64 = 4,194,304 floats; carry dead until scan_b

    k_flag0<<<1, 1, 0, stream>>>(flag);
    k_detect<<<128, 256, 0, stream>>>((const unsigned short*)d_in[0], flag);

    {
        Seg9 segs;
        int idxs[9] = {0, 2, 4, 5, 6, 7, 8, 9, 10};
        int pre = 0;
        for (int i = 0; i < 9; ++i) {
            segs.src[i] = d_in[idxs[i]];
            segs.prefix[i] = pre;
            pre += in_sizes[idxs[i]];
        }
        segs.prefix[9] = pre;
        k_cvt_batch<<<(pre + 255) / 256, 256, 0, stream>>>(segs, xw, pre, flag);
        int n0 = 2 * 2 * ED_ * D_;
        int tot = n0 + 2 * D_ * ED_;
        k_cvt_bf_batch<<<(tot + 255) / 256, 256, 0, stream>>>(d_in[3], d_in[11], wib, n0, tot, flag);
    }
    k_prep<<<(2 * ED_) / 256, 256, 0, stream>>>(wdt, wal, wT, A0s, stfl);

    for (int layer = 0; layer < 2; ++layer) {
        const float* nw = wn  + layer * D_;
        const unsigned short* iw = wib + (size_t)layer * 2 * ED_ * D_;
        const float* cw = wc  + layer * ED_ * KC_;
        const float* cb = wcb + layer * ED_;
        const float* xwp= wx  + (size_t)layer * 64 * ED_;
        const float* db = wdtb+ layer * ED_;
        const float* al = wal + layer * ED_ * N_;
        const float* dp = wdp + layer * ED_;
        const float* wtl= wT  + (size_t)layer * R_ * ED_;
        const float* a0l= A0s + layer * ED_;
        const int*   sfl= stfl+ layer * ED_;
        const unsigned short* ow = wob + (size_t)layer * D_ * ED_;

        k_rmsnorm<<<M_, 128, 0, stream>>>(xw, mask, nw, ubf);
        gemm_bt<1, 128><<<dim3(2 * ED_ / 128, M_ / 128), 256, 0, stream>>>(ubf, iw, xzb, nullptr, nullptr, nullptr, M_, 2 * ED_, D_);
        k_conv<<<(M_ * ED_ / 2) / 256, 256, 0, stream>>>(xzb, cw, cb, xcb);
        gemm_nt_sk<<<dim3(KS, M_ / BM), 256, 0, stream>>>(xcb, xwp, part, M_, 64, ED_);
        k_red8<<<(M_ * 64 / 4 + 255) / 256, 256, 0, stream>>>(part, dbc, M_ * 64 / 4);
        k_scan_a<<<dim3(ED_ / 256, NC_, B_), 256, 0, stream>>>(xcb, dbc, wtl, db, a0l, sfl, al, sumd, hl);
        k_scan_b<<<S_ / 256, 256, 0, stream>>>(sumd, hl, al, carry);
        k_scan_c<<<dim3(ED_ / 256, NC_, B_), 256, 0, stream>>>(xcb, dbc, xzb, wtl, db, a0l, sfl, al, dp, carry, ybf);
        if (layer == 0) {
            gemm_bt<2, 64><<<dim3(D_ / 64, M_ / 128), 256, 0, stream>>>(ybf, ow, xw, mask, nullptr, nullptr, M_, D_, ED_);
        } else {
            gemm_bt<3, 64><<<dim3(D_ / 64, M_ / 128), 256, 0, stream>>>(ybf, ow, xw, mask, flag, d_out, M_, D_, ED_);
        }
    }
}

// Round 13
// 485.729 us; speedup vs baseline: 1.1190x; 1.0344x over previous
//
#include <hip/hip_runtime.h>
#include <math.h>

#define B_ 4
#define L_ 2048
#define D_ 512
#define ED_ 1024
#define N_ 16
#define R_ 32
#define KC_ 4
#define M_ (B_*L_)   // 8192 rows
#define NC_ 128      // scan chunks (8 blocks/CU occupancy regime)
#define T_  (L_/NC_) // 16 steps per chunk
#define S_  (B_*ED_*N_)  // 65536 scan series
#define BE_ (B_*ED_)     // 4096
#define LOG2E 1.44269504f
#define LN2   0.69314718f

typedef __attribute__((ext_vector_type(8))) short short8;
typedef __attribute__((ext_vector_type(4))) float floatx4;
typedef __attribute__((ext_vector_type(2))) float floatv2;   // -> v_pk_*_f32

static __device__ __forceinline__ float b2f(unsigned short u) {
    unsigned int v = ((unsigned int)u) << 16;
    float f;
    __builtin_memcpy(&f, &v, 4);
    return f;
}
static __device__ __forceinline__ unsigned short f2b(float f) {
    unsigned int u;
    __builtin_memcpy(&u, &f, 4);
    unsigned int lsb = (u >> 16) & 1u;
    u += 0x7fffu + lsb;                 // round-to-nearest-even
    return (unsigned short)(u >> 16);
}
static __device__ __forceinline__ float silu(float x) {
    return x / (1.f + exp2f(-LOG2E * x));
}
static __device__ __forceinline__ float softplusf(float x) {
    return fmaxf(x, 0.f) + LN2 * log2f(1.f + exp2f(-LOG2E * fabsf(x)));
}
// pw[i] = {a^(2i+1), a^(2i+2)} via packed tree (depth 4)
static __device__ __forceinline__ void pow_tree2(float a1, floatv2* pw) {
    float a2 = a1 * a1, a4 = a2 * a2, a8 = a4 * a4;
    pw[0] = (floatv2){a1, a2};
    pw[1] = pw[0] * a2;
    pw[2] = pw[0] * a4;
    pw[3] = pw[1] * a4;
    pw[4] = pw[0] * a8;
    pw[5] = pw[1] * a8;
    pw[6] = pw[2] * a8;
    pw[7] = pw[3] * a8;
}

// ---------- dtype detection ----------
__global__ void k_flag0(int* flag) {
    if (blockIdx.x == 0 && threadIdx.x == 0) *flag = 0;
}
__global__ void k_detect(const unsigned short* __restrict__ x, int* flag) {
    int i = blockIdx.x * 256 + threadIdx.x;
    unsigned int e = (x[i] >> 7) & 0xFF;
    unsigned long long m = __ballot(e >= 0x88);
    if ((threadIdx.x & 63) == 0 && m != 0ull) atomicOr(flag, 1);
}

// ---------- batched conversions ----------
struct Seg9 { const void* src[9]; int prefix[10]; };
__global__ void k_cvt_batch(Seg9 segs, float* __restrict__ dst, int total,
                            const int* __restrict__ flag) {
    int i = blockIdx.x * 256 + threadIdx.x;
    if (i >= total) return;
    int s = 0;
#pragma unroll
    for (int k = 1; k < 9; ++k) if (i >= segs.prefix[k]) s = k;
    int off = i - segs.prefix[s];
    if (*flag) dst[i] = ((const float*)segs.src[s])[off];
    else       dst[i] = b2f(((const unsigned short*)segs.src[s])[off]);
}
__global__ void k_cvt_bf_batch(const void* __restrict__ src0,
                               const void* __restrict__ src1,
                               unsigned short* __restrict__ dst,
                               int n0, int total, const int* __restrict__ flag) {
    int i = blockIdx.x * 256 + threadIdx.x;
    if (i >= total) return;
    const void* src = (i < n0) ? src0 : src1;
    int off = (i < n0) ? i : i - n0;
    if (*flag) dst[i] = f2b(((const float*)src)[off]);
    else       dst[i] = ((const unsigned short*)src)[off];
}

// ---------- scan prep (once): transpose dtw to coalesced layout, A0, flag ----
// wT layout per layer: [R/4][ED][4] floats = float4 index (r4*ED + e).
__global__ void k_prep(const float* __restrict__ wdt,
                       const float* __restrict__ A_log,
                       float* __restrict__ wT,
                       float* __restrict__ A0s,
                       int* __restrict__ structf) {
    int idx = blockIdx.x * 256 + threadIdx.x;       // 0 .. 2*ED_-1
    int layer = idx >> 10, e = idx & (ED_ - 1);
    const float* src = wdt + (size_t)idx * R_;
    float* dstb = wT + (size_t)layer * (R_ * ED_);
#pragma unroll
    for (int r = 0; r < R_; ++r)
        dstb[(r >> 2) * (ED_ * 4) + e * 4 + (r & 3)] = src[r];
    float A0 = -exp2f(LOG2E * A_log[(size_t)idx * N_]) * LOG2E;
    bool st = true;
#pragma unroll
    for (int n = 1; n < N_; ++n) {
        float An = -exp2f(LOG2E * A_log[(size_t)idx * N_ + n]) * LOG2E;
        st = st && (fabsf(An - (n + 1) * A0) <= 1e-4f * fabsf(An));
    }
    A0s[idx] = A0;
    structf[idx] = st ? 1 : 0;
}

// ---------- rmsnorm with mask; writes u (bf16). 2 rows/block.
// xw write-back removed: MODE2/3 epilogue's (xw+acc)*mv applies the mask
// (m in {0,1} => (x+d)*m == x*m + d*m), so masking xw here is redundant.
__global__ __launch_bounds__(256) void k_rmsnorm(const float* __restrict__ x,
                                                 const int* __restrict__ mask,
                                                 const float* __restrict__ w,
                                                 unsigned short* __restrict__ ubf) {
    int tid = threadIdx.x;
    int row = blockIdx.x * 2 + (tid >> 7);
    int t128 = tid & 127;
    size_t base = (size_t)row * D_ + t128 * 4;
    float4 v = *(const float4*)(x + base);
    float mv = (float)mask[row];
    v.x *= mv; v.y *= mv; v.z *= mv; v.w *= mv;
    float ss = v.x*v.x + v.y*v.y + v.z*v.z + v.w*v.w;
#pragma unroll
    for (int o = 1; o < 64; o <<= 1) ss += __shfl_xor(ss, o, 64);
    __shared__ float sred[4];
    if ((tid & 63) == 0) sred[tid >> 6] = ss;
    __syncthreads();
    int g = tid >> 7;
    float rs = rsqrtf((sred[2 * g] + sred[2 * g + 1]) / (float)D_ + 1e-5f);
    float4 wv = *(const float4*)(w + t128 * 4);
    ushort4 b4;
    b4.x = f2b(v.x * rs * wv.x);
    b4.y = f2b(v.y * rs * wv.y);
    b4.z = f2b(v.z * rs * wv.z);
    b4.w = f2b(v.w * rs * wv.w);
    *(ushort4*)(ubf + base) = b4;
}

// ---------- bf16 MFMA GEMM: out = A[M,K] * W[N,K]^T ----------
// 3-buffer rotation, depth-2 prefetch, counted vmcnt (T3+T4). One raw
// s_barrier per K-step; lgkmcnt(0) before barrier closes the read-reuse race.
// XCD-aware bijective block swizzle (grid % 8 == 0 for all call sites).
// MODE 1: write bf16. MODE 2: C=xw RMW + mask. MODE 3: like 2 but writes the
// final output buffer (dtype by flag) + the x[:,0,:] slice; xw not written.
typedef __attribute__((address_space(1))) const unsigned int guint;
typedef __attribute__((address_space(3))) unsigned int luint;
#define GLL(gp, lp) __builtin_amdgcn_global_load_lds((guint*)(const void*)(gp), (luint*)(void*)(lp), 16, 0, 0)

template<int N> static __device__ __forceinline__ void waitv() {
    if constexpr (N == 0) asm volatile("s_waitcnt vmcnt(0)" ::: "memory");
    else if constexpr (N == 3) asm volatile("s_waitcnt vmcnt(3)" ::: "memory");
    else if constexpr (N == 4) asm volatile("s_waitcnt vmcnt(4)" ::: "memory");
}

template<int MODE, int BNT>
__global__ __launch_bounds__(256) void gemm_bt(const unsigned short* __restrict__ A,
                                               const unsigned short* __restrict__ W,
                                               void* __restrict__ C,
                                               const int* __restrict__ mask,
                                               const int* __restrict__ flag,
                                               void* __restrict__ out,
                                               int M, int N, int K) {
    constexpr int NF = BNT / 32;                 // n-frags per wave: 128->4, 64->2
    constexpr int LW = 2 + BNT / 64;             // GLL issues per wave per stage: 4 or 3
    __shared__ unsigned short As[3][128][32];
    __shared__ unsigned short Bs[3][BNT][32];
    int tid  = threadIdx.x;
    int wave = tid >> 6;
    int lane = tid & 63;
    // XCD-aware bijective swizzle (nwg multiple of 8)
    int nwg = gridDim.x * gridDim.y;
    int id  = blockIdx.y * gridDim.x + blockIdx.x;
    int swz = (id & 7) * (nwg >> 3) + (id >> 3);
    int m0 = (swz / gridDim.x) * 128;
    int n0 = (swz % gridDim.x) * BNT;
    int wm = (wave & 1) * 64;
    int wn = (wave >> 1) * (BNT / 2);
    int quad = lane >> 4;
    int l16  = lane & 15;
    int crd = (quad ^ ((l16 >> 1) & 3)) * 8;       // swizzled fragment-read position

    int rA0 = wave * 16 + (lane >> 2);             // rows 0..63; +64 for second issue
    int cA  = ((lane & 3) ^ ((rA0 >> 1) & 3)) * 8;

    floatx4 acc[4][NF] = {};

    auto stage = [&](int buf, int k0) {
        const unsigned short* gA0 = A + (size_t)(m0 + rA0) * K + k0 + cA;
        GLL(gA0,                   &As[buf][wave * 16][0]);
        GLL(gA0 + (size_t)64 * K,  &As[buf][64 + wave * 16][0]);
        const unsigned short* gB0 = W + (size_t)(n0 + rA0) * K + k0 + cA;
        GLL(gB0,                   &Bs[buf][wave * 16][0]);
        if constexpr (BNT == 128)
            GLL(gB0 + (size_t)64 * K, &Bs[buf][64 + wave * 16][0]);
    };

    int nk = K / 32;                               // >= 2 always here
    stage(0, 0);
    stage(1, 32);

    int cur = 0;
    for (int t = 0; t < nk; ++t) {
        if (t + 1 < nk) waitv<LW>();               // stage t landed; t+1 stays in flight
        else            waitv<0>();
        asm volatile("s_barrier" ::: "memory");    // collective: buf cur fully written,
                                                   // and all reads of buf (cur+2)%3 done
        if (t + 2 < nk) {
            int bw = cur + 2; if (bw >= 3) bw -= 3;
            stage(bw, (t + 2) * 32);
        }
        short8 af[4], bfr[NF];
#pragma unroll
        for (int f = 0; f < 4; ++f)
            af[f]  = *(const short8*)&As[cur][wm + f * 16 + l16][crd];
#pragma unroll
        for (int f = 0; f < NF; ++f)
            bfr[f] = *(const short8*)&Bs[cur][wn + f * 16 + l16][crd];
#pragma unroll
        for (int mf = 0; mf < 4; ++mf)
#pragma unroll
            for (int nf = 0; nf < NF; ++nf)
                acc[mf][nf] = __builtin_amdgcn_mfma_f32_16x16x32_bf16(af[mf], bfr[nf], acc[mf][nf], 0, 0, 0);
        asm volatile("s_waitcnt lgkmcnt(0)" ::: "memory");  // reads of buf cur complete
        cur = (cur == 2) ? 0 : cur + 1;
    }

    int fl = (MODE == 3) ? *flag : 0;
#pragma unroll
    for (int mf = 0; mf < 4; ++mf) {
#pragma unroll
        for (int nf = 0; nf < NF; ++nf) {
#pragma unroll
            for (int i = 0; i < 4; ++i) {
                int r = m0 + wm + mf * 16 + quad * 4 + i;   // C/D: row=quad*4+reg
                int c = n0 + wn + nf * 16 + l16;            //      col=lane&15
                size_t idx = (size_t)r * N + c;
                if (MODE == 1) {
                    ((unsigned short*)C)[idx] = f2b(acc[mf][nf][i]);
                } else if (MODE == 2) {
                    float* C32 = (float*)C;
                    float mv = (float)mask[r];
                    C32[idx] = (C32[idx] + acc[mf][nf][i]) * mv;
                } else {
                    const float* C32 = (const float*)C;
                    float mv = (float)mask[r];
                    float v = (C32[idx] + acc[mf][nf][i]) * mv;
                    if (fl) ((float*)out)[idx] = v;
                    else    ((unsigned short*)out)[idx] = f2b(v);
                    if ((r & (L_ - 1)) == 0) {
                        size_t oidx = (size_t)M_ * D_ + (size_t)(r >> 11) * D_ + c;
                        if (fl) ((float*)out)[oidx] = v;
                        else    ((unsigned short*)out)[oidx] = f2b(v);
                    }
                }
            }
        }
    }
}

// ---------- split-K f32 GEMM (GEMM2, N=64); A in bf16 ----------
#define BM 64
#define BN 64
#define BK 16
#define KS 8
__global__ __launch_bounds__(256) void gemm_nt_sk(const unsigned short* __restrict__ A,
                                                  const float* __restrict__ W,
                                                  float* __restrict__ part,
                                                  int M, int N, int K) {
    __shared__ float Asm[BK][BM + 4];
    __shared__ float Wsm[BK][BN + 4];
    int tid = threadIdx.x;
    int ks = blockIdx.x;
    int m0 = blockIdx.y * BM;
    int kb = ks * (K / KS);
    int ke = kb + (K / KS);
    int tx = tid & 15;
    int ty = tid >> 4;
    int lr = tid >> 2;
    int lk = (tid & 3) * 4;
    float acc[4][4] = {};
    for (int k0 = kb; k0 < ke; k0 += BK) {
        ushort4 av = *(const ushort4*)(A + (size_t)(m0 + lr) * K + k0 + lk);
        Asm[lk + 0][lr] = b2f(av.x); Asm[lk + 1][lr] = b2f(av.y);
        Asm[lk + 2][lr] = b2f(av.z); Asm[lk + 3][lr] = b2f(av.w);
        float4 wv = *(const float4*)(W + (size_t)lr * K + k0 + lk);
        Wsm[lk + 0][lr] = wv.x; Wsm[lk + 1][lr] = wv.y;
        Wsm[lk + 2][lr] = wv.z; Wsm[lk + 3][lr] = wv.w;
        __syncthreads();
#pragma unroll
        for (int kk = 0; kk < BK; ++kk) {
            float4 a = *(const float4*)&Asm[kk][ty * 4];
            float4 w = *(const float4*)&Wsm[kk][tx * 4];
            acc[0][0] += a.x * w.x; acc[0][1] += a.x * w.y; acc[0][2] += a.x * w.z; acc[0][3] += a.x * w.w;
            acc[1][0] += a.y * w.x; acc[1][1] += a.y * w.y; acc[1][2] += a.y * w.z; acc[1][3] += a.y * w.w;
            acc[2][0] += a.z * w.x; acc[2][1] += a.z * w.y; acc[2][2] += a.z * w.z; acc[2][3] += a.z * w.w;
            acc[3][0] += a.w * w.x; acc[3][1] += a.w * w.y; acc[3][2] += a.w * w.z; acc[3][3] += a.w * w.w;
        }
        __syncthreads();
    }
    float* p = part + (size_t)ks * M * N;
#pragma unroll
    for (int i = 0; i < 4; ++i) {
        int m = m0 + ty * 4 + i;
#pragma unroll
        for (int j = 0; j < 4; ++j) {
            int n = tx * 4 + j;
            p[(size_t)m * N + n] = acc[i][j];
        }
    }
}

__global__ void k_red8(const float* __restrict__ part, float* __restrict__ dbc, int mn4) {
    int i = blockIdx.x * 256 + threadIdx.x;
    if (i >= mn4) return;
    float4 s = ((const float4*)part)[i];
#pragma unroll
    for (int ks = 1; ks < KS; ++ks) {
        float4 v = ((const float4*)(part + (size_t)ks * mn4 * 4))[i];
        s.x += v.x; s.y += v.y; s.z += v.z; s.w += v.w;
    }
    ((float4*)dbc)[i] = s;
}

// ---------- depthwise causal conv (K=4) + bias + SiLU; xz in bf16 ----------
// 2-wide over e: ushort2 reads (4B/lane); OUTPUT bf16.
__global__ __launch_bounds__(256) void k_conv(const unsigned short* __restrict__ xzb,
                                              const float* __restrict__ cw,
                                              const float* __restrict__ cb,
                                              unsigned short* __restrict__ xcb) {
    int idx = blockIdx.x * 256 + threadIdx.x;      // 0 .. M_*ED_/2
    int e2 = idx & (ED_ / 2 - 1);
    int e  = e2 * 2;
    int bl = idx >> 9;
    int l  = bl & (L_ - 1);
    float acc0 = cb[e], acc1 = cb[e + 1];
    const unsigned short* col = xzb + (size_t)bl * (2 * ED_) + e;
    float4 wa = *(const float4*)(cw + e * 4);
    float4 wb = *(const float4*)(cw + e * 4 + 4);
    ushort2 v3 = *(const ushort2*)(col);
    if (l >= 3) {
        ushort2 v0 = *(const ushort2*)(col - 3 * 2 * ED_);
        ushort2 v1 = *(const ushort2*)(col - 2 * 2 * ED_);
        ushort2 v2 = *(const ushort2*)(col - 1 * 2 * ED_);
        acc0 += wa.x * b2f(v0.x) + wa.y * b2f(v1.x) + wa.z * b2f(v2.x) + wa.w * b2f(v3.x);
        acc1 += wb.x * b2f(v0.y) + wb.y * b2f(v1.y) + wb.z * b2f(v2.y) + wb.w * b2f(v3.y);
    } else {
        if (l >= 2) {
            ushort2 v1 = *(const ushort2*)(col - 2 * 2 * ED_);
            acc0 += wa.y * b2f(v1.x); acc1 += wb.y * b2f(v1.y);
        }
        if (l >= 1) {
            ushort2 v2 = *(const ushort2*)(col - 1 * 2 * ED_);
            acc0 += wa.z * b2f(v2.x); acc1 += wb.z * b2f(v2.y);
        }
        acc0 += wa.w * b2f(v3.x); acc1 += wb.w * b2f(v3.y);
    }
    ushort2 o;
    o.x = f2b(silu(acc0));
    o.y = f2b(silu(acc1));
    *(ushort2*)(xcb + (size_t)bl * ED_ + e) = o;
}

// ---------- chunked selective scan ----------
// scan_a computes delta ONCE (packed dot) and stores it f32 (coalesced);
// scan_c reads delta (bitwise-identical to recompute) -- no dot, no wT
// prologue, B/C-half-only LDS staging. hl/carry in coalesced [n][c][be].
__global__ __launch_bounds__(256) void k_scan_a(const unsigned short* __restrict__ xcb,
                                                const float* __restrict__ dbc,
                                                const float* __restrict__ wt,
                                                const float* __restrict__ dtb,
                                                const float* __restrict__ A0s,
                                                const int* __restrict__ structf,
                                                const float* __restrict__ A_log,
                                                float* __restrict__ delta,
                                                float* __restrict__ sumdbuf,
                                                float* __restrict__ hl) {
    int b = blockIdx.z, c = blockIdx.y;
    int e = blockIdx.x * 256 + threadIdx.x;
    __shared__ float sRow[T_][64];
    size_t t0 = (size_t)b * L_ + (size_t)c * T_;
    {
        const float4* src = (const float4*)(dbc + t0 * 64);
        float4* dst = (float4*)&sRow[0][0];
#pragma unroll
        for (int i = 0; i < T_ * 16; i += 256)
            dst[i + threadIdx.x] = src[i + threadIdx.x];
    }
    __syncthreads();
    floatv2 w2[R_ / 2];
    {
        const float4* wtp = (const float4*)wt;
#pragma unroll
        for (int i = 0; i < 8; ++i) {
            float4 v = wtp[(size_t)i * ED_ + e];              // coalesced
            w2[2 * i]     = (floatv2){v.x, v.y};
            w2[2 * i + 1] = (floatv2){v.z, v.w};
        }
    }
    float bias = dtb[e];
    float A0 = A0s[e];
    bool structured = structf[e] != 0;
    floatv2 h2[8];
#pragma unroll
    for (int i = 0; i < 8; ++i) h2[i] = (floatv2){0.f, 0.f};
    float sumd = 0.f;
    if (structured) {
        const unsigned short* xp = xcb + t0 * ED_ + e;
        float* dep = delta + t0 * ED_ + e;
        float xv_t = b2f(*xp); xp += ED_;
        for (int t = 0; t < T_; ++t) {
            unsigned short xr = (t + 1 < T_) ? *xp : (unsigned short)0; xp += ED_;  // prefetch
            const floatv2* dt2 = (const floatv2*)&sRow[t][0];
            floatv2 q0 = {0.f, 0.f}, q1 = {0.f, 0.f}, q2 = {0.f, 0.f}, q3 = {0.f, 0.f};
#pragma unroll
            for (int r = 0; r < R_ / 2; r += 4) {
                q0 += dt2[r + 0] * w2[r + 0];
                q1 += dt2[r + 1] * w2[r + 1];
                q2 += dt2[r + 2] * w2[r + 2];
                q3 += dt2[r + 3] * w2[r + 3];
            }
            floatv2 qs = (q0 + q1) + (q2 + q3);
            float d = softplusf(qs.x + qs.y + bias);
            *dep = d; dep += ED_;                  // coalesced delta store
            float dx = d * xv_t;
            sumd += d;
            floatv2 pw[8];
            pow_tree2(exp2f(d * A0), pw);
            const floatv2* bb2 = (const floatv2*)&sRow[t][32];
#pragma unroll
            for (int i = 0; i < 8; ++i)
                h2[i] = pw[i] * h2[i] + dx * bb2[i];
            xv_t = b2f(xr);
        }
    } else {
        float A[N_];
        float* h = (float*)h2;
#pragma unroll
        for (int n = 0; n < N_; ++n) A[n] = -exp2f(LOG2E * A_log[e * N_ + n]) * LOG2E;
        float* wsc = (float*)w2;
        for (int t = 0; t < T_; ++t) {
            size_t bl = t0 + t;
            float p0 = bias, p1 = 0.f, p2 = 0.f, p3 = 0.f;
#pragma unroll
            for (int r = 0; r < R_; r += 4) {
                p0 += sRow[t][r + 0] * wsc[r + 0];
                p1 += sRow[t][r + 1] * wsc[r + 1];
                p2 += sRow[t][r + 2] * wsc[r + 2];
                p3 += sRow[t][r + 3] * wsc[r + 3];
            }
            float d = softplusf((p0 + p1) + (p2 + p3));
            delta[bl * ED_ + e] = d;
            float dx = d * b2f(xcb[bl * ED_ + e]);
            sumd += d;
#pragma unroll
            for (int n = 0; n < N_; ++n) {
                float a = exp2f(d * A[n]);
                h[n] = a * h[n] + dx * sRow[t][32 + n];
            }
        }
    }
    size_t base = (size_t)c * BE_ + (size_t)b * ED_ + e;
    const float* h = (const float*)h2;
#pragma unroll
    for (int n = 0; n < N_; ++n)
        hl[(size_t)n * (NC_ * BE_) + base] = h[n];              // coalesced streams
    sumdbuf[base] = sumd;
}

// carry recurrence over chunks; pa reconstructed as exp2(sumd*A_n).
// thread -> (n, be): all hl/carry/sumd accesses coalesced.
// 8-deep prefetch ring (fully unrolled -> static reg indices).
__global__ __launch_bounds__(256) void k_scan_b(const float* __restrict__ sumd,
                                                const float* __restrict__ hl,
                                                const float* __restrict__ A_log,
                                                float* __restrict__ carry) {
    int s = blockIdx.x * 256 + threadIdx.x;     // 0..S_-1
    int n  = s >> 12;                           // S_/N_ = 4096 = BE_
    int be = s & (BE_ - 1);
    int e  = be & (ED_ - 1);
    float An = -exp2f(LOG2E * A_log[e * N_ + n]) * LOG2E;
    const float* hln = hl    + (size_t)n * (NC_ * BE_);
    float*       crn = carry + (size_t)n * (NC_ * BE_);
    float sdr[8], hlr[8];
#pragma unroll
    for (int c = 0; c < 8; ++c) {
        sdr[c] = sumd[(size_t)c * BE_ + be];
        hlr[c] = hln[(size_t)c * BE_ + be];
    }
    float h = 0.f;
#pragma unroll
    for (int c = 0; c < NC_; ++c) {
        int r = c & 7;
        crn[(size_t)c * BE_ + be] = h;
        float p = exp2f(sdr[r] * An), q = hlr[r];
        if (c + 8 < NC_) {
            sdr[r] = sumd[(size_t)(c + 8) * BE_ + be];
            hlr[r] = hln[(size_t)(c + 8) * BE_ + be];
        }
        h = p * h + q;
    }
}

__global__ __launch_bounds__(256) void k_scan_c(const unsigned short* __restrict__ xcb,
                                                const float* __restrict__ delta,
                                                const float* __restrict__ dbc,
                                                const unsigned short* __restrict__ xzb,
                                                const float* __restrict__ A0s,
                                                const int* __restrict__ structf,
                                                const float* __restrict__ A_log,
                                                const float* __restrict__ Dp,
                                                const float* __restrict__ carry,
                                                unsigned short* __restrict__ ybf) {
    int b = blockIdx.z, c = blockIdx.y;
    int e = blockIdx.x * 256 + threadIdx.x;
    __shared__ float sBC[T_][32];                   // B at [0..16), C at [16..32)
    size_t t0 = (size_t)b * L_ + (size_t)c * T_;
    {
        int i = threadIdx.x;                        // stage only cols 32..63 of dbc rows
        if (i < T_ * 8) {
            int t = i >> 3, q = i & 7;
            ((float4*)&sBC[t][0])[q] = *(const float4*)(dbc + (t0 + t) * 64 + 32 + q * 4);
        }
    }
    __syncthreads();
    float A0 = A0s[e];
    bool structured = structf[e] != 0;
    floatv2 h2[8];
    size_t base = (size_t)c * BE_ + (size_t)b * ED_ + e;
    {
        float hs[N_];
#pragma unroll
        for (int n = 0; n < N_; ++n)
            hs[n] = carry[(size_t)n * (NC_ * BE_) + base];      // coalesced streams
#pragma unroll
        for (int i = 0; i < 8; ++i) h2[i] = (floatv2){hs[2 * i], hs[2 * i + 1]};
    }
    float Dv = Dp[e];
    if (structured) {
        const unsigned short* xp = xcb + t0 * ED_ + e;
        const float* dp_ = delta + t0 * ED_ + e;
        const unsigned short* zp = xzb + t0 * (2 * ED_) + ED_ + e;
        unsigned short* yp = ybf + t0 * ED_ + e;
        float xv_t = b2f(*xp); xp += ED_;
        float d_t  = *dp_;     dp_ += ED_;
        unsigned short z_t = *zp; zp += 2 * ED_;
        for (int t = 0; t < T_; ++t) {
            unsigned short xr = 0, z_n = 0;
            float d_n = 0.f;
            if (t + 1 < T_) {                       // prefetch next step
                xr  = *xp;
                d_n = *dp_;
                z_n = *zp;
            }
            xp += ED_; dp_ += ED_; zp += 2 * ED_;
            float dx = d_t * xv_t;
            floatv2 pw[8];
            pow_tree2(exp2f(d_t * A0), pw);
            const floatv2* bb2 = (const floatv2*)&sBC[t][0];
            const floatv2* cc2 = (const floatv2*)&sBC[t][16];
            floatv2 y0 = {0.f, 0.f}, y1 = {0.f, 0.f};
#pragma unroll
            for (int i = 0; i < 8; i += 2) {
                h2[i + 0] = pw[i + 0] * h2[i + 0] + dx * bb2[i + 0];
                h2[i + 1] = pw[i + 1] * h2[i + 1] + dx * bb2[i + 1];
                y0 += h2[i + 0] * cc2[i + 0];
                y1 += h2[i + 1] * cc2[i + 1];
            }
            floatv2 ys = y0 + y1;
            float y = ys.x + ys.y;
            float z = b2f(z_t);
            *yp = f2b((y + Dv * xv_t) * silu(z)); yp += ED_;
            xv_t = b2f(xr); d_t = d_n; z_t = z_n;
        }
    } else {
        float A[N_];
        float* h = (float*)h2;
#pragma unroll
        for (int n = 0; n < N_; ++n) A[n] = -exp2f(LOG2E * A_log[e * N_ + n]) * LOG2E;
        for (int t = 0; t < T_; ++t) {
            size_t bl = t0 + t;
            float d  = delta[bl * ED_ + e];
            float xv = b2f(xcb[bl * ED_ + e]);
            float dx = d * xv;
            float y = 0.f;
#pragma unroll
            for (int n = 0; n < N_; ++n) {
                float a = exp2f(d * A[n]);
                h[n] = a * h[n] + dx * sBC[t][n];
                y += h[n] * sBC[t][16 + n];
            }
            float z = b2f(xzb[bl * (2 * ED_) + ED_ + e]);
            ybf[bl * ED_ + e] = f2b((y + Dv * xv) * silu(z));
        }
    }
}

extern "C" void kernel_launch(void* const* d_in, const int* in_sizes, int n_in,
                              void* d_out, int out_size, void* d_ws, size_t ws_size,
                              hipStream_t stream) {
    const int* mask = (const int*)d_in[1];

    // workspace layout: ~46.97M floats = 187.9 MB (< 191.8 MB proven)
    float* ws = (float*)d_ws;
    int*   flag = (int*)d_ws;
    float* xw   = ws + 16;                          // M_*D_         4,194,304
    float* wn   = xw   + (size_t)M_ * D_;           // 1,024
    float* wc   = wn   + 1024;                      // 8,192
    float* wcb  = wc   + 8192;                      // 2,048
    float* wx   = wcb  + 2048;                      // 131,072
    float* wdt  = wx   + 131072;                    // 65,536
    float* wdtb = wdt  + 65536;                     // 2,048
    float* wal  = wdtb + 2048;                      // 32,768
    float* wdp  = wal  + 32768;                     // 2,048
    unsigned short* wib = (unsigned short*)(wdp + 2048);      // 2,097,152 ushorts
    unsigned short* wob = wib + 2097152;                      // 1,048,576 ushorts
    unsigned short* ubf = wob + 1048576;                      // 4,194,304 ushorts
    unsigned short* xzb = ubf + (size_t)M_ * D_;              // 16,777,216 ushorts
    unsigned short* xcb = xzb + (size_t)M_ * 2 * ED_;         // 8,388,608 ushorts (bf16 xc)
    float* dbc  = (float*)(xcb + (size_t)M_ * ED_);  // 524,288
    float* hl   = dbc   + (size_t)M_ * 64;          // NC_*S_ = 8,388,608
    float* carry= hl    + (size_t)NC_ * S_;         // 8,388,608
    float* sumd = carry + (size_t)NC_ * S_;         // NC_*BE_ = 524,288
    float* wT   = sumd  + (size_t)NC_ * BE_;        // 2*R_*ED_ = 65,536
    float* A0s  = wT    + 2 * R_ * ED_;             // 2*ED_ = 2,048
    int*   stfl = (int*)(A0s + 2 * ED_);            // 2*ED_ = 2,048
    float* delta= (float*)(stfl + 2 * ED_);         // M_*ED_ = 8,388,608
    unsigned short* ybf = (unsigned short*)hl;      // alias: hl dead after scan_b
    float* part = carry;   // KS*M_*64 = 4,194,304 floats; carry dead until scan_b

    k_flag0<<<1, 1, 0, stream>>>(flag);
    k_detect<<<128, 256, 0, stream>>>((const unsigned short*)d_in[0], flag);

    {
        Seg9 segs;
        int idxs[9] = {0, 2, 4, 5, 6, 7, 8, 9, 10};
        int pre = 0;
        for (int i = 0; i < 9; ++i) {
            segs.src[i] = d_in[idxs[i]];
            segs.prefix[i] = pre;
            pre += in_sizes[idxs[i]];
        }
        segs.prefix[9] = pre;
        k_cvt_batch<<<(pre + 255) / 256, 256, 0, stream>>>(segs, xw, pre, flag);
        int n0 = 2 * 2 * ED_ * D_;
        int tot = n0 + 2 * D_ * ED_;
        k_cvt_bf_batch<<<(tot + 255) / 256, 256, 0, stream>>>(d_in[3], d_in[11], wib, n0, tot, flag);
    }
    k_prep<<<(2 * ED_) / 256, 256, 0, stream>>>(wdt, wal, wT, A0s, stfl);

    for (int layer = 0; layer < 2; ++layer) {
        const float* nw = wn  + layer * D_;
        const unsigned short* iw = wib + (size_t)layer * 2 * ED_ * D_;
        const float* cw = wc  + layer * ED_ * KC_;
        const float* cb = wcb + layer * ED_;
        const float* xwp= wx  + (size_t)layer * 64 * ED_;
        const float* db = wdtb+ layer * ED_;
        const float* al = wal + layer * ED_ * N_;
        const float* dp = wdp + layer * ED_;
        const float* wtl= wT  + (size_t)layer * R_ * ED_;
        const float* a0l= A0s + layer * ED_;
        const int*   sfl= stfl+ layer * ED_;
        const unsigned short* ow = wob + (size_t)layer * D_ * ED_;

        k_rmsnorm<<<M_ / 2, 256, 0, stream>>>(xw, mask, nw, ubf);
        gemm_bt<1, 128><<<dim3(2 * ED_ / 128, M_ / 128), 256, 0, stream>>>(ubf, iw, xzb, nullptr, nullptr, nullptr, M_, 2 * ED_, D_);
        k_conv<<<(M_ * ED_ / 2) / 256, 256, 0, stream>>>(xzb, cw, cb, xcb);
        gemm_nt_sk<<<dim3(KS, M_ / BM), 256, 0, stream>>>(xcb, xwp, part, M_, 64, ED_);
        k_red8<<<(M_ * 64 / 4 + 255) / 256, 256, 0, stream>>>(part, dbc, M_ * 64 / 4);
        k_scan_a<<<dim3(ED_ / 256, NC_, B_), 256, 0, stream>>>(xcb, dbc, wtl, db, a0l, sfl, al, delta, sumd, hl);
        k_scan_b<<<S_ / 256, 256, 0, stream>>>(sumd, hl, al, carry);
        k_scan_c<<<dim3(ED_ / 256, NC_, B_), 256, 0, stream>>>(xcb, delta, dbc, xzb, a0l, sfl, al, dp, carry, ybf);
        if (layer == 0) {
            gemm_bt<2, 64><<<dim3(D_ / 64, M_ / 128), 256, 0, stream>>>(ybf, ow, xw, mask, nullptr, nullptr, M_, D_, ED_);
        } else {
            gemm_bt<3, 64><<<dim3(D_ / 64, M_ / 128), 256, 0, stream>>>(ybf, ow, xw, mask, flag, d_out, M_, D_, ED_);
        }
    }
}

// Round 14
// 469.893 us; speedup vs baseline: 1.1568x; 1.0337x over previous
//
#include <hip/hip_runtime.h>
#include <math.h>

#define B_ 4
#define L_ 2048
#define D_ 512
#define ED_ 1024
#define N_ 16
#define R_ 32
#define KC_ 4
#define M_ (B_*L_)   // 8192 rows
#define NC_ 128      // scan chunks (8 blocks/CU occupancy regime)
#define T_  (L_/NC_) // 16 steps per chunk
#define S_  (B_*ED_*N_)  // 65536 scan series
#define BE_ (B_*ED_)     // 4096
#define LOG2E 1.44269504f
#define LN2   0.69314718f

typedef __attribute__((ext_vector_type(8))) short short8;
typedef __attribute__((ext_vector_type(4))) float floatx4;
typedef __attribute__((ext_vector_type(2))) float floatv2;   // -> v_pk_*_f32

static __device__ __forceinline__ float b2f(unsigned short u) {
    unsigned int v = ((unsigned int)u) << 16;
    float f;
    __builtin_memcpy(&f, &v, 4);
    return f;
}
static __device__ __forceinline__ unsigned short f2b(float f) {
    unsigned int u;
    __builtin_memcpy(&u, &f, 4);
    unsigned int lsb = (u >> 16) & 1u;
    u += 0x7fffu + lsb;                 // round-to-nearest-even
    return (unsigned short)(u >> 16);
}
static __device__ __forceinline__ float silu(float x) {
    return x / (1.f + exp2f(-LOG2E * x));
}
static __device__ __forceinline__ float softplusf(float x) {
    return fmaxf(x, 0.f) + LN2 * log2f(1.f + exp2f(-LOG2E * fabsf(x)));
}
// pw[i] = {a^(2i+1), a^(2i+2)} via packed tree (depth 4)
static __device__ __forceinline__ void pow_tree2(float a1, floatv2* pw) {
    float a2 = a1 * a1, a4 = a2 * a2, a8 = a4 * a4;
    pw[0] = (floatv2){a1, a2};
    pw[1] = pw[0] * a2;
    pw[2] = pw[0] * a4;
    pw[3] = pw[1] * a4;
    pw[4] = pw[0] * a8;
    pw[5] = pw[1] * a8;
    pw[6] = pw[2] * a8;
    pw[7] = pw[3] * a8;
}

// ---------- dtype detection ----------
__global__ void k_flag0(int* flag) {
    if (blockIdx.x == 0 && threadIdx.x == 0) *flag = 0;
}
__global__ void k_detect(const unsigned short* __restrict__ x, int* flag) {
    int i = blockIdx.x * 256 + threadIdx.x;
    unsigned int e = (x[i] >> 7) & 0xFF;
    unsigned long long m = __ballot(e >= 0x88);
    if ((threadIdx.x & 63) == 0 && m != 0ull) atomicOr(flag, 1);
}

// ---------- batched conversions ----------
struct Seg9 { const void* src[9]; int prefix[10]; };
__global__ void k_cvt_batch(Seg9 segs, float* __restrict__ dst, int total,
                            const int* __restrict__ flag) {
    int i = blockIdx.x * 256 + threadIdx.x;
    if (i >= total) return;
    int s = 0;
#pragma unroll
    for (int k = 1; k < 9; ++k) if (i >= segs.prefix[k]) s = k;
    int off = i - segs.prefix[s];
    if (*flag) dst[i] = ((const float*)segs.src[s])[off];
    else       dst[i] = b2f(((const unsigned short*)segs.src[s])[off]);
}
__global__ void k_cvt_bf_batch(const void* __restrict__ src0,
                               const void* __restrict__ src1,
                               unsigned short* __restrict__ dst,
                               int n0, int total, const int* __restrict__ flag) {
    int i = blockIdx.x * 256 + threadIdx.x;
    if (i >= total) return;
    const void* src = (i < n0) ? src0 : src1;
    int off = (i < n0) ? i : i - n0;
    if (*flag) dst[i] = f2b(((const float*)src)[off]);
    else       dst[i] = ((const unsigned short*)src)[off];
}

// ---------- scan prep (once): transpose dtw to coalesced layout, A0, flag ----
// wT layout per layer: [R/4][ED][4] floats = float4 index (r4*ED + e).
__global__ void k_prep(const float* __restrict__ wdt,
                       const float* __restrict__ A_log,
                       float* __restrict__ wT,
                       float* __restrict__ A0s,
                       int* __restrict__ structf) {
    int idx = blockIdx.x * 256 + threadIdx.x;       // 0 .. 2*ED_-1
    int layer = idx >> 10, e = idx & (ED_ - 1);
    const float* src = wdt + (size_t)idx * R_;
    float* dstb = wT + (size_t)layer * (R_ * ED_);
#pragma unroll
    for (int r = 0; r < R_; ++r)
        dstb[(r >> 2) * (ED_ * 4) + e * 4 + (r & 3)] = src[r];
    float A0 = -exp2f(LOG2E * A_log[(size_t)idx * N_]) * LOG2E;
    bool st = true;
#pragma unroll
    for (int n = 1; n < N_; ++n) {
        float An = -exp2f(LOG2E * A_log[(size_t)idx * N_ + n]) * LOG2E;
        st = st && (fabsf(An - (n + 1) * A0) <= 1e-4f * fabsf(An));
    }
    A0s[idx] = A0;
    structf[idx] = st ? 1 : 0;
}

// ---------- rmsnorm with mask; writes u (bf16). 2 rows/block. ----------
__global__ __launch_bounds__(256) void k_rmsnorm(const float* __restrict__ x,
                                                 const int* __restrict__ mask,
                                                 const float* __restrict__ w,
                                                 unsigned short* __restrict__ ubf) {
    int tid = threadIdx.x;
    int row = blockIdx.x * 2 + (tid >> 7);
    int t128 = tid & 127;
    size_t base = (size_t)row * D_ + t128 * 4;
    float4 v = *(const float4*)(x + base);
    float mv = (float)mask[row];
    v.x *= mv; v.y *= mv; v.z *= mv; v.w *= mv;
    float ss = v.x*v.x + v.y*v.y + v.z*v.z + v.w*v.w;
#pragma unroll
    for (int o = 1; o < 64; o <<= 1) ss += __shfl_xor(ss, o, 64);
    __shared__ float sred[4];
    if ((tid & 63) == 0) sred[tid >> 6] = ss;
    __syncthreads();
    int g = tid >> 7;
    float rs = rsqrtf((sred[2 * g] + sred[2 * g + 1]) / (float)D_ + 1e-5f);
    float4 wv = *(const float4*)(w + t128 * 4);
    ushort4 b4;
    b4.x = f2b(v.x * rs * wv.x);
    b4.y = f2b(v.y * rs * wv.y);
    b4.z = f2b(v.z * rs * wv.z);
    b4.w = f2b(v.w * rs * wv.w);
    *(ushort4*)(ubf + base) = b4;
}

// ---------- bf16 MFMA GEMM: out = A[M,K] * W[N,K]^T ----------
// 3-buffer rotation, depth-2 prefetch, counted vmcnt (T3+T4). One raw
// s_barrier per K-step; lgkmcnt(0) before barrier closes the read-reuse race.
// XCD-aware bijective block swizzle (grid % 8 == 0 for all call sites).
// MODE 1: write bf16. MODE 2: C=xw RMW + mask. MODE 3: like 2 but writes the
// final output buffer (dtype by flag) + the x[:,0,:] slice; xw not written.
typedef __attribute__((address_space(1))) const unsigned int guint;
typedef __attribute__((address_space(3))) unsigned int luint;
#define GLL(gp, lp) __builtin_amdgcn_global_load_lds((guint*)(const void*)(gp), (luint*)(void*)(lp), 16, 0, 0)

template<int N> static __device__ __forceinline__ void waitv() {
    if constexpr (N == 0) asm volatile("s_waitcnt vmcnt(0)" ::: "memory");
    else if constexpr (N == 3) asm volatile("s_waitcnt vmcnt(3)" ::: "memory");
    else if constexpr (N == 4) asm volatile("s_waitcnt vmcnt(4)" ::: "memory");
}

template<int MODE, int BNT>
__global__ __launch_bounds__(256) void gemm_bt(const unsigned short* __restrict__ A,
                                               const unsigned short* __restrict__ W,
                                               void* __restrict__ C,
                                               const int* __restrict__ mask,
                                               const int* __restrict__ flag,
                                               void* __restrict__ out,
                                               int M, int N, int K) {
    constexpr int NF = BNT / 32;                 // n-frags per wave: 128->4, 64->2
    constexpr int LW = 2 + BNT / 64;             // GLL issues per wave per stage: 4 or 3
    __shared__ unsigned short As[3][128][32];
    __shared__ unsigned short Bs[3][BNT][32];
    int tid  = threadIdx.x;
    int wave = tid >> 6;
    int lane = tid & 63;
    // XCD-aware bijective swizzle (nwg multiple of 8)
    int nwg = gridDim.x * gridDim.y;
    int id  = blockIdx.y * gridDim.x + blockIdx.x;
    int swz = (id & 7) * (nwg >> 3) + (id >> 3);
    int m0 = (swz / gridDim.x) * 128;
    int n0 = (swz % gridDim.x) * BNT;
    int wm = (wave & 1) * 64;
    int wn = (wave >> 1) * (BNT / 2);
    int quad = lane >> 4;
    int l16  = lane & 15;
    int crd = (quad ^ ((l16 >> 1) & 3)) * 8;       // swizzled fragment-read position

    int rA0 = wave * 16 + (lane >> 2);             // rows 0..63; +64 for second issue
    int cA  = ((lane & 3) ^ ((rA0 >> 1) & 3)) * 8;

    floatx4 acc[4][NF] = {};

    auto stage = [&](int buf, int k0) {
        const unsigned short* gA0 = A + (size_t)(m0 + rA0) * K + k0 + cA;
        GLL(gA0,                   &As[buf][wave * 16][0]);
        GLL(gA0 + (size_t)64 * K,  &As[buf][64 + wave * 16][0]);
        const unsigned short* gB0 = W + (size_t)(n0 + rA0) * K + k0 + cA;
        GLL(gB0,                   &Bs[buf][wave * 16][0]);
        if constexpr (BNT == 128)
            GLL(gB0 + (size_t)64 * K, &Bs[buf][64 + wave * 16][0]);
    };

    int nk = K / 32;                               // >= 2 always here
    stage(0, 0);
    stage(1, 32);

    int cur = 0;
    for (int t = 0; t < nk; ++t) {
        if (t + 1 < nk) waitv<LW>();               // stage t landed; t+1 stays in flight
        else            waitv<0>();
        asm volatile("s_barrier" ::: "memory");    // collective: buf cur fully written,
                                                   // and all reads of buf (cur+2)%3 done
        if (t + 2 < nk) {
            int bw = cur + 2; if (bw >= 3) bw -= 3;
            stage(bw, (t + 2) * 32);
        }
        short8 af[4], bfr[NF];
#pragma unroll
        for (int f = 0; f < 4; ++f)
            af[f]  = *(const short8*)&As[cur][wm + f * 16 + l16][crd];
#pragma unroll
        for (int f = 0; f < NF; ++f)
            bfr[f] = *(const short8*)&Bs[cur][wn + f * 16 + l16][crd];
#pragma unroll
        for (int mf = 0; mf < 4; ++mf)
#pragma unroll
            for (int nf = 0; nf < NF; ++nf)
                acc[mf][nf] = __builtin_amdgcn_mfma_f32_16x16x32_bf16(af[mf], bfr[nf], acc[mf][nf], 0, 0, 0);
        asm volatile("s_waitcnt lgkmcnt(0)" ::: "memory");  // reads of buf cur complete
        cur = (cur == 2) ? 0 : cur + 1;
    }

    int fl = (MODE == 3) ? *flag : 0;
#pragma unroll
    for (int mf = 0; mf < 4; ++mf) {
#pragma unroll
        for (int nf = 0; nf < NF; ++nf) {
#pragma unroll
            for (int i = 0; i < 4; ++i) {
                int r = m0 + wm + mf * 16 + quad * 4 + i;   // C/D: row=quad*4+reg
                int c = n0 + wn + nf * 16 + l16;            //      col=lane&15
                size_t idx = (size_t)r * N + c;
                if (MODE == 1) {
                    ((unsigned short*)C)[idx] = f2b(acc[mf][nf][i]);
                } else if (MODE == 2) {
                    float* C32 = (float*)C;
                    float mv = (float)mask[r];
                    C32[idx] = (C32[idx] + acc[mf][nf][i]) * mv;
                } else {
                    const float* C32 = (const float*)C;
                    float mv = (float)mask[r];
                    float v = (C32[idx] + acc[mf][nf][i]) * mv;
                    if (fl) ((float*)out)[idx] = v;
                    else    ((unsigned short*)out)[idx] = f2b(v);
                    if ((r & (L_ - 1)) == 0) {
                        size_t oidx = (size_t)M_ * D_ + (size_t)(r >> 11) * D_ + c;
                        if (fl) ((float*)out)[oidx] = v;
                        else    ((unsigned short*)out)[oidx] = f2b(v);
                    }
                }
            }
        }
    }
}

// ---------- split-K f32 GEMM (GEMM2, N=64); A in bf16 ----------
#define BM 64
#define BN 64
#define BK 16
#define KS 8
__global__ __launch_bounds__(256) void gemm_nt_sk(const unsigned short* __restrict__ A,
                                                  const float* __restrict__ W,
                                                  float* __restrict__ part,
                                                  int M, int N, int K) {
    __shared__ float Asm[BK][BM + 4];
    __shared__ float Wsm[BK][BN + 4];
    int tid = threadIdx.x;
    int ks = blockIdx.x;
    int m0 = blockIdx.y * BM;
    int kb = ks * (K / KS);
    int ke = kb + (K / KS);
    int tx = tid & 15;
    int ty = tid >> 4;
    int lr = tid >> 2;
    int lk = (tid & 3) * 4;
    float acc[4][4] = {};
    for (int k0 = kb; k0 < ke; k0 += BK) {
        ushort4 av = *(const ushort4*)(A + (size_t)(m0 + lr) * K + k0 + lk);
        Asm[lk + 0][lr] = b2f(av.x); Asm[lk + 1][lr] = b2f(av.y);
        Asm[lk + 2][lr] = b2f(av.z); Asm[lk + 3][lr] = b2f(av.w);
        float4 wv = *(const float4*)(W + (size_t)lr * K + k0 + lk);
        Wsm[lk + 0][lr] = wv.x; Wsm[lk + 1][lr] = wv.y;
        Wsm[lk + 2][lr] = wv.z; Wsm[lk + 3][lr] = wv.w;
        __syncthreads();
#pragma unroll
        for (int kk = 0; kk < BK; ++kk) {
            float4 a = *(const float4*)&Asm[kk][ty * 4];
            float4 w = *(const float4*)&Wsm[kk][tx * 4];
            acc[0][0] += a.x * w.x; acc[0][1] += a.x * w.y; acc[0][2] += a.x * w.z; acc[0][3] += a.x * w.w;
            acc[1][0] += a.y * w.x; acc[1][1] += a.y * w.y; acc[1][2] += a.y * w.z; acc[1][3] += a.y * w.w;
            acc[2][0] += a.z * w.x; acc[2][1] += a.z * w.y; acc[2][2] += a.z * w.z; acc[2][3] += a.z * w.w;
            acc[3][0] += a.w * w.x; acc[3][1] += a.w * w.y; acc[3][2] += a.w * w.z; acc[3][3] += a.w * w.w;
        }
        __syncthreads();
    }
    float* p = part + (size_t)ks * M * N;
#pragma unroll
    for (int i = 0; i < 4; ++i) {
        int m = m0 + ty * 4 + i;
#pragma unroll
        for (int j = 0; j < 4; ++j) {
            int n = tx * 4 + j;
            p[(size_t)m * N + n] = acc[i][j];
        }
    }
}

__global__ void k_red8(const float* __restrict__ part, float* __restrict__ dbc, int mn4) {
    int i = blockIdx.x * 256 + threadIdx.x;
    if (i >= mn4) return;
    float4 s = ((const float4*)part)[i];
#pragma unroll
    for (int ks = 1; ks < KS; ++ks) {
        float4 v = ((const float4*)(part + (size_t)ks * mn4 * 4))[i];
        s.x += v.x; s.y += v.y; s.z += v.z; s.w += v.w;
    }
    ((float4*)dbc)[i] = s;
}

// ---------- depthwise causal conv (K=4) + bias + SiLU; xz in bf16 ----------
// 2-wide over e: ushort2 reads (4B/lane); OUTPUT bf16.
__global__ __launch_bounds__(256) void k_conv(const unsigned short* __restrict__ xzb,
                                              const float* __restrict__ cw,
                                              const float* __restrict__ cb,
                                              unsigned short* __restrict__ xcb) {
    int idx = blockIdx.x * 256 + threadIdx.x;      // 0 .. M_*ED_/2
    int e2 = idx & (ED_ / 2 - 1);
    int e  = e2 * 2;
    int bl = idx >> 9;
    int l  = bl & (L_ - 1);
    float acc0 = cb[e], acc1 = cb[e + 1];
    const unsigned short* col = xzb + (size_t)bl * (2 * ED_) + e;
    float4 wa = *(const float4*)(cw + e * 4);
    float4 wb = *(const float4*)(cw + e * 4 + 4);
    ushort2 v3 = *(const ushort2*)(col);
    if (l >= 3) {
        ushort2 v0 = *(const ushort2*)(col - 3 * 2 * ED_);
        ushort2 v1 = *(const ushort2*)(col - 2 * 2 * ED_);
        ushort2 v2 = *(const ushort2*)(col - 1 * 2 * ED_);
        acc0 += wa.x * b2f(v0.x) + wa.y * b2f(v1.x) + wa.z * b2f(v2.x) + wa.w * b2f(v3.x);
        acc1 += wb.x * b2f(v0.y) + wb.y * b2f(v1.y) + wb.z * b2f(v2.y) + wb.w * b2f(v3.y);
    } else {
        if (l >= 2) {
            ushort2 v1 = *(const ushort2*)(col - 2 * 2 * ED_);
            acc0 += wa.y * b2f(v1.x); acc1 += wb.y * b2f(v1.y);
        }
        if (l >= 1) {
            ushort2 v2 = *(const ushort2*)(col - 1 * 2 * ED_);
            acc0 += wa.z * b2f(v2.x); acc1 += wb.z * b2f(v2.y);
        }
        acc0 += wa.w * b2f(v3.x); acc1 += wb.w * b2f(v3.y);
    }
    ushort2 o;
    o.x = f2b(silu(acc0));
    o.y = f2b(silu(acc1));
    *(ushort2*)(xcb + (size_t)bl * ED_ + e) = o;
}

// ---------- chunked selective scan ----------
// bf16 hl/carry (halves the scan glue traffic; recurrence stays f32
// internally, only cross-kernel storage is quantized). delta/sumd stay f32.
__global__ __launch_bounds__(256) void k_scan_a(const unsigned short* __restrict__ xcb,
                                                const float* __restrict__ dbc,
                                                const float* __restrict__ wt,
                                                const float* __restrict__ dtb,
                                                const float* __restrict__ A0s,
                                                const int* __restrict__ structf,
                                                const float* __restrict__ A_log,
                                                float* __restrict__ delta,
                                                float* __restrict__ sumdbuf,
                                                unsigned short* __restrict__ hl) {
    int b = blockIdx.z, c = blockIdx.y;
    int e = blockIdx.x * 256 + threadIdx.x;
    __shared__ float sRow[T_][64];
    size_t t0 = (size_t)b * L_ + (size_t)c * T_;
    {
        const float4* src = (const float4*)(dbc + t0 * 64);
        float4* dst = (float4*)&sRow[0][0];
#pragma unroll
        for (int i = 0; i < T_ * 16; i += 256)
            dst[i + threadIdx.x] = src[i + threadIdx.x];
    }
    __syncthreads();
    floatv2 w2[R_ / 2];
    {
        const float4* wtp = (const float4*)wt;
#pragma unroll
        for (int i = 0; i < 8; ++i) {
            float4 v = wtp[(size_t)i * ED_ + e];              // coalesced
            w2[2 * i]     = (floatv2){v.x, v.y};
            w2[2 * i + 1] = (floatv2){v.z, v.w};
        }
    }
    float bias = dtb[e];
    float A0 = A0s[e];
    bool structured = structf[e] != 0;
    floatv2 h2[8];
#pragma unroll
    for (int i = 0; i < 8; ++i) h2[i] = (floatv2){0.f, 0.f};
    float sumd = 0.f;
    if (structured) {
        const unsigned short* xp = xcb + t0 * ED_ + e;
        float* dep = delta + t0 * ED_ + e;
        float xv_t = b2f(*xp); xp += ED_;
        for (int t = 0; t < T_; ++t) {
            unsigned short xr = (t + 1 < T_) ? *xp : (unsigned short)0; xp += ED_;  // prefetch
            const floatv2* dt2 = (const floatv2*)&sRow[t][0];
            floatv2 q0 = {0.f, 0.f}, q1 = {0.f, 0.f}, q2 = {0.f, 0.f}, q3 = {0.f, 0.f};
#pragma unroll
            for (int r = 0; r < R_ / 2; r += 4) {
                q0 += dt2[r + 0] * w2[r + 0];
                q1 += dt2[r + 1] * w2[r + 1];
                q2 += dt2[r + 2] * w2[r + 2];
                q3 += dt2[r + 3] * w2[r + 3];
            }
            floatv2 qs = (q0 + q1) + (q2 + q3);
            float d = softplusf(qs.x + qs.y + bias);
            *dep = d; dep += ED_;                  // coalesced delta store
            float dx = d * xv_t;
            sumd += d;
            floatv2 pw[8];
            pow_tree2(exp2f(d * A0), pw);
            const floatv2* bb2 = (const floatv2*)&sRow[t][32];
#pragma unroll
            for (int i = 0; i < 8; ++i)
                h2[i] = pw[i] * h2[i] + dx * bb2[i];
            xv_t = b2f(xr);
        }
    } else {
        float A[N_];
        float* h = (float*)h2;
#pragma unroll
        for (int n = 0; n < N_; ++n) A[n] = -exp2f(LOG2E * A_log[e * N_ + n]) * LOG2E;
        float* wsc = (float*)w2;
        for (int t = 0; t < T_; ++t) {
            size_t bl = t0 + t;
            float p0 = bias, p1 = 0.f, p2 = 0.f, p3 = 0.f;
#pragma unroll
            for (int r = 0; r < R_; r += 4) {
                p0 += sRow[t][r + 0] * wsc[r + 0];
                p1 += sRow[t][r + 1] * wsc[r + 1];
                p2 += sRow[t][r + 2] * wsc[r + 2];
                p3 += sRow[t][r + 3] * wsc[r + 3];
            }
            float d = softplusf((p0 + p1) + (p2 + p3));
            delta[bl * ED_ + e] = d;
            float dx = d * b2f(xcb[bl * ED_ + e]);
            sumd += d;
#pragma unroll
            for (int n = 0; n < N_; ++n) {
                float a = exp2f(d * A[n]);
                h[n] = a * h[n] + dx * sRow[t][32 + n];
            }
        }
    }
    size_t base = (size_t)c * BE_ + (size_t)b * ED_ + e;
    const float* h = (const float*)h2;
#pragma unroll
    for (int n = 0; n < N_; ++n)
        hl[(size_t)n * (NC_ * BE_) + base] = f2b(h[n]);         // bf16 coalesced streams
    sumdbuf[base] = sumd;
}

// carry recurrence over chunks; pa reconstructed as exp2(sumd*A_n).
// thread -> (n, be): all hl/carry/sumd accesses coalesced. Internal h is f32;
// stored hl/carry are bf16. 8-deep prefetch ring.
__global__ __launch_bounds__(256) void k_scan_b(const float* __restrict__ sumd,
                                                const unsigned short* __restrict__ hl,
                                                const float* __restrict__ A_log,
                                                unsigned short* __restrict__ carry) {
    int s = blockIdx.x * 256 + threadIdx.x;     // 0..S_-1
    int n  = s >> 12;                           // S_/N_ = 4096 = BE_
    int be = s & (BE_ - 1);
    int e  = be & (ED_ - 1);
    float An = -exp2f(LOG2E * A_log[e * N_ + n]) * LOG2E;
    const unsigned short* hln = hl    + (size_t)n * (NC_ * BE_);
    unsigned short*       crn = carry + (size_t)n * (NC_ * BE_);
    float sdr[8], hlr[8];
#pragma unroll
    for (int c = 0; c < 8; ++c) {
        sdr[c] = sumd[(size_t)c * BE_ + be];
        hlr[c] = b2f(hln[(size_t)c * BE_ + be]);
    }
    float h = 0.f;
#pragma unroll
    for (int c = 0; c < NC_; ++c) {
        int r = c & 7;
        crn[(size_t)c * BE_ + be] = f2b(h);
        float p = exp2f(sdr[r] * An), q = hlr[r];
        if (c + 8 < NC_) {
            sdr[r] = sumd[(size_t)(c + 8) * BE_ + be];
            hlr[r] = b2f(hln[(size_t)(c + 8) * BE_ + be]);
        }
        h = p * h + q;
    }
}

__global__ __launch_bounds__(256) void k_scan_c(const unsigned short* __restrict__ xcb,
                                                const float* __restrict__ delta,
                                                const float* __restrict__ dbc,
                                                const unsigned short* __restrict__ xzb,
                                                const float* __restrict__ A0s,
                                                const int* __restrict__ structf,
                                                const float* __restrict__ A_log,
                                                const float* __restrict__ Dp,
                                                const unsigned short* __restrict__ carry,
                                                unsigned short* __restrict__ ybf) {
    int b = blockIdx.z, c = blockIdx.y;
    int e = blockIdx.x * 256 + threadIdx.x;
    __shared__ float sBC[T_][32];                   // B at [0..16), C at [16..32)
    size_t t0 = (size_t)b * L_ + (size_t)c * T_;
    {
        int i = threadIdx.x;                        // stage only cols 32..63 of dbc rows
        if (i < T_ * 8) {
            int t = i >> 3, q = i & 7;
            ((float4*)&sBC[t][0])[q] = *(const float4*)(dbc + (t0 + t) * 64 + 32 + q * 4);
        }
    }
    __syncthreads();
    float A0 = A0s[e];
    bool structured = structf[e] != 0;
    floatv2 h2[8];
    size_t base = (size_t)c * BE_ + (size_t)b * ED_ + e;
    {
        float hs[N_];
#pragma unroll
        for (int n = 0; n < N_; ++n)
            hs[n] = b2f(carry[(size_t)n * (NC_ * BE_) + base]);  // bf16 coalesced streams
#pragma unroll
        for (int i = 0; i < 8; ++i) h2[i] = (floatv2){hs[2 * i], hs[2 * i + 1]};
    }
    float Dv = Dp[e];
    if (structured) {
        const unsigned short* xp = xcb + t0 * ED_ + e;
        const float* dp_ = delta + t0 * ED_ + e;
        const unsigned short* zp = xzb + t0 * (2 * ED_) + ED_ + e;
        unsigned short* yp = ybf + t0 * ED_ + e;
        float xv_t = b2f(*xp); xp += ED_;
        float d_t  = *dp_;     dp_ += ED_;
        unsigned short z_t = *zp; zp += 2 * ED_;
        for (int t = 0; t < T_; ++t) {
            unsigned short xr = 0, z_n = 0;
            float d_n = 0.f;
            if (t + 1 < T_) {                       // prefetch next step
                xr  = *xp;
                d_n = *dp_;
                z_n = *zp;
            }
            xp += ED_; dp_ += ED_; zp += 2 * ED_;
            float dx = d_t * xv_t;
            floatv2 pw[8];
            pow_tree2(exp2f(d_t * A0), pw);
            const floatv2* bb2 = (const floatv2*)&sBC[t][0];
            const floatv2* cc2 = (const floatv2*)&sBC[t][16];
            floatv2 y0 = {0.f, 0.f}, y1 = {0.f, 0.f};
#pragma unroll
            for (int i = 0; i < 8; i += 2) {
                h2[i + 0] = pw[i + 0] * h2[i + 0] + dx * bb2[i + 0];
                h2[i + 1] = pw[i + 1] * h2[i + 1] + dx * bb2[i + 1];
                y0 += h2[i + 0] * cc2[i + 0];
                y1 += h2[i + 1] * cc2[i + 1];
            }
            floatv2 ys = y0 + y1;
            float y = ys.x + ys.y;
            float z = b2f(z_t);
            *yp = f2b((y + Dv * xv_t) * silu(z)); yp += ED_;
            xv_t = b2f(xr); d_t = d_n; z_t = z_n;
        }
    } else {
        float A[N_];
        float* h = (float*)h2;
#pragma unroll
        for (int n = 0; n < N_; ++n) A[n] = -exp2f(LOG2E * A_log[e * N_ + n]) * LOG2E;
        for (int t = 0; t < T_; ++t) {
            size_t bl = t0 + t;
            float d  = delta[bl * ED_ + e];
            float xv = b2f(xcb[bl * ED_ + e]);
            float dx = d * xv;
            float y = 0.f;
#pragma unroll
            for (int n = 0; n < N_; ++n) {
                float a = exp2f(d * A[n]);
                h[n] = a * h[n] + dx * sBC[t][n];
                y += h[n] * sBC[t][16 + n];
            }
            float z = b2f(xzb[bl * (2 * ED_) + ED_ + e]);
            ybf[bl * ED_ + e] = f2b((y + Dv * xv) * silu(z));
        }
    }
}

extern "C" void kernel_launch(void* const* d_in, const int* in_sizes, int n_in,
                              void* d_out, int out_size, void* d_ws, size_t ws_size,
                              hipStream_t stream) {
    const int* mask = (const int*)d_in[1];

    // workspace layout: byte offsets unchanged from r13 (regions half-used
    // where dtype shrank); ~187.9 MB < 191.8 MB proven
    float* ws = (float*)d_ws;
    int*   flag = (int*)d_ws;
    float* xw   = ws + 16;                          // M_*D_         4,194,304
    float* wn   = xw   + (size_t)M_ * D_;           // 1,024
    float* wc   = wn   + 1024;                      // 8,192
    float* wcb  = wc   + 8192;                      // 2,048
    float* wx   = wcb  + 2048;                      // 131,072
    float* wdt  = wx   + 131072;                    // 65,536
    float* wdtb = wdt  + 65536;                     // 2,048
    float* wal  = wdtb + 2048;                      // 32,768
    float* wdp  = wal  + 32768;                     // 2,048
    unsigned short* wib = (unsigned short*)(wdp + 2048);      // 2,097,152 ushorts
    unsigned short* wob = wib + 2097152;                      // 1,048,576 ushorts
    unsigned short* ubf = wob + 1048576;                      // 4,194,304 ushorts
    unsigned short* xzb = ubf + (size_t)M_ * D_;              // 16,777,216 ushorts
    unsigned short* xcb = xzb + (size_t)M_ * 2 * ED_;         // 8,388,608 ushorts (bf16 xc)
    float* dbc  = (float*)(xcb + (size_t)M_ * ED_);  // 524,288
    float* hlf  = dbc   + (size_t)M_ * 64;          // region: NC_*S_ floats (bf16 uses half)
    float* carf = hlf   + (size_t)NC_ * S_;         // region: NC_*S_ floats
    float* sumd = carf  + (size_t)NC_ * S_;         // NC_*BE_ = 524,288
    float* wT   = sumd  + (size_t)NC_ * BE_;        // 2*R_*ED_ = 65,536
    float* A0s  = wT    + 2 * R_ * ED_;             // 2*ED_ = 2,048
    int*   stfl = (int*)(A0s + 2 * ED_);            // 2*ED_ = 2,048
    float* delta= (float*)(stfl + 2 * ED_);         // M_*ED_ = 8,388,608
    unsigned short* hl    = (unsigned short*)hlf;   // NC_*S_ ushorts (half the region)
    unsigned short* carry = (unsigned short*)carf;  // NC_*S_ ushorts
    unsigned short* ybf = (unsigned short*)hlf;     // alias: hl dead after scan_b
    float* part = carf;    // KS*M_*64 floats = full carf region; dead until scan_b

    k_flag0<<<1, 1, 0, stream>>>(flag);
    k_detect<<<128, 256, 0, stream>>>((const unsigned short*)d_in[0], flag);

    {
        Seg9 segs;
        int idxs[9] = {0, 2, 4, 5, 6, 7, 8, 9, 10};
        int pre = 0;
        for (int i = 0; i < 9; ++i) {
            segs.src[i] = d_in[idxs[i]];
            segs.prefix[i] = pre;
            pre += in_sizes[idxs[i]];
        }
        segs.prefix[9] = pre;
        k_cvt_batch<<<(pre + 255) / 256, 256, 0, stream>>>(segs, xw, pre, flag);
        int n0 = 2 * 2 * ED_ * D_;
        int tot = n0 + 2 * D_ * ED_;
        k_cvt_bf_batch<<<(tot + 255) / 256, 256, 0, stream>>>(d_in[3], d_in[11], wib, n0, tot, flag);
    }
    k_prep<<<(2 * ED_) / 256, 256, 0, stream>>>(wdt, wal, wT, A0s, stfl);

    for (int layer = 0; layer < 2; ++layer) {
        const float* nw = wn  + layer * D_;
        const unsigned short* iw = wib + (size_t)layer * 2 * ED_ * D_;
        const float* cw = wc  + layer * ED_ * KC_;
        const float* cb = wcb + layer * ED_;
        const float* xwp= wx  + (size_t)layer * 64 * ED_;
        const float* db = wdtb+ layer * ED_;
        const float* al = wal + layer * ED_ * N_;
        const float* dp = wdp + layer * ED_;
        const float* wtl= wT  + (size_t)layer * R_ * ED_;
        const float* a0l= A0s + layer * ED_;
        const int*   sfl= stfl+ layer * ED_;
        const unsigned short* ow = wob + (size_t)layer * D_ * ED_;

        k_rmsnorm<<<M_ / 2, 256, 0, stream>>>(xw, mask, nw, ubf);
        gemm_bt<1, 128><<<dim3(2 * ED_ / 128, M_ / 128), 256, 0, stream>>>(ubf, iw, xzb, nullptr, nullptr, nullptr, M_, 2 * ED_, D_);
        k_conv<<<(M_ * ED_ / 2) / 256, 256, 0, stream>>>(xzb, cw, cb, xcb);
        gemm_nt_sk<<<dim3(KS, M_ / BM), 256, 0, stream>>>(xcb, xwp, part, M_, 64, ED_);
        k_red8<<<(M_ * 64 / 4 + 255) / 256, 256, 0, stream>>>(part, dbc, M_ * 64 / 4);
        k_scan_a<<<dim3(ED_ / 256, NC_, B_), 256, 0, stream>>>(xcb, dbc, wtl, db, a0l, sfl, al, delta, sumd, hl);
        k_scan_b<<<S_ / 256, 256, 0, stream>>>(sumd, hl, al, carry);
        k_scan_c<<<dim3(ED_ / 256, NC_, B_), 256, 0, stream>>>(xcb, delta, dbc, xzb, a0l, sfl, al, dp, carry, ybf);
        if (layer == 0) {
            gemm_bt<2, 64><<<dim3(D_ / 64, M_ / 128), 256, 0, stream>>>(ybf, ow, xw, mask, nullptr, nullptr, M_, D_, ED_);
        } else {
            gemm_bt<3, 64><<<dim3(D_ / 64, M_ / 128), 256, 0, stream>>>(ybf, ow, xw, mask, flag, d_out, M_, D_, ED_);
        }
    }
}

// Round 15
// 467.429 us; speedup vs baseline: 1.1628x; 1.0053x over previous
//
#include <hip/hip_runtime.h>
#include <math.h>

#define B_ 4
#define L_ 2048
#define D_ 512
#define ED_ 1024
#define N_ 16
#define R_ 32
#define KC_ 4
#define M_ (B_*L_)   // 8192 rows
#define NC_ 128      // scan chunks (8 blocks/CU occupancy regime)
#define T_  (L_/NC_) // 16 steps per chunk
#define S_  (B_*ED_*N_)  // 65536 scan series
#define BE_ (B_*ED_)     // 4096
#define LOG2E 1.44269504f
#define LN2   0.69314718f

typedef __attribute__((ext_vector_type(8))) short short8;
typedef __attribute__((ext_vector_type(4))) float floatx4;
typedef __attribute__((ext_vector_type(2))) float floatv2;   // -> v_pk_*_f32

static __device__ __forceinline__ float b2f(unsigned short u) {
    unsigned int v = ((unsigned int)u) << 16;
    float f;
    __builtin_memcpy(&f, &v, 4);
    return f;
}
static __device__ __forceinline__ unsigned short f2b(float f) {
    unsigned int u;
    __builtin_memcpy(&u, &f, 4);
    unsigned int lsb = (u >> 16) & 1u;
    u += 0x7fffu + lsb;                 // round-to-nearest-even
    return (unsigned short)(u >> 16);
}
static __device__ __forceinline__ float silu(float x) {
    return x / (1.f + exp2f(-LOG2E * x));
}
static __device__ __forceinline__ float softplusf(float x) {
    return fmaxf(x, 0.f) + LN2 * log2f(1.f + exp2f(-LOG2E * fabsf(x)));
}
// pw[i] = {a^(2i+1), a^(2i+2)} via packed tree (depth 4)
static __device__ __forceinline__ void pow_tree2(float a1, floatv2* pw) {
    float a2 = a1 * a1, a4 = a2 * a2, a8 = a4 * a4;
    pw[0] = (floatv2){a1, a2};
    pw[1] = pw[0] * a2;
    pw[2] = pw[0] * a4;
    pw[3] = pw[1] * a4;
    pw[4] = pw[0] * a8;
    pw[5] = pw[1] * a8;
    pw[6] = pw[2] * a8;
    pw[7] = pw[3] * a8;
}

// ---------- dtype detection ----------
__global__ void k_flag0(int* flag) {
    if (blockIdx.x == 0 && threadIdx.x == 0) *flag = 0;
}
__global__ void k_detect(const unsigned short* __restrict__ x, int* flag) {
    int i = blockIdx.x * 256 + threadIdx.x;
    unsigned int e = (x[i] >> 7) & 0xFF;
    unsigned long long m = __ballot(e >= 0x88);
    if ((threadIdx.x & 63) == 0 && m != 0ull) atomicOr(flag, 1);
}

// ---------- batched conversions ----------
struct Seg9 { const void* src[9]; int prefix[10]; };
__global__ void k_cvt_batch(Seg9 segs, float* __restrict__ dst, int total,
                            const int* __restrict__ flag) {
    int i = blockIdx.x * 256 + threadIdx.x;
    if (i >= total) return;
    int s = 0;
#pragma unroll
    for (int k = 1; k < 9; ++k) if (i >= segs.prefix[k]) s = k;
    int off = i - segs.prefix[s];
    if (*flag) dst[i] = ((const float*)segs.src[s])[off];
    else       dst[i] = b2f(((const unsigned short*)segs.src[s])[off]);
}
__global__ void k_cvt_bf_batch(const void* __restrict__ src0,
                               const void* __restrict__ src1,
                               unsigned short* __restrict__ dst,
                               int n0, int total, const int* __restrict__ flag) {
    int i = blockIdx.x * 256 + threadIdx.x;
    if (i >= total) return;
    const void* src = (i < n0) ? src0 : src1;
    int off = (i < n0) ? i : i - n0;
    if (*flag) dst[i] = f2b(((const float*)src)[off]);
    else       dst[i] = ((const unsigned short*)src)[off];
}

// ---------- scan prep (once): transpose dtw to coalesced layout, A0, flag ----
// wT layout per layer: [R/4][ED][4] floats = float4 index (r4*ED + e).
__global__ void k_prep(const float* __restrict__ wdt,
                       const float* __restrict__ A_log,
                       float* __restrict__ wT,
                       float* __restrict__ A0s,
                       int* __restrict__ structf) {
    int idx = blockIdx.x * 256 + threadIdx.x;       // 0 .. 2*ED_-1
    int layer = idx >> 10, e = idx & (ED_ - 1);
    const float* src = wdt + (size_t)idx * R_;
    float* dstb = wT + (size_t)layer * (R_ * ED_);
#pragma unroll
    for (int r = 0; r < R_; ++r)
        dstb[(r >> 2) * (ED_ * 4) + e * 4 + (r & 3)] = src[r];
    float A0 = -exp2f(LOG2E * A_log[(size_t)idx * N_]) * LOG2E;
    bool st = true;
#pragma unroll
    for (int n = 1; n < N_; ++n) {
        float An = -exp2f(LOG2E * A_log[(size_t)idx * N_ + n]) * LOG2E;
        st = st && (fabsf(An - (n + 1) * A0) <= 1e-4f * fabsf(An));
    }
    A0s[idx] = A0;
    structf[idx] = st ? 1 : 0;
}

// ---------- rmsnorm with mask; writes u (bf16). 2 rows/block. ----------
__global__ __launch_bounds__(256) void k_rmsnorm(const float* __restrict__ x,
                                                 const int* __restrict__ mask,
                                                 const float* __restrict__ w,
                                                 unsigned short* __restrict__ ubf) {
    int tid = threadIdx.x;
    int row = blockIdx.x * 2 + (tid >> 7);
    int t128 = tid & 127;
    size_t base = (size_t)row * D_ + t128 * 4;
    float4 v = *(const float4*)(x + base);
    float mv = (float)mask[row];
    v.x *= mv; v.y *= mv; v.z *= mv; v.w *= mv;
    float ss = v.x*v.x + v.y*v.y + v.z*v.z + v.w*v.w;
#pragma unroll
    for (int o = 1; o < 64; o <<= 1) ss += __shfl_xor(ss, o, 64);
    __shared__ float sred[4];
    if ((tid & 63) == 0) sred[tid >> 6] = ss;
    __syncthreads();
    int g = tid >> 7;
    float rs = rsqrtf((sred[2 * g] + sred[2 * g + 1]) / (float)D_ + 1e-5f);
    float4 wv = *(const float4*)(w + t128 * 4);
    ushort4 b4;
    b4.x = f2b(v.x * rs * wv.x);
    b4.y = f2b(v.y * rs * wv.y);
    b4.z = f2b(v.z * rs * wv.z);
    b4.w = f2b(v.w * rs * wv.w);
    *(ushort4*)(ubf + base) = b4;
}

// ---------- bf16 MFMA GEMM: out = A[M,K] * W[N,K]^T ----------
// 3-buffer rotation, depth-2 prefetch, counted vmcnt (T3+T4). One raw
// s_barrier per K-step; lgkmcnt(0) before barrier closes the read-reuse race.
// XCD-aware bijective block swizzle (grid % 8 == 0 for all call sites).
// MODE 1: write bf16. MODE 2: C=xw RMW + mask. MODE 3: like 2 but writes the
// final output buffer (dtype by flag) + the x[:,0,:] slice; xw not written.
typedef __attribute__((address_space(1))) const unsigned int guint;
typedef __attribute__((address_space(3))) unsigned int luint;
#define GLL(gp, lp) __builtin_amdgcn_global_load_lds((guint*)(const void*)(gp), (luint*)(void*)(lp), 16, 0, 0)

template<int N> static __device__ __forceinline__ void waitv() {
    if constexpr (N == 0) asm volatile("s_waitcnt vmcnt(0)" ::: "memory");
    else if constexpr (N == 3) asm volatile("s_waitcnt vmcnt(3)" ::: "memory");
    else if constexpr (N == 4) asm volatile("s_waitcnt vmcnt(4)" ::: "memory");
}

template<int MODE, int BNT>
__global__ __launch_bounds__(256) void gemm_bt(const unsigned short* __restrict__ A,
                                               const unsigned short* __restrict__ W,
                                               void* __restrict__ C,
                                               const int* __restrict__ mask,
                                               const int* __restrict__ flag,
                                               void* __restrict__ out,
                                               int M, int N, int K) {
    constexpr int NF = BNT / 32;                 // n-frags per wave: 128->4, 64->2
    constexpr int LW = 2 + BNT / 64;             // GLL issues per wave per stage: 4 or 3
    __shared__ unsigned short As[3][128][32];
    __shared__ unsigned short Bs[3][BNT][32];
    int tid  = threadIdx.x;
    int wave = tid >> 6;
    int lane = tid & 63;
    // XCD-aware bijective swizzle (nwg multiple of 8)
    int nwg = gridDim.x * gridDim.y;
    int id  = blockIdx.y * gridDim.x + blockIdx.x;
    int swz = (id & 7) * (nwg >> 3) + (id >> 3);
    int m0 = (swz / gridDim.x) * 128;
    int n0 = (swz % gridDim.x) * BNT;
    int wm = (wave & 1) * 64;
    int wn = (wave >> 1) * (BNT / 2);
    int quad = lane >> 4;
    int l16  = lane & 15;
    int crd = (quad ^ ((l16 >> 1) & 3)) * 8;       // swizzled fragment-read position

    int rA0 = wave * 16 + (lane >> 2);             // rows 0..63; +64 for second issue
    int cA  = ((lane & 3) ^ ((rA0 >> 1) & 3)) * 8;

    floatx4 acc[4][NF] = {};

    auto stage = [&](int buf, int k0) {
        const unsigned short* gA0 = A + (size_t)(m0 + rA0) * K + k0 + cA;
        GLL(gA0,                   &As[buf][wave * 16][0]);
        GLL(gA0 + (size_t)64 * K,  &As[buf][64 + wave * 16][0]);
        const unsigned short* gB0 = W + (size_t)(n0 + rA0) * K + k0 + cA;
        GLL(gB0,                   &Bs[buf][wave * 16][0]);
        if constexpr (BNT == 128)
            GLL(gB0 + (size_t)64 * K, &Bs[buf][64 + wave * 16][0]);
    };

    int nk = K / 32;                               // >= 2 always here
    stage(0, 0);
    stage(1, 32);

    int cur = 0;
    for (int t = 0; t < nk; ++t) {
        if (t + 1 < nk) waitv<LW>();               // stage t landed; t+1 stays in flight
        else            waitv<0>();
        asm volatile("s_barrier" ::: "memory");    // collective: buf cur fully written,
                                                   // and all reads of buf (cur+2)%3 done
        if (t + 2 < nk) {
            int bw = cur + 2; if (bw >= 3) bw -= 3;
            stage(bw, (t + 2) * 32);
        }
        short8 af[4], bfr[NF];
#pragma unroll
        for (int f = 0; f < 4; ++f)
            af[f]  = *(const short8*)&As[cur][wm + f * 16 + l16][crd];
#pragma unroll
        for (int f = 0; f < NF; ++f)
            bfr[f] = *(const short8*)&Bs[cur][wn + f * 16 + l16][crd];
#pragma unroll
        for (int mf = 0; mf < 4; ++mf)
#pragma unroll
            for (int nf = 0; nf < NF; ++nf)
                acc[mf][nf] = __builtin_amdgcn_mfma_f32_16x16x32_bf16(af[mf], bfr[nf], acc[mf][nf], 0, 0, 0);
        asm volatile("s_waitcnt lgkmcnt(0)" ::: "memory");  // reads of buf cur complete
        cur = (cur == 2) ? 0 : cur + 1;
    }

    int fl = (MODE == 3) ? *flag : 0;
#pragma unroll
    for (int mf = 0; mf < 4; ++mf) {
#pragma unroll
        for (int nf = 0; nf < NF; ++nf) {
#pragma unroll
            for (int i = 0; i < 4; ++i) {
                int r = m0 + wm + mf * 16 + quad * 4 + i;   // C/D: row=quad*4+reg
                int c = n0 + wn + nf * 16 + l16;            //      col=lane&15
                size_t idx = (size_t)r * N + c;
                if (MODE == 1) {
                    ((unsigned short*)C)[idx] = f2b(acc[mf][nf][i]);
                } else if (MODE == 2) {
                    float* C32 = (float*)C;
                    float mv = (float)mask[r];
                    C32[idx] = (C32[idx] + acc[mf][nf][i]) * mv;
                } else {
                    const float* C32 = (const float*)C;
                    float mv = (float)mask[r];
                    float v = (C32[idx] + acc[mf][nf][i]) * mv;
                    if (fl) ((float*)out)[idx] = v;
                    else    ((unsigned short*)out)[idx] = f2b(v);
                    if ((r & (L_ - 1)) == 0) {
                        size_t oidx = (size_t)M_ * D_ + (size_t)(r >> 11) * D_ + c;
                        if (fl) ((float*)out)[oidx] = v;
                        else    ((unsigned short*)out)[oidx] = f2b(v);
                    }
                }
            }
        }
    }
}

// ---------- split-K f32 GEMM (GEMM2, N=64); A in bf16; part in bf16 ----------
#define BM 64
#define BN 64
#define BK 16
#define KS 8
__global__ __launch_bounds__(256) void gemm_nt_sk(const unsigned short* __restrict__ A,
                                                  const float* __restrict__ W,
                                                  unsigned short* __restrict__ part,
                                                  int M, int N, int K) {
    __shared__ float Asm[BK][BM + 4];
    __shared__ float Wsm[BK][BN + 4];
    int tid = threadIdx.x;
    int ks = blockIdx.x;
    int m0 = blockIdx.y * BM;
    int kb = ks * (K / KS);
    int ke = kb + (K / KS);
    int tx = tid & 15;
    int ty = tid >> 4;
    int lr = tid >> 2;
    int lk = (tid & 3) * 4;
    float acc[4][4] = {};
    for (int k0 = kb; k0 < ke; k0 += BK) {
        ushort4 av = *(const ushort4*)(A + (size_t)(m0 + lr) * K + k0 + lk);
        Asm[lk + 0][lr] = b2f(av.x); Asm[lk + 1][lr] = b2f(av.y);
        Asm[lk + 2][lr] = b2f(av.z); Asm[lk + 3][lr] = b2f(av.w);
        float4 wv = *(const float4*)(W + (size_t)lr * K + k0 + lk);
        Wsm[lk + 0][lr] = wv.x; Wsm[lk + 1][lr] = wv.y;
        Wsm[lk + 2][lr] = wv.z; Wsm[lk + 3][lr] = wv.w;
        __syncthreads();
#pragma unroll
        for (int kk = 0; kk < BK; ++kk) {
            float4 a = *(const float4*)&Asm[kk][ty * 4];
            float4 w = *(const float4*)&Wsm[kk][tx * 4];
            acc[0][0] += a.x * w.x; acc[0][1] += a.x * w.y; acc[0][2] += a.x * w.z; acc[0][3] += a.x * w.w;
            acc[1][0] += a.y * w.x; acc[1][1] += a.y * w.y; acc[1][2] += a.y * w.z; acc[1][3] += a.y * w.w;
            acc[2][0] += a.z * w.x; acc[2][1] += a.z * w.y; acc[2][2] += a.z * w.z; acc[2][3] += a.z * w.w;
            acc[3][0] += a.w * w.x; acc[3][1] += a.w * w.y; acc[3][2] += a.w * w.z; acc[3][3] += a.w * w.w;
        }
        __syncthreads();
    }
    unsigned short* p = part + (size_t)ks * M * N;
#pragma unroll
    for (int i = 0; i < 4; ++i) {
        int m = m0 + ty * 4 + i;
        ushort4 o;
        o.x = f2b(acc[i][0]); o.y = f2b(acc[i][1]);
        o.z = f2b(acc[i][2]); o.w = f2b(acc[i][3]);
        *(ushort4*)(p + (size_t)m * N + tx * 4) = o;
    }
}

__global__ void k_red8(const unsigned short* __restrict__ part, float* __restrict__ dbc, int mn4) {
    int i = blockIdx.x * 256 + threadIdx.x;
    if (i >= mn4) return;
    float4 s;
    {
        ushort4 v = ((const ushort4*)part)[i];
        s.x = b2f(v.x); s.y = b2f(v.y); s.z = b2f(v.z); s.w = b2f(v.w);
    }
#pragma unroll
    for (int ks = 1; ks < KS; ++ks) {
        ushort4 v = ((const ushort4*)(part + (size_t)ks * mn4 * 4))[i];
        s.x += b2f(v.x); s.y += b2f(v.y); s.z += b2f(v.z); s.w += b2f(v.w);
    }
    ((float4*)dbc)[i] = s;
}

// ---------- depthwise causal conv (K=4) + bias + SiLU; xz in bf16 ----------
// 2-wide over e: ushort2 reads (4B/lane); OUTPUT bf16.
__global__ __launch_bounds__(256) void k_conv(const unsigned short* __restrict__ xzb,
                                              const float* __restrict__ cw,
                                              const float* __restrict__ cb,
                                              unsigned short* __restrict__ xcb) {
    int idx = blockIdx.x * 256 + threadIdx.x;      // 0 .. M_*ED_/2
    int e2 = idx & (ED_ / 2 - 1);
    int e  = e2 * 2;
    int bl = idx >> 9;
    int l  = bl & (L_ - 1);
    float acc0 = cb[e], acc1 = cb[e + 1];
    const unsigned short* col = xzb + (size_t)bl * (2 * ED_) + e;
    float4 wa = *(const float4*)(cw + e * 4);
    float4 wb = *(const float4*)(cw + e * 4 + 4);
    ushort2 v3 = *(const ushort2*)(col);
    if (l >= 3) {
        ushort2 v0 = *(const ushort2*)(col - 3 * 2 * ED_);
        ushort2 v1 = *(const ushort2*)(col - 2 * 2 * ED_);
        ushort2 v2 = *(const ushort2*)(col - 1 * 2 * ED_);
        acc0 += wa.x * b2f(v0.x) + wa.y * b2f(v1.x) + wa.z * b2f(v2.x) + wa.w * b2f(v3.x);
        acc1 += wb.x * b2f(v0.y) + wb.y * b2f(v1.y) + wb.z * b2f(v2.y) + wb.w * b2f(v3.y);
    } else {
        if (l >= 2) {
            ushort2 v1 = *(const ushort2*)(col - 2 * 2 * ED_);
            acc0 += wa.y * b2f(v1.x); acc1 += wb.y * b2f(v1.y);
        }
        if (l >= 1) {
            ushort2 v2 = *(const ushort2*)(col - 1 * 2 * ED_);
            acc0 += wa.z * b2f(v2.x); acc1 += wb.z * b2f(v2.y);
        }
        acc0 += wa.w * b2f(v3.x); acc1 += wb.w * b2f(v3.y);
    }
    ushort2 o;
    o.x = f2b(silu(acc0));
    o.y = f2b(silu(acc1));
    *(ushort2*)(xcb + (size_t)bl * ED_ + e) = o;
}

// ---------- chunked selective scan ----------
// bf16 hl/carry and bf16 delta (cross-kernel storage quantized; all internal
// arithmetic f32). sumd stays f32.
__global__ __launch_bounds__(256) void k_scan_a(const unsigned short* __restrict__ xcb,
                                                const float* __restrict__ dbc,
                                                const float* __restrict__ wt,
                                                const float* __restrict__ dtb,
                                                const float* __restrict__ A0s,
                                                const int* __restrict__ structf,
                                                const float* __restrict__ A_log,
                                                unsigned short* __restrict__ delta,
                                                float* __restrict__ sumdbuf,
                                                unsigned short* __restrict__ hl) {
    int b = blockIdx.z, c = blockIdx.y;
    int e = blockIdx.x * 256 + threadIdx.x;
    __shared__ float sRow[T_][64];
    size_t t0 = (size_t)b * L_ + (size_t)c * T_;
    {
        const float4* src = (const float4*)(dbc + t0 * 64);
        float4* dst = (float4*)&sRow[0][0];
#pragma unroll
        for (int i = 0; i < T_ * 16; i += 256)
            dst[i + threadIdx.x] = src[i + threadIdx.x];
    }
    __syncthreads();
    floatv2 w2[R_ / 2];
    {
        const float4* wtp = (const float4*)wt;
#pragma unroll
        for (int i = 0; i < 8; ++i) {
            float4 v = wtp[(size_t)i * ED_ + e];              // coalesced
            w2[2 * i]     = (floatv2){v.x, v.y};
            w2[2 * i + 1] = (floatv2){v.z, v.w};
        }
    }
    float bias = dtb[e];
    float A0 = A0s[e];
    bool structured = structf[e] != 0;
    floatv2 h2[8];
#pragma unroll
    for (int i = 0; i < 8; ++i) h2[i] = (floatv2){0.f, 0.f};
    float sumd = 0.f;
    if (structured) {
        const unsigned short* xp = xcb + t0 * ED_ + e;
        unsigned short* dep = delta + t0 * ED_ + e;
        float xv_t = b2f(*xp); xp += ED_;
        for (int t = 0; t < T_; ++t) {
            unsigned short xr = (t + 1 < T_) ? *xp : (unsigned short)0; xp += ED_;  // prefetch
            const floatv2* dt2 = (const floatv2*)&sRow[t][0];
            floatv2 q0 = {0.f, 0.f}, q1 = {0.f, 0.f}, q2 = {0.f, 0.f}, q3 = {0.f, 0.f};
#pragma unroll
            for (int r = 0; r < R_ / 2; r += 4) {
                q0 += dt2[r + 0] * w2[r + 0];
                q1 += dt2[r + 1] * w2[r + 1];
                q2 += dt2[r + 2] * w2[r + 2];
                q3 += dt2[r + 3] * w2[r + 3];
            }
            floatv2 qs = (q0 + q1) + (q2 + q3);
            float d = softplusf(qs.x + qs.y + bias);
            *dep = f2b(d); dep += ED_;             // bf16 coalesced delta store
            float dx = d * xv_t;
            sumd += d;
            floatv2 pw[8];
            pow_tree2(exp2f(d * A0), pw);
            const floatv2* bb2 = (const floatv2*)&sRow[t][32];
#pragma unroll
            for (int i = 0; i < 8; ++i)
                h2[i] = pw[i] * h2[i] + dx * bb2[i];
            xv_t = b2f(xr);
        }
    } else {
        float A[N_];
        float* h = (float*)h2;
#pragma unroll
        for (int n = 0; n < N_; ++n) A[n] = -exp2f(LOG2E * A_log[e * N_ + n]) * LOG2E;
        float* wsc = (float*)w2;
        for (int t = 0; t < T_; ++t) {
            size_t bl = t0 + t;
            float p0 = bias, p1 = 0.f, p2 = 0.f, p3 = 0.f;
#pragma unroll
            for (int r = 0; r < R_; r += 4) {
                p0 += sRow[t][r + 0] * wsc[r + 0];
                p1 += sRow[t][r + 1] * wsc[r + 1];
                p2 += sRow[t][r + 2] * wsc[r + 2];
                p3 += sRow[t][r + 3] * wsc[r + 3];
            }
            float d = softplusf((p0 + p1) + (p2 + p3));
            delta[bl * ED_ + e] = f2b(d);
            float dx = d * b2f(xcb[bl * ED_ + e]);
            sumd += d;
#pragma unroll
            for (int n = 0; n < N_; ++n) {
                float a = exp2f(d * A[n]);
                h[n] = a * h[n] + dx * sRow[t][32 + n];
            }
        }
    }
    size_t base = (size_t)c * BE_ + (size_t)b * ED_ + e;
    const float* h = (const float*)h2;
#pragma unroll
    for (int n = 0; n < N_; ++n)
        hl[(size_t)n * (NC_ * BE_) + base] = f2b(h[n]);         // bf16 coalesced streams
    sumdbuf[base] = sumd;
}

// carry recurrence over chunks; pa reconstructed as exp2(sumd*A_n).
// thread -> (n, be): all hl/carry/sumd accesses coalesced. Internal h is f32;
// stored hl/carry are bf16. 8-deep prefetch ring.
__global__ __launch_bounds__(256) void k_scan_b(const float* __restrict__ sumd,
                                                const unsigned short* __restrict__ hl,
                                                const float* __restrict__ A_log,
                                                unsigned short* __restrict__ carry) {
    int s = blockIdx.x * 256 + threadIdx.x;     // 0..S_-1
    int n  = s >> 12;                           // S_/N_ = 4096 = BE_
    int be = s & (BE_ - 1);
    int e  = be & (ED_ - 1);
    float An = -exp2f(LOG2E * A_log[e * N_ + n]) * LOG2E;
    const unsigned short* hln = hl    + (size_t)n * (NC_ * BE_);
    unsigned short*       crn = carry + (size_t)n * (NC_ * BE_);
    float sdr[8], hlr[8];
#pragma unroll
    for (int c = 0; c < 8; ++c) {
        sdr[c] = sumd[(size_t)c * BE_ + be];
        hlr[c] = b2f(hln[(size_t)c * BE_ + be]);
    }
    float h = 0.f;
#pragma unroll
    for (int c = 0; c < NC_; ++c) {
        int r = c & 7;
        crn[(size_t)c * BE_ + be] = f2b(h);
        float p = exp2f(sdr[r] * An), q = hlr[r];
        if (c + 8 < NC_) {
            sdr[r] = sumd[(size_t)(c + 8) * BE_ + be];
            hlr[r] = b2f(hln[(size_t)(c + 8) * BE_ + be]);
        }
        h = p * h + q;
    }
}

__global__ __launch_bounds__(256) void k_scan_c(const unsigned short* __restrict__ xcb,
                                                const unsigned short* __restrict__ delta,
                                                const float* __restrict__ dbc,
                                                const unsigned short* __restrict__ xzb,
                                                const float* __restrict__ A0s,
                                                const int* __restrict__ structf,
                                                const float* __restrict__ A_log,
                                                const float* __restrict__ Dp,
                                                const unsigned short* __restrict__ carry,
                                                unsigned short* __restrict__ ybf) {
    int b = blockIdx.z, c = blockIdx.y;
    int e = blockIdx.x * 256 + threadIdx.x;
    __shared__ float sBC[T_][32];                   // B at [0..16), C at [16..32)
    size_t t0 = (size_t)b * L_ + (size_t)c * T_;
    {
        int i = threadIdx.x;                        // stage only cols 32..63 of dbc rows
        if (i < T_ * 8) {
            int t = i >> 3, q = i & 7;
            ((float4*)&sBC[t][0])[q] = *(const float4*)(dbc + (t0 + t) * 64 + 32 + q * 4);
        }
    }
    __syncthreads();
    float A0 = A0s[e];
    bool structured = structf[e] != 0;
    floatv2 h2[8];
    size_t base = (size_t)c * BE_ + (size_t)b * ED_ + e;
    {
        float hs[N_];
#pragma unroll
        for (int n = 0; n < N_; ++n)
            hs[n] = b2f(carry[(size_t)n * (NC_ * BE_) + base]);  // bf16 coalesced streams
#pragma unroll
        for (int i = 0; i < 8; ++i) h2[i] = (floatv2){hs[2 * i], hs[2 * i + 1]};
    }
    float Dv = Dp[e];
    if (structured) {
        const unsigned short* xp = xcb + t0 * ED_ + e;
        const unsigned short* dp_ = delta + t0 * ED_ + e;
        const unsigned short* zp = xzb + t0 * (2 * ED_) + ED_ + e;
        unsigned short* yp = ybf + t0 * ED_ + e;
        float xv_t = b2f(*xp); xp += ED_;
        float d_t  = b2f(*dp_); dp_ += ED_;
        unsigned short z_t = *zp; zp += 2 * ED_;
        for (int t = 0; t < T_; ++t) {
            unsigned short xr = 0, dr = 0, z_n = 0;
            if (t + 1 < T_) {                       // prefetch next step
                xr  = *xp;
                dr  = *dp_;
                z_n = *zp;
            }
            xp += ED_; dp_ += ED_; zp += 2 * ED_;
            float dx = d_t * xv_t;
            floatv2 pw[8];
            pow_tree2(exp2f(d_t * A0), pw);
            const floatv2* bb2 = (const floatv2*)&sBC[t][0];
            const floatv2* cc2 = (const floatv2*)&sBC[t][16];
            floatv2 y0 = {0.f, 0.f}, y1 = {0.f, 0.f};
#pragma unroll
            for (int i = 0; i < 8; i += 2) {
                h2[i + 0] = pw[i + 0] * h2[i + 0] + dx * bb2[i + 0];
                h2[i + 1] = pw[i + 1] * h2[i + 1] + dx * bb2[i + 1];
                y0 += h2[i + 0] * cc2[i + 0];
                y1 += h2[i + 1] * cc2[i + 1];
            }
            floatv2 ys = y0 + y1;
            float y = ys.x + ys.y;
            float z = b2f(z_t);
            *yp = f2b((y + Dv * xv_t) * silu(z)); yp += ED_;
            xv_t = b2f(xr); d_t = b2f(dr); z_t = z_n;
        }
    } else {
        float A[N_];
        float* h = (float*)h2;
#pragma unroll
        for (int n = 0; n < N_; ++n) A[n] = -exp2f(LOG2E * A_log[e * N_ + n]) * LOG2E;
        for (int t = 0; t < T_; ++t) {
            size_t bl = t0 + t;
            float d  = b2f(delta[bl * ED_ + e]);
            float xv = b2f(xcb[bl * ED_ + e]);
            float dx = d * xv;
            float y = 0.f;
#pragma unroll
            for (int n = 0; n < N_; ++n) {
                float a = exp2f(d * A[n]);
                h[n] = a * h[n] + dx * sBC[t][n];
                y += h[n] * sBC[t][16 + n];
            }
            float z = b2f(xzb[bl * (2 * ED_) + ED_ + e]);
            ybf[bl * ED_ + e] = f2b((y + Dv * xv) * silu(z));
        }
    }
}

extern "C" void kernel_launch(void* const* d_in, const int* in_sizes, int n_in,
                              void* d_out, int out_size, void* d_ws, size_t ws_size,
                              hipStream_t stream) {
    const int* mask = (const int*)d_in[1];

    // workspace layout: byte offsets unchanged from r14 (regions half-used
    // where dtype shrank); ~187.9 MB < 191.8 MB proven
    float* ws = (float*)d_ws;
    int*   flag = (int*)d_ws;
    float* xw   = ws + 16;                          // M_*D_         4,194,304
    float* wn   = xw   + (size_t)M_ * D_;           // 1,024
    float* wc   = wn   + 1024;                      // 8,192
    float* wcb  = wc   + 8192;                      // 2,048
    float* wx   = wcb  + 2048;                      // 131,072
    float* wdt  = wx   + 131072;                    // 65,536
    float* wdtb = wdt  + 65536;                     // 2,048
    float* wal  = wdtb + 2048;                      // 32,768
    float* wdp  = wal  + 32768;                     // 2,048
    unsigned short* wib = (unsigned short*)(wdp + 2048);      // 2,097,152 ushorts
    unsigned short* wob = wib + 2097152;                      // 1,048,576 ushorts
    unsigned short* ubf = wob + 1048576;                      // 4,194,304 ushorts
    unsigned short* xzb = ubf + (size_t)M_ * D_;              // 16,777,216 ushorts
    unsigned short* xcb = xzb + (size_t)M_ * 2 * ED_;         // 8,388,608 ushorts (bf16 xc)
    float* dbc  = (float*)(xcb + (size_t)M_ * ED_);  // 524,288
    float* hlf  = dbc   + (size_t)M_ * 64;          // region: NC_*S_ floats (bf16 uses half)
    float* carf = hlf   + (size_t)NC_ * S_;         // region: NC_*S_ floats
    float* sumd = carf  + (size_t)NC_ * S_;         // NC_*BE_ = 524,288
    float* wT   = sumd  + (size_t)NC_ * BE_;        // 2*R_*ED_ = 65,536
    float* A0s  = wT    + 2 * R_ * ED_;             // 2*ED_ = 2,048
    int*   stfl = (int*)(A0s + 2 * ED_);            // 2*ED_ = 2,048
    unsigned short* delta = (unsigned short*)(stfl + 2 * ED_); // M_*ED_ ushorts (bf16)
    unsigned short* hl    = (unsigned short*)hlf;   // NC_*S_ ushorts (half the region)
    unsigned short* carry = (unsigned short*)carf;  // NC_*S_ ushorts
    unsigned short* ybf = (unsigned short*)hlf;     // alias: hl dead after scan_b
    unsigned short* part = (unsigned short*)carf;   // KS*M_*64 ushorts; carf dead until scan_b

    k_flag0<<<1, 1, 0, stream>>>(flag);
    k_detect<<<128, 256, 0, stream>>>((const unsigned short*)d_in[0], flag);

    {
        Seg9 segs;
        int idxs[9] = {0, 2, 4, 5, 6, 7, 8, 9, 10};
        int pre = 0;
        for (int i = 0; i < 9; ++i) {
            segs.src[i] = d_in[idxs[i]];
            segs.prefix[i] = pre;
            pre += in_sizes[idxs[i]];
        }
        segs.prefix[9] = pre;
        k_cvt_batch<<<(pre + 255) / 256, 256, 0, stream>>>(segs, xw, pre, flag);
        int n0 = 2 * 2 * ED_ * D_;
        int tot = n0 + 2 * D_ * ED_;
        k_cvt_bf_batch<<<(tot + 255) / 256, 256, 0, stream>>>(d_in[3], d_in[11], wib, n0, tot, flag);
    }
    k_prep<<<(2 * ED_) / 256, 256, 0, stream>>>(wdt, wal, wT, A0s, stfl);

    for (int layer = 0; layer < 2; ++layer) {
        const float* nw = wn  + layer * D_;
        const unsigned short* iw = wib + (size_t)layer * 2 * ED_ * D_;
        const float* cw = wc  + layer * ED_ * KC_;
        const float* cb = wcb + layer * ED_;
        const float* xwp= wx  + (size_t)layer * 64 * ED_;
        const float* db = wdtb+ layer * ED_;
        const float* al = wal + layer * ED_ * N_;
        const float* dp = wdp + layer * ED_;
        const float* wtl= wT  + (size_t)layer * R_ * ED_;
        const float* a0l= A0s + layer * ED_;
        const int*   sfl= stfl+ layer * ED_;
        const unsigned short* ow = wob + (size_t)layer * D_ * ED_;

        k_rmsnorm<<<M_ / 2, 256, 0, stream>>>(xw, mask, nw, ubf);
        gemm_bt<1, 128><<<dim3(2 * ED_ / 128, M_ / 128), 256, 0, stream>>>(ubf, iw, xzb, nullptr, nullptr, nullptr, M_, 2 * ED_, D_);
        k_conv<<<(M_ * ED_ / 2) / 256, 256, 0, stream>>>(xzb, cw, cb, xcb);
        gemm_nt_sk<<<dim3(KS, M_ / BM), 256, 0, stream>>>(xcb, xwp, part, M_, 64, ED_);
        k_red8<<<(M_ * 64 / 4 + 255) / 256, 256, 0, stream>>>(part, dbc, M_ * 64 / 4);
        k_scan_a<<<dim3(ED_ / 256, NC_, B_), 256, 0, stream>>>(xcb, dbc, wtl, db, a0l, sfl, al, delta, sumd, hl);
        k_scan_b<<<S_ / 256, 256, 0, stream>>>(sumd, hl, al, carry);
        k_scan_c<<<dim3(ED_ / 256, NC_, B_), 256, 0, stream>>>(xcb, delta, dbc, xzb, a0l, sfl, al, dp, carry, ybf);
        if (layer == 0) {
            gemm_bt<2, 64><<<dim3(D_ / 64, M_ / 128), 256, 0, stream>>>(ybf, ow, xw, mask, nullptr, nullptr, M_, D_, ED_);
        } else {
            gemm_bt<3, 64><<<dim3(D_ / 64, M_ / 128), 256, 0, stream>>>(ybf, ow, xw, mask, flag, d_out, M_, D_, ED_);
        }
    }
}